// Round 9
// baseline (349.847 us; speedup 1.0000x reference)
//
#include <hip/hip_runtime.h>
#include <math.h>

#define NN 16384
#define BB 128
#define FF 32
#define RR 20
#define EE 262144

__device__ __forceinline__ float sspf(float x) {
  // softplus(x) - log(2), numerically stable
  return fmaxf(x, 0.0f) + log1pf(expf(-fabsf(x))) - 0.69314718055994531f;
}

// Pin a float into a VGPR (defeats load-rematerialization). Only safe when the
// pinned set + live temps fits the register budget (proven at 32 pinned, R4).
#define PIN(v) asm volatile("" : "+v"(v))

// ---------------- K1: node embeddings, x rows staged in LDS ----------------
__global__ __launch_bounds__(256) void k_embed(const float* __restrict__ x,
        const float* __restrict__ ws, const float* __restrict__ wv,
        float4* __restrict__ hsv) {
  __shared__ float sx[32 * 516];   // 66 KB
  int t = threadIdx.x;
  int b0 = blockIdx.x * 32;        // 512 blocks
  const float4* xg = (const float4*)(x + (size_t)b0 * 512);
  for (int i = t; i < 4096; i += 256) {
    int row = i >> 7, col = i & 127;
    *(float4*)(sx + row * 516 + col * 4) = xg[i];
  }
  __syncthreads();
  int n = t >> 3, fq = t & 7;
  const float* xr = sx + n * 516;
  float acc[4][4];
#pragma unroll
  for (int k = 0; k < 4; k++)
#pragma unroll
    for (int c = 0; c < 4; c++) acc[k][c] = 0.f;
  for (int bq = 0; bq < 32; bq++) {
    float4 xs4 = *(const float4*)(xr + 4 * bq);
    float4 a0 = *(const float4*)(xr + 128 + 12 * bq);
    float4 a1 = *(const float4*)(xr + 128 + 12 * bq + 4);
    float4 a2 = *(const float4*)(xr + 128 + 12 * bq + 8);
    float xsv[4] = {xs4.x, xs4.y, xs4.z, xs4.w};
    float vv[4][3];
    vv[0][0] = a0.x; vv[0][1] = a0.y; vv[0][2] = a0.z;
    vv[1][0] = a0.w; vv[1][1] = a1.x; vv[1][2] = a1.y;
    vv[2][0] = a1.z; vv[2][1] = a1.w; vv[2][2] = a2.x;
    vv[3][0] = a2.y; vv[3][1] = a2.z; vv[3][2] = a2.w;
#pragma unroll
    for (int bb = 0; bb < 4; bb++) {
      int b = 4 * bq + bb;
      float4 w_s = *(const float4*)(ws + b * 32 + 4 * fq);
      float4 w_v = *(const float4*)(wv + b * 32 + 4 * fq);
      float wsx[4] = {w_s.x, w_s.y, w_s.z, w_s.w};
      float wvx[4] = {w_v.x, w_v.y, w_v.z, w_v.w};
#pragma unroll
      for (int k = 0; k < 4; k++) {
        acc[k][0] += xsv[bb] * wsx[k];
        acc[k][1] += vv[bb][0] * wvx[k];
        acc[k][2] += vv[bb][1] * wvx[k];
        acc[k][3] += vv[bb][2] * wvx[k];
      }
    }
  }
  const float sc = 0.088388347648318447f;  // 1/sqrt(128)
#pragma unroll
  for (int k = 0; k < 4; k++) {
    float4 o;
    o.x = acc[k][0] * sc; o.y = acc[k][1] * sc;
    o.z = acc[k][2] * sc; o.w = acc[k][3] * sc;
    hsv[(size_t)(b0 + n) * 32 + 4 * fq + k] = o;
  }
}

// ---------------- CSR build ----------------
__global__ __launch_bounds__(256) void k_count(const int* __restrict__ idx_i,
        int* __restrict__ cnt, int* __restrict__ pos) {
  int e = blockIdx.x * 256 + threadIdx.x;
  pos[e] = atomicAdd(cnt + idx_i[e], 1);
}

__global__ __launch_bounds__(256) void k_scan(const int* __restrict__ cnt,
        int* __restrict__ offs) {
  __shared__ int part[256];
  int t = threadIdx.x;
  int s = 0;
  for (int i = t * 64; i < t * 64 + 64; ++i) s += cnt[i];
  part[t] = s;
  __syncthreads();
  if (t == 0) {
    int run = 0;
    for (int i = 0; i < 256; i++) { int v = part[i]; part[i] = run; run += v; }
    offs[NN] = run;
  }
  __syncthreads();
  int run = part[t];
  for (int i = t * 64; i < t * 64 + 64; ++i) { offs[i] = run; run += cnt[i]; }
}

// permutes idx_j, Yr, rcut into CSR order so k_agg2 streams them sequentially
__global__ __launch_bounds__(256) void k_fill(const int* __restrict__ idx_i,
        const int* __restrict__ idx_j, const float* __restrict__ Yr,
        const float* __restrict__ rcut,
        const int* __restrict__ pos, const int* __restrict__ offs,
        int* __restrict__ elist, int* __restrict__ idxj_csr,
        float4* __restrict__ Yr_csr, float* __restrict__ rcut_csr) {
  int e = blockIdx.x * 256 + threadIdx.x;
  int slot = offs[idx_i[e]] + pos[e];
  elist[slot] = e;
  idxj_csr[slot] = idx_j[e];
  Yr_csr[slot] = *(const float4*)(Yr + (size_t)e * 4);
  rcut_csr[slot] = rcut[e];
}

// ---------------- fused vector output weight: Wv = w1v @ w2v * 1/sqrt(64*128) ----------------
__global__ __launch_bounds__(256) void k_wv(const float* __restrict__ w1v,
        const float* __restrict__ w2v, float* __restrict__ Wv) {
  int o = blockIdx.x * 256 + threadIdx.x;   // 8192
  int m = o >> 7, d = o & 127;
  float s = 0.f;
  for (int b = 0; b < 128; b++) s += w1v[m * 128 + b] * w2v[b * 128 + d];
  Wv[o] = s * 0.011048543456039804f;
}

// ---------------- k_h: per-edge filter first layer, EDGE order (coalesced) ----------------
__global__ __launch_bounds__(256) void k_h(const float* __restrict__ fij,
        const float* __restrict__ W1, const float* __restrict__ b1,
        float* __restrict__ hout) {
  __shared__ float sfij[20 * 256];   // [r][edge_local]
  __shared__ float sW1[640];
  __shared__ float sb1[32];
  int t = threadIdx.x;
  int e0 = blockIdx.x * 256;
  for (int i = t; i < 5120; i += 256) {
    float v = fij[(size_t)e0 * 20 + i];
    int el = i / 20, r = i - el * 20;
    sfij[r * 256 + el] = v;
  }
  for (int i = t; i < 640; i += 256) sW1[i] = W1[i];
  if (t < 32) sb1[t] = b1[t];
  __syncthreads();
  int fq = t & 3, el = t >> 2;   // el 0..63 (4 edges each), fq 0..3 (8 fp each)
  int fp0 = fq * 8;
  float acc[4][8];
#pragma unroll
  for (int j = 0; j < 4; j++)
#pragma unroll
    for (int i = 0; i < 8; i++) acc[j][i] = sb1[fp0 + i];
#pragma unroll
  for (int r = 0; r < 20; r++) {
    float4 fe4 = *(const float4*)(sfij + r * 256 + el * 4);
    float fe[4] = {fe4.x, fe4.y, fe4.z, fe4.w};
    float4 wA = *(const float4*)(sW1 + r * 32 + fp0);
    float4 wB = *(const float4*)(sW1 + r * 32 + fp0 + 4);
    float w[8] = {wA.x, wA.y, wA.z, wA.w, wB.x, wB.y, wB.z, wB.w};
#pragma unroll
    for (int j = 0; j < 4; j++)
#pragma unroll
      for (int i = 0; i < 8; i++) acc[j][i] += fe[j] * w[i];
  }
#pragma unroll
  for (int j = 0; j < 4; j++) {
    float4 o1, o2;
    o1.x = sspf(acc[j][0]); o1.y = sspf(acc[j][1]);
    o1.z = sspf(acc[j][2]); o1.w = sspf(acc[j][3]);
    o2.x = sspf(acc[j][4]); o2.y = sspf(acc[j][5]);
    o2.z = sspf(acc[j][6]); o2.w = sspf(acc[j][7]);
    size_t base = ((size_t)(e0 + el * 4 + j)) * 32 + fp0;
    *(float4*)(hout + base) = o1;
    *(float4*)(hout + base + 4) = o2;
  }
}

// ---------------- k_agg2: fused W2-GEMV + geometry + aggregation ----------------
// Wave-PAIR per node; lane owns ONE compact col c = hw*64+l (f=c>>2, k=c&3,
// W2 col 6f+k), 32 pinned weights (R4-proven). Streams elist/idxj/Yr/rcut in
// CSR order; h row read via 8 uniform float4 loads; hsv prefetched depth-2.
__global__ __launch_bounds__(256, 4) void k_agg2(
        const float* __restrict__ h, const int* __restrict__ elist,
        const int* __restrict__ idxj_csr, const float4* __restrict__ Yr_csr,
        const float* __restrict__ rcut_csr, const float4* __restrict__ hsv,
        const float* __restrict__ W2, const float* __restrict__ b2,
        const int* __restrict__ offs, float* __restrict__ nagg) {
  int t = threadIdx.x;
  int w = t >> 6, l = t & 63;
  int pair = w >> 1, hw = w & 1;
  int n = blockIdx.x * 2 + pair;       // 8192 blocks
  int c = hw * 64 + l;                 // compact col 0..127
  int f = c >> 2, k = c & 3;
  int col = 6 * f + k;
  float wreg[32];
#pragma unroll
  for (int p = 0; p < 32; p++) wreg[p] = W2[p * 192 + col];
#pragma unroll
  for (int p = 0; p < 32; p++) PIN(wreg[p]);
  float bcol = b2[col];
  int start = offs[n], end = offs[n + 1];
  float a0 = 0.f, a1 = 0.f, a2 = 0.f;
  bool k2 = (k == 2);
  if (start < end) {
    int last = end - 1;
    int i1 = start + 1 < last ? start + 1 : last;
    int j0 = idxj_csr[start];
    int j1 = idxj_csr[i1];
    float4 sv0 = hsv[(size_t)j0 * 32 + f];
    float4 sv1 = hsv[(size_t)j1 * 32 + f];
    float4 y0 = Yr_csr[start];
    float rc0 = rcut_csr[start];
    int e0 = elist[start];
    for (int ei = start; ei < end; ++ei) {
      int in1 = ei + 1 < last ? ei + 1 : last;
      int in2 = ei + 2 < last ? ei + 2 : last;
      int j2 = idxj_csr[in2];
      float4 sv2 = hsv[(size_t)j2 * 32 + f];   // depth-2 random prefetch
      float4 y1 = Yr_csr[in1];
      float rc1 = rcut_csr[in1];
      int e1 = elist[in1];
      // GEMV: h row (uniform 8x float4) . wreg
      const float4* hp = (const float4*)(h + (size_t)e0 * 32);
      float d = 0.f;
#pragma unroll
      for (int q = 0; q < 8; q++) {
        float4 h4 = hp[q];
        d += h4.x * wreg[4 * q] + h4.y * wreg[4 * q + 1]
           + h4.z * wreg[4 * q + 2] + h4.w * wreg[4 * q + 3];
      }
      float W = (d + bcol) * rc0;
      float ys = y0.x, yx = y0.y, yy = y0.z, yz = y0.w;
      float ss = sv0.x, vx = sv0.y, vy = sv0.z, vz = sv0.w;
      float dv = (vx * yx + vy * yy + vz * yz) * 0.57735026918962576f; // IS3
      float m0 = (k == 0) ? ss * ys : (k == 1) ? dv : k2 ? ss * yx : vx * ys;
      float m1 = k2 ? ss * yy : vy * ys;
      float m2 = k2 ? ss * yz : vz * ys;
      a0 += m0 * W; a1 += m1 * W; a2 += m2 * W;
      y0 = y1; rc0 = rc1; e0 = e1; sv0 = sv1; sv1 = sv2;
    }
  }
  float* na = nagg + (size_t)n * 256;
  if (k == 0)      na[f] = a0;                         // ch0 -> s_in[0:32]
  else if (k == 1) na[32 + f] = a0;                    // ch1 -> s_in[32:64]
  else if (k2) {                                       // t_v1 -> v_in m=f
    na[64 + 3 * f + 0] = a0; na[64 + 3 * f + 1] = a1; na[64 + 3 * f + 2] = a2;
  } else {                                             // t_v2 -> v_in m=32+f
    na[160 + 3 * f + 0] = a0; na[160 + 3 * f + 1] = a1; na[160 + 3 * f + 2] = a2;
  }
}

// ---------------- output GEMMs: W in LDS [k][d], A in register tiles ----------------
__global__ __launch_bounds__(256) void k_os1(const float* __restrict__ na,
        const float* __restrict__ w1s, float* __restrict__ os1) {
  __shared__ float sw[8192];       // w1s [64][128]
  int t = threadIdx.x;
  for (int i = t; i < 8192; i += 256) sw[i] = w1s[i];
  __syncthreads();
  int dg = t & 31, ng = t >> 5;
  int d0 = dg * 4;
  int n0 = blockIdx.x * 32 + ng * 4;      // grid 512
  const float* ap = na + (size_t)n0 * 256;
  float acc[4][4] = {};
#pragma unroll
  for (int kq = 0; kq < 16; kq++) {
    float4 a[4];
#pragma unroll
    for (int j = 0; j < 4; j++) a[j] = *(const float4*)(ap + j * 256 + 4 * kq);
    float4 w0 = *(const float4*)(sw + (4 * kq + 0) * 128 + d0);
    float4 w1 = *(const float4*)(sw + (4 * kq + 1) * 128 + d0);
    float4 w2 = *(const float4*)(sw + (4 * kq + 2) * 128 + d0);
    float4 w3 = *(const float4*)(sw + (4 * kq + 3) * 128 + d0);
#pragma unroll
    for (int j = 0; j < 4; j++) {
      acc[j][0] += a[j].x * w0.x + a[j].y * w1.x + a[j].z * w2.x + a[j].w * w3.x;
      acc[j][1] += a[j].x * w0.y + a[j].y * w1.y + a[j].z * w2.y + a[j].w * w3.y;
      acc[j][2] += a[j].x * w0.z + a[j].y * w1.z + a[j].z * w2.z + a[j].w * w3.z;
      acc[j][3] += a[j].x * w0.w + a[j].y * w1.w + a[j].z * w2.w + a[j].w * w3.w;
    }
  }
#pragma unroll
  for (int j = 0; j < 4; j++) {
    float4 o;
    o.x = sspf(acc[j][0] * 0.125f);   // 1/sqrt(64)
    o.y = sspf(acc[j][1] * 0.125f);
    o.z = sspf(acc[j][2] * 0.125f);
    o.w = sspf(acc[j][3] * 0.125f);
    *(float4*)(os1 + (size_t)(n0 + j) * 128 + d0) = o;
  }
}

__global__ __launch_bounds__(256) void k_os2(const float* __restrict__ os1,
        const float* __restrict__ w2s, float* __restrict__ out) {
  __shared__ float sw[16384];      // w2s [128][128] = 64 KB
  int t = threadIdx.x;
  for (int i = t; i < 16384; i += 256) sw[i] = w2s[i];
  __syncthreads();
  int dg = t & 31, ng = t >> 5;
  int d0 = dg * 4;
  int n0 = blockIdx.x * 32 + ng * 4;      // grid 512
  const float* ap = os1 + (size_t)n0 * 128;
  float acc[4][4] = {};
#pragma unroll
  for (int kq = 0; kq < 32; kq++) {
    float4 a[4];
#pragma unroll
    for (int j = 0; j < 4; j++) a[j] = *(const float4*)(ap + j * 128 + 4 * kq);
    float4 w0 = *(const float4*)(sw + (4 * kq + 0) * 128 + d0);
    float4 w1 = *(const float4*)(sw + (4 * kq + 1) * 128 + d0);
    float4 w2 = *(const float4*)(sw + (4 * kq + 2) * 128 + d0);
    float4 w3 = *(const float4*)(sw + (4 * kq + 3) * 128 + d0);
#pragma unroll
    for (int j = 0; j < 4; j++) {
      acc[j][0] += a[j].x * w0.x + a[j].y * w1.x + a[j].z * w2.x + a[j].w * w3.x;
      acc[j][1] += a[j].x * w0.y + a[j].y * w1.y + a[j].z * w2.y + a[j].w * w3.y;
      acc[j][2] += a[j].x * w0.z + a[j].y * w1.z + a[j].z * w2.z + a[j].w * w3.z;
      acc[j][3] += a[j].x * w0.w + a[j].y * w1.w + a[j].z * w2.w + a[j].w * w3.w;
    }
  }
  const float sc = 0.088388347648318447f;   // 1/sqrt(128)
#pragma unroll
  for (int j = 0; j < 4; j++) {
    float4 o;
    o.x = acc[j][0] * sc; o.y = acc[j][1] * sc;
    o.z = acc[j][2] * sc; o.w = acc[j][3] * sc;
    *(float4*)(out + (size_t)(n0 + j) * 512 + d0) = o;
  }
}

// thread = 2 nodes x 4 d x 3 comps
__global__ __launch_bounds__(256) void k_ov(const float* __restrict__ na,
        const float* __restrict__ Wv, float* __restrict__ out) {
  __shared__ float sw[8192];       // Wv [64][128]
  int t = threadIdx.x;
  for (int i = t; i < 8192; i += 256) sw[i] = Wv[i];
  __syncthreads();
  int dg = t & 31, ng = t >> 5;
  int d0 = dg * 4;
  int n0 = blockIdx.x * 16 + ng * 2;      // grid 1024
  const float* ap = na + (size_t)n0 * 256 + 64;   // v_in row: 192 contiguous
  float acc[2][12] = {};
#pragma unroll
  for (int mq = 0; mq < 16; mq++) {
    float4 p[2][3];
#pragma unroll
    for (int j = 0; j < 2; j++) {
      p[j][0] = *(const float4*)(ap + j * 256 + 12 * mq);
      p[j][1] = *(const float4*)(ap + j * 256 + 12 * mq + 4);
      p[j][2] = *(const float4*)(ap + j * 256 + 12 * mq + 8);
    }
    float4 w0 = *(const float4*)(sw + (4 * mq + 0) * 128 + d0);
    float4 w1 = *(const float4*)(sw + (4 * mq + 1) * 128 + d0);
    float4 w2 = *(const float4*)(sw + (4 * mq + 2) * 128 + d0);
    float4 w3 = *(const float4*)(sw + (4 * mq + 3) * 128 + d0);
#pragma unroll
    for (int j = 0; j < 2; j++) {
      float vm[4][3];
      vm[0][0] = p[j][0].x; vm[0][1] = p[j][0].y; vm[0][2] = p[j][0].z;
      vm[1][0] = p[j][0].w; vm[1][1] = p[j][1].x; vm[1][2] = p[j][1].y;
      vm[2][0] = p[j][1].z; vm[2][1] = p[j][1].w; vm[2][2] = p[j][2].x;
      vm[3][0] = p[j][2].y; vm[3][1] = p[j][2].z; vm[3][2] = p[j][2].w;
      float wm[4][4];
      wm[0][0] = w0.x; wm[0][1] = w0.y; wm[0][2] = w0.z; wm[0][3] = w0.w;
      wm[1][0] = w1.x; wm[1][1] = w1.y; wm[1][2] = w1.z; wm[1][3] = w1.w;
      wm[2][0] = w2.x; wm[2][1] = w2.y; wm[2][2] = w2.z; wm[2][3] = w2.w;
      wm[3][0] = w3.x; wm[3][1] = w3.y; wm[3][2] = w3.z; wm[3][3] = w3.w;
#pragma unroll
      for (int m = 0; m < 4; m++)
#pragma unroll
        for (int i = 0; i < 4; i++)
#pragma unroll
          for (int c = 0; c < 3; c++)
            acc[j][i * 3 + c] += vm[m][c] * wm[m][i];
    }
  }
#pragma unroll
  for (int j = 0; j < 2; j++) {
    float* op = out + (size_t)(n0 + j) * 512 + 128 + 12 * dg;
    float4 o0, o1, o2;
    o0.x = acc[j][0]; o0.y = acc[j][1]; o0.z = acc[j][2]; o0.w = acc[j][3];
    o1.x = acc[j][4]; o1.y = acc[j][5]; o1.z = acc[j][6]; o1.w = acc[j][7];
    o2.x = acc[j][8]; o2.y = acc[j][9]; o2.z = acc[j][10]; o2.w = acc[j][11];
    *(float4*)op = o0;
    *(float4*)(op + 4) = o1;
    *(float4*)(op + 8) = o2;
  }
}

extern "C" void kernel_launch(void* const* d_in, const int* in_sizes, int n_in,
                              void* d_out, int out_size, void* d_ws, size_t ws_size,
                              hipStream_t stream) {
  const float* x    = (const float*)d_in[0];
  const int*   idx_i = (const int*)d_in[1];
  const int*   idx_j = (const int*)d_in[2];
  const float* fij  = (const float*)d_in[3];
  const float* rcut = (const float*)d_in[4];
  const float* Yr   = (const float*)d_in[5];
  const float* w_s  = (const float*)d_in[6];
  const float* w_v  = (const float*)d_in[7];
  const float* W1   = (const float*)d_in[8];
  const float* b1   = (const float*)d_in[9];
  const float* W2   = (const float*)d_in[10];
  const float* b2   = (const float*)d_in[11];
  const float* w1s  = (const float*)d_in[12];
  const float* w1v  = (const float*)d_in[13];
  const float* w2s  = (const float*)d_in[14];
  const float* w2v  = (const float*)d_in[15];
  float* out = (float*)d_out;

  char* ws = (char*)d_ws;
  size_t off = 0;
  auto alloc = [&](size_t bytes) {
    void* p = ws + off;
    off += (bytes + 255) & ~(size_t)255;
    return p;
  };
  float4* hsv   = (float4*)alloc((size_t)NN * 32 * 16);
  float*  nagg  = (float*)alloc((size_t)NN * 256 * 4);
  float*  hbuf  = (float*)alloc((size_t)EE * 32 * 4);   // 33.5 MB
  float*  os1   = (float*)alloc((size_t)NN * 128 * 4);
  float4* Yr_csr = (float4*)alloc((size_t)EE * 16);
  int* idxj_csr = (int*)alloc((size_t)EE * 4);
  float* rcut_csr = (float*)alloc((size_t)EE * 4);
  float* Wv     = (float*)alloc((size_t)8192 * 4);
  int* cnt      = (int*)alloc((size_t)NN * 4);
  int* offs     = (int*)alloc((size_t)(NN + 1) * 4);
  int* pos      = (int*)alloc((size_t)EE * 4);
  int* elist    = (int*)alloc((size_t)EE * 4);

  hipMemsetAsync(cnt, 0, (size_t)NN * 4, stream);
  k_count<<<EE / 256, 256, 0, stream>>>(idx_i, cnt, pos);
  k_scan<<<1, 256, 0, stream>>>(cnt, offs);
  k_fill<<<EE / 256, 256, 0, stream>>>(idx_i, idx_j, Yr, rcut, pos, offs,
                                       elist, idxj_csr, Yr_csr, rcut_csr);
  k_embed<<<NN / 32, 256, 0, stream>>>(x, w_s, w_v, hsv);
  k_wv<<<32, 256, 0, stream>>>(w1v, w2v, Wv);
  k_h<<<EE / 256, 256, 0, stream>>>(fij, W1, b1, hbuf);
  k_agg2<<<NN / 2, 256, 0, stream>>>(hbuf, elist, idxj_csr, Yr_csr, rcut_csr,
                                     hsv, W2, b2, offs, nagg);
  k_os1<<<512, 256, 0, stream>>>(nagg, w1s, os1);
  k_os2<<<512, 256, 0, stream>>>(os1, w2s, out);
  k_ov<<<1024, 256, 0, stream>>>(nagg, Wv, out);
}

// Round 10
// 256.851 us; speedup vs baseline: 1.3621x; 1.3621x over previous
//
#include <hip/hip_runtime.h>
#include <math.h>

#define NN 16384
#define BB 128
#define FF 32
#define RR 20
#define EE 262144

__device__ __forceinline__ float sspf(float x) {
  // softplus(x) - log(2), numerically stable
  return fmaxf(x, 0.0f) + log1pf(expf(-fabsf(x))) - 0.69314718055994531f;
}

// ---------------- K1: node embeddings, x rows staged in LDS ----------------
__global__ __launch_bounds__(256) void k_embed(const float* __restrict__ x,
        const float* __restrict__ ws, const float* __restrict__ wv,
        float4* __restrict__ hsv) {
  __shared__ float sx[32 * 516];   // 66 KB
  int t = threadIdx.x;
  int b0 = blockIdx.x * 32;        // 512 blocks
  const float4* xg = (const float4*)(x + (size_t)b0 * 512);
  for (int i = t; i < 4096; i += 256) {
    int row = i >> 7, col = i & 127;
    *(float4*)(sx + row * 516 + col * 4) = xg[i];
  }
  __syncthreads();
  int n = t >> 3, fq = t & 7;
  const float* xr = sx + n * 516;
  float acc[4][4];
#pragma unroll
  for (int k = 0; k < 4; k++)
#pragma unroll
    for (int c = 0; c < 4; c++) acc[k][c] = 0.f;
  for (int bq = 0; bq < 32; bq++) {
    float4 xs4 = *(const float4*)(xr + 4 * bq);
    float4 a0 = *(const float4*)(xr + 128 + 12 * bq);
    float4 a1 = *(const float4*)(xr + 128 + 12 * bq + 4);
    float4 a2 = *(const float4*)(xr + 128 + 12 * bq + 8);
    float xsv[4] = {xs4.x, xs4.y, xs4.z, xs4.w};
    float vv[4][3];
    vv[0][0] = a0.x; vv[0][1] = a0.y; vv[0][2] = a0.z;
    vv[1][0] = a0.w; vv[1][1] = a1.x; vv[1][2] = a1.y;
    vv[2][0] = a1.z; vv[2][1] = a1.w; vv[2][2] = a2.x;
    vv[3][0] = a2.y; vv[3][1] = a2.z; vv[3][2] = a2.w;
#pragma unroll
    for (int bb = 0; bb < 4; bb++) {
      int b = 4 * bq + bb;
      float4 w_s = *(const float4*)(ws + b * 32 + 4 * fq);
      float4 w_v = *(const float4*)(wv + b * 32 + 4 * fq);
      float wsx[4] = {w_s.x, w_s.y, w_s.z, w_s.w};
      float wvx[4] = {w_v.x, w_v.y, w_v.z, w_v.w};
#pragma unroll
      for (int k = 0; k < 4; k++) {
        acc[k][0] += xsv[bb] * wsx[k];
        acc[k][1] += vv[bb][0] * wvx[k];
        acc[k][2] += vv[bb][1] * wvx[k];
        acc[k][3] += vv[bb][2] * wvx[k];
      }
    }
  }
  const float sc = 0.088388347648318447f;  // 1/sqrt(128)
#pragma unroll
  for (int k = 0; k < 4; k++) {
    float4 o;
    o.x = acc[k][0] * sc; o.y = acc[k][1] * sc;
    o.z = acc[k][2] * sc; o.w = acc[k][3] * sc;
    hsv[(size_t)(b0 + n) * 32 + 4 * fq + k] = o;
  }
}

// ---------------- CSR build ----------------
__global__ __launch_bounds__(256) void k_count(const int* __restrict__ idx_i,
        int* __restrict__ cnt, int* __restrict__ pos) {
  int e = blockIdx.x * 256 + threadIdx.x;
  pos[e] = atomicAdd(cnt + idx_i[e], 1);
}

__global__ __launch_bounds__(256) void k_scan(const int* __restrict__ cnt,
        int* __restrict__ offs) {
  __shared__ int part[256];
  int t = threadIdx.x;
  int s = 0;
  for (int i = t * 64; i < t * 64 + 64; ++i) s += cnt[i];
  part[t] = s;
  __syncthreads();
  if (t == 0) {
    int run = 0;
    for (int i = 0; i < 256; i++) { int v = part[i]; part[i] = run; run += v; }
    offs[NN] = run;
  }
  __syncthreads();
  int run = part[t];
  for (int i = t * 64; i < t * 64 + 64; ++i) { offs[i] = run; run += cnt[i]; }
}

// CSR permutation: merged {e, idx_j} stream + Yr stream
__global__ __launch_bounds__(256) void k_fill(const int* __restrict__ idx_i,
        const int* __restrict__ idx_j, const float* __restrict__ Yr,
        const int* __restrict__ pos, const int* __restrict__ offs,
        int2* __restrict__ ej_csr, float4* __restrict__ Yr_csr) {
  int e = blockIdx.x * 256 + threadIdx.x;
  int slot = offs[idx_i[e]] + pos[e];
  int2 ej; ej.x = e; ej.y = idx_j[e];
  ej_csr[slot] = ej;
  Yr_csr[slot] = *(const float4*)(Yr + (size_t)e * 4);
}

// ---------------- fused vector output weight: Wv = w1v @ w2v * 1/sqrt(64*128) ----------------
__global__ __launch_bounds__(256) void k_wv(const float* __restrict__ w1v,
        const float* __restrict__ w2v, float* __restrict__ Wv) {
  int o = blockIdx.x * 256 + threadIdx.x;   // 8192
  int m = o >> 7, d = o & 127;
  float s = 0.f;
  for (int b = 0; b < 128; b++) s += w1v[m * 128 + b] * w2v[b * 128 + d];
  Wv[o] = s * 0.011048543456039804f;
}

// ---------------- k_wab: EDGE-ORDER fused filter MLP ----------------
// 64-edge tiles; fij coalesced; h in LDS; Wab[e][c] = (h@W2c + b2c)*rcut[e].
// Compact col c <-> W2 col 6*(c>>2)+(c&3). Bias+rcut folded here.
__global__ __launch_bounds__(256) void k_wab(
        const float* __restrict__ fij, const float* __restrict__ rcut,
        const float* __restrict__ W1, const float* __restrict__ b1,
        const float* __restrict__ W2, const float* __restrict__ b2,
        float* __restrict__ Wab) {
  __shared__ float sW1[640];
  __shared__ float sb1[32];
  __shared__ float sW2c[4096];     // [p][128]
  __shared__ float sb2c[128];
  __shared__ float sfij[20 * 66];  // [r][el]
  __shared__ float sh[64 * 37];    // [el][fp]
  __shared__ float srct[64];
  int t = threadIdx.x;
  size_t e0 = (size_t)blockIdx.x * 64;   // 4096 blocks
  for (int i = t; i < 640; i += 256) sW1[i] = W1[i];
  if (t < 32) sb1[t] = b1[t];
  for (int i = t; i < 4096; i += 256) {
    int p = i >> 7, c = i & 127;
    sW2c[i] = W2[p * 192 + 6 * (c >> 2) + (c & 3)];
  }
  if (t < 128) sb2c[t] = b2[6 * (t >> 2) + (t & 3)];
  for (int i = t; i < 1280; i += 256) {
    int el = i / 20, r = i - el * 20;
    sfij[r * 66 + el] = fij[e0 * 20 + i];   // coalesced global read
  }
  if (t < 64) srct[t] = rcut[e0 + t];
  __syncthreads();
  {
    int el = t & 63, fp0 = (t >> 6) * 8;
    float acc[8];
#pragma unroll
    for (int i = 0; i < 8; i++) acc[i] = sb1[fp0 + i];
#pragma unroll
    for (int r = 0; r < 20; r++) {
      float fe = sfij[r * 66 + el];
      float4 wA = *(const float4*)(sW1 + r * 32 + fp0);
      float4 wB = *(const float4*)(sW1 + r * 32 + fp0 + 4);
      acc[0] += fe * wA.x; acc[1] += fe * wA.y;
      acc[2] += fe * wA.z; acc[3] += fe * wA.w;
      acc[4] += fe * wB.x; acc[5] += fe * wB.y;
      acc[6] += fe * wB.z; acc[7] += fe * wB.w;
    }
#pragma unroll
    for (int i = 0; i < 8; i++) sh[el * 37 + fp0 + i] = sspf(acc[i]);
  }
  __syncthreads();
  {
    int eq = t >> 4, cq = (t & 15) * 8;   // 4 edges x 8 cols per thread
    float acc[4][8];
#pragma unroll
    for (int j = 0; j < 4; j++)
#pragma unroll
      for (int i = 0; i < 8; i++) acc[j][i] = sb2c[cq + i];
#pragma unroll
    for (int p = 0; p < 32; p++) {
      float4 wA = *(const float4*)(sW2c + p * 128 + cq);
      float4 wB = *(const float4*)(sW2c + p * 128 + cq + 4);
      float w[8] = {wA.x, wA.y, wA.z, wA.w, wB.x, wB.y, wB.z, wB.w};
#pragma unroll
      for (int j = 0; j < 4; j++) {
        float hh = sh[(4 * eq + j) * 37 + p];
#pragma unroll
        for (int i = 0; i < 8; i++) acc[j][i] += hh * w[i];
      }
    }
#pragma unroll
    for (int j = 0; j < 4; j++) {
      float rc = srct[4 * eq + j];
      float* base = Wab + (e0 + 4 * eq + j) * 128 + cq;
      float4 o1, o2;
      o1.x = acc[j][0] * rc; o1.y = acc[j][1] * rc;
      o1.z = acc[j][2] * rc; o1.w = acc[j][3] * rc;
      o2.x = acc[j][4] * rc; o2.y = acc[j][5] * rc;
      o2.z = acc[j][6] * rc; o2.w = acc[j][7] * rc;
      *(float4*)base = o1;
      *(float4*)(base + 4) = o2;
    }
  }
}

// ---------------- k_agg3: one wave per node; all streams prefetched ----------------
// Lane l: f=l>>1, kb=(l&1)*2 -> cols {6f+kb, 6f+kb+1}; W from Wab2[e*64+l]
// (wave reads one contiguous 512B row). sv depth-2, W depth-2, y depth-1.
__global__ __launch_bounds__(256, 4) void k_agg3(
        const float2* __restrict__ Wab2, const int2* __restrict__ ej_csr,
        const float4* __restrict__ Yr_csr, const float4* __restrict__ hsv,
        const int* __restrict__ offs, float* __restrict__ nagg) {
  int t = threadIdx.x;
  int w = t >> 6, l = t & 63;
  int n = blockIdx.x * 4 + w;          // 4096 blocks
  int f = l >> 1, kb = (l & 1) * 2;
  int start = offs[n], end = offs[n + 1];
  float a0 = 0, a1 = 0, a2 = 0, a3 = 0, a4 = 0, a5 = 0;
  if (start < end) {
    int last = end - 1;
    int i1 = start + 1 < last ? start + 1 : last;
    int i2 = start + 2 < last ? start + 2 : last;
    int2 ej0 = ej_csr[start];
    int2 ej1 = ej_csr[i1];
    int2 ej2 = ej_csr[i2];
    float4 y0 = Yr_csr[start];
    float4 sv0 = hsv[(size_t)ej0.y * 32 + f];
    float4 sv1 = hsv[(size_t)ej1.y * 32 + f];
    float2 W0 = Wab2[(size_t)ej0.x * 64 + l];
    float2 W1 = Wab2[(size_t)ej1.x * 64 + l];
    for (int ei = start; ei < end; ++ei) {
      int in1 = ei + 1 < last ? ei + 1 : last;
      int in3 = ei + 3 < last ? ei + 3 : last;
      float4 sv2 = hsv[(size_t)ej2.y * 32 + f];   // depth-2
      float2 W2r = Wab2[(size_t)ej2.x * 64 + l];  // depth-2
      float4 y1 = Yr_csr[in1];                    // depth-1
      int2 ej3 = ej_csr[in3];                     // depth-3
      float ys = y0.x, yx = y0.y, yy = y0.z, yz = y0.w;
      float ss = sv0.x, vx = sv0.y, vy = sv0.z, vz = sv0.w;
      if (kb == 0) {
        a0 += ss * ys * W0.x;                                          // ch0
        a1 += (vx * yx + vy * yy + vz * yz) * 0.57735026918962576f * W0.y; // ch1
      } else {
        a0 += ss * yx * W0.x; a1 += ss * yy * W0.x; a2 += ss * yz * W0.x; // t_v1
        a3 += vx * ys * W0.y; a4 += vy * ys * W0.y; a5 += vz * ys * W0.y; // t_v2
      }
      y0 = y1; sv0 = sv1; sv1 = sv2; W0 = W1; W1 = W2r; ej2 = ej3;
    }
  }
  float* na = nagg + (size_t)n * 256;
  if (kb == 0) {
    na[f] = a0;
    na[32 + f] = a1;
  } else {
    na[64 + 3 * f + 0] = a0;  na[64 + 3 * f + 1] = a1;  na[64 + 3 * f + 2] = a2;
    na[160 + 3 * f + 0] = a3; na[160 + 3 * f + 1] = a4; na[160 + 3 * f + 2] = a5;
  }
}

// ---------------- output GEMMs: W in LDS [k][d], A in register tiles ----------------
__global__ __launch_bounds__(256) void k_os1(const float* __restrict__ na,
        const float* __restrict__ w1s, float* __restrict__ os1) {
  __shared__ float sw[8192];       // w1s [64][128]
  int t = threadIdx.x;
  for (int i = t; i < 8192; i += 256) sw[i] = w1s[i];
  __syncthreads();
  int dg = t & 31, ng = t >> 5;
  int d0 = dg * 4;
  int n0 = blockIdx.x * 32 + ng * 4;      // grid 512
  const float* ap = na + (size_t)n0 * 256;
  float acc[4][4] = {};
#pragma unroll
  for (int kq = 0; kq < 16; kq++) {
    float4 a[4];
#pragma unroll
    for (int j = 0; j < 4; j++) a[j] = *(const float4*)(ap + j * 256 + 4 * kq);
    float4 w0 = *(const float4*)(sw + (4 * kq + 0) * 128 + d0);
    float4 w1 = *(const float4*)(sw + (4 * kq + 1) * 128 + d0);
    float4 w2 = *(const float4*)(sw + (4 * kq + 2) * 128 + d0);
    float4 w3 = *(const float4*)(sw + (4 * kq + 3) * 128 + d0);
#pragma unroll
    for (int j = 0; j < 4; j++) {
      acc[j][0] += a[j].x * w0.x + a[j].y * w1.x + a[j].z * w2.x + a[j].w * w3.x;
      acc[j][1] += a[j].x * w0.y + a[j].y * w1.y + a[j].z * w2.y + a[j].w * w3.y;
      acc[j][2] += a[j].x * w0.z + a[j].y * w1.z + a[j].z * w2.z + a[j].w * w3.z;
      acc[j][3] += a[j].x * w0.w + a[j].y * w1.w + a[j].z * w2.w + a[j].w * w3.w;
    }
  }
#pragma unroll
  for (int j = 0; j < 4; j++) {
    float4 o;
    o.x = sspf(acc[j][0] * 0.125f);   // 1/sqrt(64)
    o.y = sspf(acc[j][1] * 0.125f);
    o.z = sspf(acc[j][2] * 0.125f);
    o.w = sspf(acc[j][3] * 0.125f);
    *(float4*)(os1 + (size_t)(n0 + j) * 128 + d0) = o;
  }
}

__global__ __launch_bounds__(256) void k_os2(const float* __restrict__ os1,
        const float* __restrict__ w2s, float* __restrict__ out) {
  __shared__ float sw[16384];      // w2s [128][128] = 64 KB
  int t = threadIdx.x;
  for (int i = t; i < 16384; i += 256) sw[i] = w2s[i];
  __syncthreads();
  int dg = t & 31, ng = t >> 5;
  int d0 = dg * 4;
  int n0 = blockIdx.x * 32 + ng * 4;      // grid 512
  const float* ap = os1 + (size_t)n0 * 128;
  float acc[4][4] = {};
#pragma unroll
  for (int kq = 0; kq < 32; kq++) {
    float4 a[4];
#pragma unroll
    for (int j = 0; j < 4; j++) a[j] = *(const float4*)(ap + j * 128 + 4 * kq);
    float4 w0 = *(const float4*)(sw + (4 * kq + 0) * 128 + d0);
    float4 w1 = *(const float4*)(sw + (4 * kq + 1) * 128 + d0);
    float4 w2 = *(const float4*)(sw + (4 * kq + 2) * 128 + d0);
    float4 w3 = *(const float4*)(sw + (4 * kq + 3) * 128 + d0);
#pragma unroll
    for (int j = 0; j < 4; j++) {
      acc[j][0] += a[j].x * w0.x + a[j].y * w1.x + a[j].z * w2.x + a[j].w * w3.x;
      acc[j][1] += a[j].x * w0.y + a[j].y * w1.y + a[j].z * w2.y + a[j].w * w3.y;
      acc[j][2] += a[j].x * w0.z + a[j].y * w1.z + a[j].z * w2.z + a[j].w * w3.z;
      acc[j][3] += a[j].x * w0.w + a[j].y * w1.w + a[j].z * w2.w + a[j].w * w3.w;
    }
  }
  const float sc = 0.088388347648318447f;   // 1/sqrt(128)
#pragma unroll
  for (int j = 0; j < 4; j++) {
    float4 o;
    o.x = acc[j][0] * sc; o.y = acc[j][1] * sc;
    o.z = acc[j][2] * sc; o.w = acc[j][3] * sc;
    *(float4*)(out + (size_t)(n0 + j) * 512 + d0) = o;
  }
}

// thread = 2 nodes x 4 d x 3 comps
__global__ __launch_bounds__(256) void k_ov(const float* __restrict__ na,
        const float* __restrict__ Wv, float* __restrict__ out) {
  __shared__ float sw[8192];       // Wv [64][128]
  int t = threadIdx.x;
  for (int i = t; i < 8192; i += 256) sw[i] = Wv[i];
  __syncthreads();
  int dg = t & 31, ng = t >> 5;
  int d0 = dg * 4;
  int n0 = blockIdx.x * 16 + ng * 2;      // grid 1024
  const float* ap = na + (size_t)n0 * 256 + 64;   // v_in row: 192 contiguous
  float acc[2][12] = {};
#pragma unroll
  for (int mq = 0; mq < 16; mq++) {
    float4 p[2][3];
#pragma unroll
    for (int j = 0; j < 2; j++) {
      p[j][0] = *(const float4*)(ap + j * 256 + 12 * mq);
      p[j][1] = *(const float4*)(ap + j * 256 + 12 * mq + 4);
      p[j][2] = *(const float4*)(ap + j * 256 + 12 * mq + 8);
    }
    float4 w0 = *(const float4*)(sw + (4 * mq + 0) * 128 + d0);
    float4 w1 = *(const float4*)(sw + (4 * mq + 1) * 128 + d0);
    float4 w2 = *(const float4*)(sw + (4 * mq + 2) * 128 + d0);
    float4 w3 = *(const float4*)(sw + (4 * mq + 3) * 128 + d0);
#pragma unroll
    for (int j = 0; j < 2; j++) {
      float vm[4][3];
      vm[0][0] = p[j][0].x; vm[0][1] = p[j][0].y; vm[0][2] = p[j][0].z;
      vm[1][0] = p[j][0].w; vm[1][1] = p[j][1].x; vm[1][2] = p[j][1].y;
      vm[2][0] = p[j][1].z; vm[2][1] = p[j][1].w; vm[2][2] = p[j][2].x;
      vm[3][0] = p[j][2].y; vm[3][1] = p[j][2].z; vm[3][2] = p[j][2].w;
      float wm[4][4];
      wm[0][0] = w0.x; wm[0][1] = w0.y; wm[0][2] = w0.z; wm[0][3] = w0.w;
      wm[1][0] = w1.x; wm[1][1] = w1.y; wm[1][2] = w1.z; wm[1][3] = w1.w;
      wm[2][0] = w2.x; wm[2][1] = w2.y; wm[2][2] = w2.z; wm[2][3] = w2.w;
      wm[3][0] = w3.x; wm[3][1] = w3.y; wm[3][2] = w3.z; wm[3][3] = w3.w;
#pragma unroll
      for (int m = 0; m < 4; m++)
#pragma unroll
        for (int i = 0; i < 4; i++)
#pragma unroll
          for (int c = 0; c < 3; c++)
            acc[j][i * 3 + c] += vm[m][c] * wm[m][i];
    }
  }
#pragma unroll
  for (int j = 0; j < 2; j++) {
    float* op = out + (size_t)(n0 + j) * 512 + 128 + 12 * dg;
    float4 o0, o1, o2;
    o0.x = acc[j][0]; o0.y = acc[j][1]; o0.z = acc[j][2]; o0.w = acc[j][3];
    o1.x = acc[j][4]; o1.y = acc[j][5]; o1.z = acc[j][6]; o1.w = acc[j][7];
    o2.x = acc[j][8]; o2.y = acc[j][9]; o2.z = acc[j][10]; o2.w = acc[j][11];
    *(float4*)op = o0;
    *(float4*)(op + 4) = o1;
    *(float4*)(op + 8) = o2;
  }
}

extern "C" void kernel_launch(void* const* d_in, const int* in_sizes, int n_in,
                              void* d_out, int out_size, void* d_ws, size_t ws_size,
                              hipStream_t stream) {
  const float* x    = (const float*)d_in[0];
  const int*   idx_i = (const int*)d_in[1];
  const int*   idx_j = (const int*)d_in[2];
  const float* fij  = (const float*)d_in[3];
  const float* rcut = (const float*)d_in[4];
  const float* Yr   = (const float*)d_in[5];
  const float* w_s  = (const float*)d_in[6];
  const float* w_v  = (const float*)d_in[7];
  const float* W1   = (const float*)d_in[8];
  const float* b1   = (const float*)d_in[9];
  const float* W2   = (const float*)d_in[10];
  const float* b2   = (const float*)d_in[11];
  const float* w1s  = (const float*)d_in[12];
  const float* w1v  = (const float*)d_in[13];
  const float* w2s  = (const float*)d_in[14];
  const float* w2v  = (const float*)d_in[15];
  float* out = (float*)d_out;

  char* ws = (char*)d_ws;
  size_t off = 0;
  auto alloc = [&](size_t bytes) {
    void* p = ws + off;
    off += (bytes + 255) & ~(size_t)255;
    return p;
  };
  float4* hsv   = (float4*)alloc((size_t)NN * 32 * 16);
  float*  nagg  = (float*)alloc((size_t)NN * 256 * 4);
  float*  Wab   = (float*)alloc((size_t)EE * 128 * 4);    // 134 MB
  float*  os1   = (float*)alloc((size_t)NN * 128 * 4);
  float4* Yr_csr = (float4*)alloc((size_t)EE * 16);
  int2*  ej_csr = (int2*)alloc((size_t)EE * 8);
  float* Wv     = (float*)alloc((size_t)8192 * 4);
  int* cnt      = (int*)alloc((size_t)NN * 4);
  int* offs     = (int*)alloc((size_t)(NN + 1) * 4);
  int* pos      = (int*)alloc((size_t)EE * 4);

  hipMemsetAsync(cnt, 0, (size_t)NN * 4, stream);
  k_count<<<EE / 256, 256, 0, stream>>>(idx_i, cnt, pos);
  k_scan<<<1, 256, 0, stream>>>(cnt, offs);
  k_fill<<<EE / 256, 256, 0, stream>>>(idx_i, idx_j, Yr, pos, offs,
                                       ej_csr, Yr_csr);
  k_embed<<<NN / 32, 256, 0, stream>>>(x, w_s, w_v, hsv);
  k_wv<<<32, 256, 0, stream>>>(w1v, w2v, Wv);
  k_wab<<<EE / 64, 256, 0, stream>>>(fij, rcut, W1, b1, W2, b2, Wab);
  k_agg3<<<NN / 4, 256, 0, stream>>>((const float2*)Wab, ej_csr, Yr_csr,
                                     hsv, offs, nagg);
  k_os1<<<512, 256, 0, stream>>>(nagg, w1s, os1);
  k_os2<<<512, 256, 0, stream>>>(os1, w2s, out);
  k_ov<<<1024, 256, 0, stream>>>(nagg, Wv, out);
}

// Round 11
// 249.399 us; speedup vs baseline: 1.4028x; 1.0299x over previous
//
#include <hip/hip_runtime.h>
#include <math.h>

#define NN 16384
#define BB 128
#define FF 32
#define RR 20
#define EE 262144

__device__ __forceinline__ float sspf(float x) {
  // softplus(x) - log(2), numerically stable
  return fmaxf(x, 0.0f) + log1pf(expf(-fabsf(x))) - 0.69314718055994531f;
}

// ---------------- K1: node embeddings, x rows staged in LDS ----------------
__global__ __launch_bounds__(256) void k_embed(const float* __restrict__ x,
        const float* __restrict__ ws, const float* __restrict__ wv,
        float4* __restrict__ hsv) {
  __shared__ float sx[32 * 516];   // 66 KB
  int t = threadIdx.x;
  int b0 = blockIdx.x * 32;        // 512 blocks
  const float4* xg = (const float4*)(x + (size_t)b0 * 512);
  for (int i = t; i < 4096; i += 256) {
    int row = i >> 7, col = i & 127;
    *(float4*)(sx + row * 516 + col * 4) = xg[i];
  }
  __syncthreads();
  int n = t >> 3, fq = t & 7;
  const float* xr = sx + n * 516;
  float acc[4][4];
#pragma unroll
  for (int k = 0; k < 4; k++)
#pragma unroll
    for (int c = 0; c < 4; c++) acc[k][c] = 0.f;
  for (int bq = 0; bq < 32; bq++) {
    float4 xs4 = *(const float4*)(xr + 4 * bq);
    float4 a0 = *(const float4*)(xr + 128 + 12 * bq);
    float4 a1 = *(const float4*)(xr + 128 + 12 * bq + 4);
    float4 a2 = *(const float4*)(xr + 128 + 12 * bq + 8);
    float xsv[4] = {xs4.x, xs4.y, xs4.z, xs4.w};
    float vv[4][3];
    vv[0][0] = a0.x; vv[0][1] = a0.y; vv[0][2] = a0.z;
    vv[1][0] = a0.w; vv[1][1] = a1.x; vv[1][2] = a1.y;
    vv[2][0] = a1.z; vv[2][1] = a1.w; vv[2][2] = a2.x;
    vv[3][0] = a2.y; vv[3][1] = a2.z; vv[3][2] = a2.w;
#pragma unroll
    for (int bb = 0; bb < 4; bb++) {
      int b = 4 * bq + bb;
      float4 w_s = *(const float4*)(ws + b * 32 + 4 * fq);
      float4 w_v = *(const float4*)(wv + b * 32 + 4 * fq);
      float wsx[4] = {w_s.x, w_s.y, w_s.z, w_s.w};
      float wvx[4] = {w_v.x, w_v.y, w_v.z, w_v.w};
#pragma unroll
      for (int k = 0; k < 4; k++) {
        acc[k][0] += xsv[bb] * wsx[k];
        acc[k][1] += vv[bb][0] * wvx[k];
        acc[k][2] += vv[bb][1] * wvx[k];
        acc[k][3] += vv[bb][2] * wvx[k];
      }
    }
  }
  const float sc = 0.088388347648318447f;  // 1/sqrt(128)
#pragma unroll
  for (int k = 0; k < 4; k++) {
    float4 o;
    o.x = acc[k][0] * sc; o.y = acc[k][1] * sc;
    o.z = acc[k][2] * sc; o.w = acc[k][3] * sc;
    hsv[(size_t)(b0 + n) * 32 + 4 * fq + k] = o;
  }
}

// ---------------- CSR build ----------------
__global__ __launch_bounds__(256) void k_count(const int* __restrict__ idx_i,
        int* __restrict__ cnt, int* __restrict__ pos) {
  int e = blockIdx.x * 256 + threadIdx.x;
  pos[e] = atomicAdd(cnt + idx_i[e], 1);
}

__global__ __launch_bounds__(256) void k_scan(const int* __restrict__ cnt,
        int* __restrict__ offs) {
  __shared__ int part[256];
  int t = threadIdx.x;
  int s = 0;
  for (int i = t * 64; i < t * 64 + 64; ++i) s += cnt[i];
  part[t] = s;
  __syncthreads();
  if (t == 0) {
    int run = 0;
    for (int i = 0; i < 256; i++) { int v = part[i]; part[i] = run; run += v; }
    offs[NN] = run;
  }
  __syncthreads();
  int run = part[t];
  for (int i = t * 64; i < t * 64 + 64; ++i) { offs[i] = run; run += cnt[i]; }
}

// CSR permutation: slot_of_e (for wab scatter-write) + idx_j/Yr slot streams
__global__ __launch_bounds__(256) void k_fill(const int* __restrict__ idx_i,
        const int* __restrict__ idx_j, const float* __restrict__ Yr,
        const int* __restrict__ pos, const int* __restrict__ offs,
        int* __restrict__ slot_of_e, int* __restrict__ idxj_csr,
        float4* __restrict__ Yr_csr) {
  int e = blockIdx.x * 256 + threadIdx.x;
  int slot = offs[idx_i[e]] + pos[e];
  slot_of_e[e] = slot;
  idxj_csr[slot] = idx_j[e];
  Yr_csr[slot] = *(const float4*)(Yr + (size_t)e * 4);
}

// ---------------- fused vector output weight: Wv = w1v @ w2v * 1/sqrt(64*128) ----------------
__global__ __launch_bounds__(256) void k_wv(const float* __restrict__ w1v,
        const float* __restrict__ w2v, float* __restrict__ Wv) {
  int o = blockIdx.x * 256 + threadIdx.x;   // 8192
  int m = o >> 7, d = o & 127;
  float s = 0.f;
  for (int b = 0; b < 128; b++) s += w1v[m * 128 + b] * w2v[b * 128 + d];
  Wv[o] = s * 0.011048543456039804f;
}

// ---------------- k_wab: EDGE-ORDER fused filter MLP, CSR-slot scatter write ----
// 64-edge tiles; fij coalesced; h in LDS; row written to Wab[slot_of_e[e]].
// Thread col ownership {4q..4q+3, 64+4q..64+4q+3} -> sW2c reads are 2-way
// (free) instead of the old 4-way-conflicting stride-8 pattern.
__global__ __launch_bounds__(256) void k_wab(
        const float* __restrict__ fij, const float* __restrict__ rcut,
        const int* __restrict__ slot_of_e,
        const float* __restrict__ W1, const float* __restrict__ b1,
        const float* __restrict__ W2, const float* __restrict__ b2,
        float* __restrict__ Wab) {
  __shared__ float sW1[640];
  __shared__ float sb1[32];
  __shared__ float sW2c[4096];     // [p][128] compact cols (4f+k <- 6f+k)
  __shared__ float sb2c[128];
  __shared__ float sfij[20 * 66];  // [r][el]
  __shared__ float sh[64 * 37];    // [el][fp]
  __shared__ float srct[64];
  __shared__ int sslot[64];
  int t = threadIdx.x;
  size_t e0 = (size_t)blockIdx.x * 64;   // 4096 blocks
  for (int i = t; i < 640; i += 256) sW1[i] = W1[i];
  if (t < 32) sb1[t] = b1[t];
  for (int i = t; i < 4096; i += 256) {
    int p = i >> 7, c = i & 127;
    sW2c[i] = W2[p * 192 + 6 * (c >> 2) + (c & 3)];
  }
  if (t < 128) sb2c[t] = b2[6 * (t >> 2) + (t & 3)];
  for (int i = t; i < 1280; i += 256) {
    int el = i / 20, r = i - el * 20;
    sfij[r * 66 + el] = fij[e0 * 20 + i];   // coalesced global read
  }
  if (t < 64) {
    srct[t] = rcut[e0 + t];
    sslot[t] = slot_of_e[e0 + t];
  }
  __syncthreads();
  {
    int el = t & 63, fp0 = (t >> 6) * 8;
    float acc[8];
#pragma unroll
    for (int i = 0; i < 8; i++) acc[i] = sb1[fp0 + i];
#pragma unroll
    for (int r = 0; r < 20; r++) {
      float fe = sfij[r * 66 + el];
      float4 wA = *(const float4*)(sW1 + r * 32 + fp0);
      float4 wB = *(const float4*)(sW1 + r * 32 + fp0 + 4);
      acc[0] += fe * wA.x; acc[1] += fe * wA.y;
      acc[2] += fe * wA.z; acc[3] += fe * wA.w;
      acc[4] += fe * wB.x; acc[5] += fe * wB.y;
      acc[6] += fe * wB.z; acc[7] += fe * wB.w;
    }
#pragma unroll
    for (int i = 0; i < 8; i++) sh[el * 37 + fp0 + i] = sspf(acc[i]);
  }
  __syncthreads();
  {
    int eq = t >> 4, q = t & 15;   // 4 edges; cols {4q..4q+3, 64+4q..64+4q+3}
    float acc[4][8];
#pragma unroll
    for (int j = 0; j < 4; j++)
#pragma unroll
      for (int i = 0; i < 8; i++)
        acc[j][i] = (i < 4) ? sb2c[4 * q + i] : sb2c[64 + 4 * q + (i - 4)];
#pragma unroll
    for (int p = 0; p < 32; p++) {
      float4 wA = *(const float4*)(sW2c + p * 128 + 4 * q);        // 2-way, free
      float4 wB = *(const float4*)(sW2c + p * 128 + 64 + 4 * q);   // 2-way, free
      float w[8] = {wA.x, wA.y, wA.z, wA.w, wB.x, wB.y, wB.z, wB.w};
#pragma unroll
      for (int j = 0; j < 4; j++) {
        float hh = sh[(4 * eq + j) * 37 + p];
#pragma unroll
        for (int i = 0; i < 8; i++) acc[j][i] += hh * w[i];
      }
    }
#pragma unroll
    for (int j = 0; j < 4; j++) {
      float rc = srct[4 * eq + j];
      float* base = Wab + (size_t)sslot[4 * eq + j] * 128;   // CSR scatter
      float4 o1, o2;
      o1.x = acc[j][0] * rc; o1.y = acc[j][1] * rc;
      o1.z = acc[j][2] * rc; o1.w = acc[j][3] * rc;
      o2.x = acc[j][4] * rc; o2.y = acc[j][5] * rc;
      o2.z = acc[j][6] * rc; o2.w = acc[j][7] * rc;
      *(float4*)(base + 4 * q) = o1;
      *(float4*)(base + 64 + 4 * q) = o2;
    }
  }
}

// ---------------- k_agg3: one wave per node; Wab read is now SEQUENTIAL ------
// Lane l owns compact cols {2l, 2l+1}; W = Wab2[slot*64+l] streams in slot
// order (prefetch depth-2, no index chase). Only random access: hsv[j].
__global__ __launch_bounds__(256, 4) void k_agg3(
        const float2* __restrict__ Wab2, const int* __restrict__ idxj_csr,
        const float4* __restrict__ Yr_csr, const float4* __restrict__ hsv,
        const int* __restrict__ offs, float* __restrict__ nagg) {
  int t = threadIdx.x;
  int w = t >> 6, l = t & 63;
  int n = blockIdx.x * 4 + w;          // 4096 blocks
  int f = l >> 1, kb = (l & 1) * 2;
  int start = offs[n], end = offs[n + 1];
  float a0 = 0, a1 = 0, a2 = 0, a3 = 0, a4 = 0, a5 = 0;
  if (start < end) {
    int last = end - 1;
    int i1 = start + 1 < last ? start + 1 : last;
    int i2 = start + 2 < last ? start + 2 : last;
    int j0 = idxj_csr[start];
    int j1 = idxj_csr[i1];
    int j2 = idxj_csr[i2];
    float4 y0 = Yr_csr[start];
    float4 sv0 = hsv[(size_t)j0 * 32 + f];
    float4 sv1 = hsv[(size_t)j1 * 32 + f];
    float2 W0 = Wab2[(size_t)start * 64 + l];
    float2 W1 = Wab2[(size_t)i1 * 64 + l];
    for (int ei = start; ei < end; ++ei) {
      int in1 = ei + 1 < last ? ei + 1 : last;
      int in2 = ei + 2 < last ? ei + 2 : last;
      int in3 = ei + 3 < last ? ei + 3 : last;
      float4 sv2 = hsv[(size_t)j2 * 32 + f];     // depth-2 (random)
      float2 W2r = Wab2[(size_t)in2 * 64 + l];   // depth-2 (sequential)
      float4 y1 = Yr_csr[in1];                   // depth-1 (sequential)
      int j3 = idxj_csr[in3];                    // depth-3 (sequential)
      float ys = y0.x, yx = y0.y, yy = y0.z, yz = y0.w;
      float ss = sv0.x, vx = sv0.y, vy = sv0.z, vz = sv0.w;
      if (kb == 0) {
        a0 += ss * ys * W0.x;                                          // ch0
        a1 += (vx * yx + vy * yy + vz * yz) * 0.57735026918962576f * W0.y; // ch1
      } else {
        a0 += ss * yx * W0.x; a1 += ss * yy * W0.x; a2 += ss * yz * W0.x; // t_v1
        a3 += vx * ys * W0.y; a4 += vy * ys * W0.y; a5 += vz * ys * W0.y; // t_v2
      }
      y0 = y1; sv0 = sv1; sv1 = sv2; W0 = W1; W1 = W2r; j2 = j3;
    }
  }
  float* na = nagg + (size_t)n * 256;
  if (kb == 0) {
    na[f] = a0;
    na[32 + f] = a1;
  } else {
    na[64 + 3 * f + 0] = a0;  na[64 + 3 * f + 1] = a1;  na[64 + 3 * f + 2] = a2;
    na[160 + 3 * f + 0] = a3; na[160 + 3 * f + 1] = a4; na[160 + 3 * f + 2] = a5;
  }
}

// ---------------- output GEMMs: W in LDS [k][d], A in register tiles ----------------
__global__ __launch_bounds__(256) void k_os1(const float* __restrict__ na,
        const float* __restrict__ w1s, float* __restrict__ os1) {
  __shared__ float sw[8192];       // w1s [64][128]
  int t = threadIdx.x;
  for (int i = t; i < 8192; i += 256) sw[i] = w1s[i];
  __syncthreads();
  int dg = t & 31, ng = t >> 5;
  int d0 = dg * 4;
  int n0 = blockIdx.x * 32 + ng * 4;      // grid 512
  const float* ap = na + (size_t)n0 * 256;
  float acc[4][4] = {};
#pragma unroll
  for (int kq = 0; kq < 16; kq++) {
    float4 a[4];
#pragma unroll
    for (int j = 0; j < 4; j++) a[j] = *(const float4*)(ap + j * 256 + 4 * kq);
    float4 w0 = *(const float4*)(sw + (4 * kq + 0) * 128 + d0);
    float4 w1 = *(const float4*)(sw + (4 * kq + 1) * 128 + d0);
    float4 w2 = *(const float4*)(sw + (4 * kq + 2) * 128 + d0);
    float4 w3 = *(const float4*)(sw + (4 * kq + 3) * 128 + d0);
#pragma unroll
    for (int j = 0; j < 4; j++) {
      acc[j][0] += a[j].x * w0.x + a[j].y * w1.x + a[j].z * w2.x + a[j].w * w3.x;
      acc[j][1] += a[j].x * w0.y + a[j].y * w1.y + a[j].z * w2.y + a[j].w * w3.y;
      acc[j][2] += a[j].x * w0.z + a[j].y * w1.z + a[j].z * w2.z + a[j].w * w3.z;
      acc[j][3] += a[j].x * w0.w + a[j].y * w1.w + a[j].z * w2.w + a[j].w * w3.w;
    }
  }
#pragma unroll
  for (int j = 0; j < 4; j++) {
    float4 o;
    o.x = sspf(acc[j][0] * 0.125f);   // 1/sqrt(64)
    o.y = sspf(acc[j][1] * 0.125f);
    o.z = sspf(acc[j][2] * 0.125f);
    o.w = sspf(acc[j][3] * 0.125f);
    *(float4*)(os1 + (size_t)(n0 + j) * 128 + d0) = o;
  }
}

__global__ __launch_bounds__(256) void k_os2(const float* __restrict__ os1,
        const float* __restrict__ w2s, float* __restrict__ out) {
  __shared__ float sw[16384];      // w2s [128][128] = 64 KB
  int t = threadIdx.x;
  for (int i = t; i < 16384; i += 256) sw[i] = w2s[i];
  __syncthreads();
  int dg = t & 31, ng = t >> 5;
  int d0 = dg * 4;
  int n0 = blockIdx.x * 32 + ng * 4;      // grid 512
  const float* ap = os1 + (size_t)n0 * 128;
  float acc[4][4] = {};
#pragma unroll
  for (int kq = 0; kq < 32; kq++) {
    float4 a[4];
#pragma unroll
    for (int j = 0; j < 4; j++) a[j] = *(const float4*)(ap + j * 128 + 4 * kq);
    float4 w0 = *(const float4*)(sw + (4 * kq + 0) * 128 + d0);
    float4 w1 = *(const float4*)(sw + (4 * kq + 1) * 128 + d0);
    float4 w2 = *(const float4*)(sw + (4 * kq + 2) * 128 + d0);
    float4 w3 = *(const float4*)(sw + (4 * kq + 3) * 128 + d0);
#pragma unroll
    for (int j = 0; j < 4; j++) {
      acc[j][0] += a[j].x * w0.x + a[j].y * w1.x + a[j].z * w2.x + a[j].w * w3.x;
      acc[j][1] += a[j].x * w0.y + a[j].y * w1.y + a[j].z * w2.y + a[j].w * w3.y;
      acc[j][2] += a[j].x * w0.z + a[j].y * w1.z + a[j].z * w2.z + a[j].w * w3.z;
      acc[j][3] += a[j].x * w0.w + a[j].y * w1.w + a[j].z * w2.w + a[j].w * w3.w;
    }
  }
  const float sc = 0.088388347648318447f;   // 1/sqrt(128)
#pragma unroll
  for (int j = 0; j < 4; j++) {
    float4 o;
    o.x = acc[j][0] * sc; o.y = acc[j][1] * sc;
    o.z = acc[j][2] * sc; o.w = acc[j][3] * sc;
    *(float4*)(out + (size_t)(n0 + j) * 512 + d0) = o;
  }
}

// thread = 2 nodes x 4 d x 3 comps
__global__ __launch_bounds__(256) void k_ov(const float* __restrict__ na,
        const float* __restrict__ Wv, float* __restrict__ out) {
  __shared__ float sw[8192];       // Wv [64][128]
  int t = threadIdx.x;
  for (int i = t; i < 8192; i += 256) sw[i] = Wv[i];
  __syncthreads();
  int dg = t & 31, ng = t >> 5;
  int d0 = dg * 4;
  int n0 = blockIdx.x * 16 + ng * 2;      // grid 1024
  const float* ap = na + (size_t)n0 * 256 + 64;   // v_in row: 192 contiguous
  float acc[2][12] = {};
#pragma unroll
  for (int mq = 0; mq < 16; mq++) {
    float4 p[2][3];
#pragma unroll
    for (int j = 0; j < 2; j++) {
      p[j][0] = *(const float4*)(ap + j * 256 + 12 * mq);
      p[j][1] = *(const float4*)(ap + j * 256 + 12 * mq + 4);
      p[j][2] = *(const float4*)(ap + j * 256 + 12 * mq + 8);
    }
    float4 w0 = *(const float4*)(sw + (4 * mq + 0) * 128 + d0);
    float4 w1 = *(const float4*)(sw + (4 * mq + 1) * 128 + d0);
    float4 w2 = *(const float4*)(sw + (4 * mq + 2) * 128 + d0);
    float4 w3 = *(const float4*)(sw + (4 * mq + 3) * 128 + d0);
#pragma unroll
    for (int j = 0; j < 2; j++) {
      float vm[4][3];
      vm[0][0] = p[j][0].x; vm[0][1] = p[j][0].y; vm[0][2] = p[j][0].z;
      vm[1][0] = p[j][0].w; vm[1][1] = p[j][1].x; vm[1][2] = p[j][1].y;
      vm[2][0] = p[j][1].z; vm[2][1] = p[j][1].w; vm[2][2] = p[j][2].x;
      vm[3][0] = p[j][2].y; vm[3][1] = p[j][2].z; vm[3][2] = p[j][2].w;
      float wm[4][4];
      wm[0][0] = w0.x; wm[0][1] = w0.y; wm[0][2] = w0.z; wm[0][3] = w0.w;
      wm[1][0] = w1.x; wm[1][1] = w1.y; wm[1][2] = w1.z; wm[1][3] = w1.w;
      wm[2][0] = w2.x; wm[2][1] = w2.y; wm[2][2] = w2.z; wm[2][3] = w2.w;
      wm[3][0] = w3.x; wm[3][1] = w3.y; wm[3][2] = w3.z; wm[3][3] = w3.w;
#pragma unroll
      for (int m = 0; m < 4; m++)
#pragma unroll
        for (int i = 0; i < 4; i++)
#pragma unroll
          for (int c = 0; c < 3; c++)
            acc[j][i * 3 + c] += vm[m][c] * wm[m][i];
    }
  }
#pragma unroll
  for (int j = 0; j < 2; j++) {
    float* op = out + (size_t)(n0 + j) * 512 + 128 + 12 * dg;
    float4 o0, o1, o2;
    o0.x = acc[j][0]; o0.y = acc[j][1]; o0.z = acc[j][2]; o0.w = acc[j][3];
    o1.x = acc[j][4]; o1.y = acc[j][5]; o1.z = acc[j][6]; o1.w = acc[j][7];
    o2.x = acc[j][8]; o2.y = acc[j][9]; o2.z = acc[j][10]; o2.w = acc[j][11];
    *(float4*)op = o0;
    *(float4*)(op + 4) = o1;
    *(float4*)(op + 8) = o2;
  }
}

extern "C" void kernel_launch(void* const* d_in, const int* in_sizes, int n_in,
                              void* d_out, int out_size, void* d_ws, size_t ws_size,
                              hipStream_t stream) {
  const float* x    = (const float*)d_in[0];
  const int*   idx_i = (const int*)d_in[1];
  const int*   idx_j = (const int*)d_in[2];
  const float* fij  = (const float*)d_in[3];
  const float* rcut = (const float*)d_in[4];
  const float* Yr   = (const float*)d_in[5];
  const float* w_s  = (const float*)d_in[6];
  const float* w_v  = (const float*)d_in[7];
  const float* W1   = (const float*)d_in[8];
  const float* b1   = (const float*)d_in[9];
  const float* W2   = (const float*)d_in[10];
  const float* b2   = (const float*)d_in[11];
  const float* w1s  = (const float*)d_in[12];
  const float* w1v  = (const float*)d_in[13];
  const float* w2s  = (const float*)d_in[14];
  const float* w2v  = (const float*)d_in[15];
  float* out = (float*)d_out;

  char* ws = (char*)d_ws;
  size_t off = 0;
  auto alloc = [&](size_t bytes) {
    void* p = ws + off;
    off += (bytes + 255) & ~(size_t)255;
    return p;
  };
  float4* hsv   = (float4*)alloc((size_t)NN * 32 * 16);
  float*  nagg  = (float*)alloc((size_t)NN * 256 * 4);
  float*  Wab   = (float*)alloc((size_t)EE * 128 * 4);    // 134 MB, slot-order
  float*  os1   = (float*)alloc((size_t)NN * 128 * 4);
  float4* Yr_csr = (float4*)alloc((size_t)EE * 16);
  int* idxj_csr = (int*)alloc((size_t)EE * 4);
  int* slot_of_e = (int*)alloc((size_t)EE * 4);
  float* Wv     = (float*)alloc((size_t)8192 * 4);
  int* cnt      = (int*)alloc((size_t)NN * 4);
  int* offs     = (int*)alloc((size_t)(NN + 1) * 4);
  int* pos      = (int*)alloc((size_t)EE * 4);

  hipMemsetAsync(cnt, 0, (size_t)NN * 4, stream);
  k_count<<<EE / 256, 256, 0, stream>>>(idx_i, cnt, pos);
  k_scan<<<1, 256, 0, stream>>>(cnt, offs);
  k_fill<<<EE / 256, 256, 0, stream>>>(idx_i, idx_j, Yr, pos, offs,
                                       slot_of_e, idxj_csr, Yr_csr);
  k_embed<<<NN / 32, 256, 0, stream>>>(x, w_s, w_v, hsv);
  k_wv<<<32, 256, 0, stream>>>(w1v, w2v, Wv);
  k_wab<<<EE / 64, 256, 0, stream>>>(fij, rcut, slot_of_e, W1, b1, W2, b2, Wab);
  k_agg3<<<NN / 4, 256, 0, stream>>>((const float2*)Wab, idxj_csr, Yr_csr,
                                     hsv, offs, nagg);
  k_os1<<<512, 256, 0, stream>>>(nagg, w1s, os1);
  k_os2<<<512, 256, 0, stream>>>(os1, w2s, out);
  k_ov<<<1024, 256, 0, stream>>>(nagg, Wv, out);
}

// Round 12
// 232.624 us; speedup vs baseline: 1.5039x; 1.0721x over previous
//
#include <hip/hip_runtime.h>
#include <math.h>

#define NN 16384
#define BB 128
#define FF 32
#define RR 20
#define EE 262144

__device__ __forceinline__ float sspf(float x) {
  // softplus(x) - log(2), numerically stable
  return fmaxf(x, 0.0f) + log1pf(expf(-fabsf(x))) - 0.69314718055994531f;
}

// pack two floats to bf16x2 (RNE)
__device__ __forceinline__ unsigned int pack_bf2(float a, float b) {
  unsigned int ua = __float_as_uint(a);
  ua = (ua + 0x7fffu + ((ua >> 16) & 1u)) >> 16;
  unsigned int ub = __float_as_uint(b);
  ub = (ub + 0x7fffu + ((ub >> 16) & 1u)) & 0xffff0000u;
  return ua | ub;
}

// ---------------- K1: node embeddings, x rows staged in LDS ----------------
__global__ __launch_bounds__(256) void k_embed(const float* __restrict__ x,
        const float* __restrict__ ws, const float* __restrict__ wv,
        float4* __restrict__ hsv) {
  __shared__ float sx[32 * 516];   // 66 KB
  int t = threadIdx.x;
  int b0 = blockIdx.x * 32;        // 512 blocks
  const float4* xg = (const float4*)(x + (size_t)b0 * 512);
  for (int i = t; i < 4096; i += 256) {
    int row = i >> 7, col = i & 127;
    *(float4*)(sx + row * 516 + col * 4) = xg[i];
  }
  __syncthreads();
  int n = t >> 3, fq = t & 7;
  const float* xr = sx + n * 516;
  float acc[4][4];
#pragma unroll
  for (int k = 0; k < 4; k++)
#pragma unroll
    for (int c = 0; c < 4; c++) acc[k][c] = 0.f;
  for (int bq = 0; bq < 32; bq++) {
    float4 xs4 = *(const float4*)(xr + 4 * bq);
    float4 a0 = *(const float4*)(xr + 128 + 12 * bq);
    float4 a1 = *(const float4*)(xr + 128 + 12 * bq + 4);
    float4 a2 = *(const float4*)(xr + 128 + 12 * bq + 8);
    float xsv[4] = {xs4.x, xs4.y, xs4.z, xs4.w};
    float vv[4][3];
    vv[0][0] = a0.x; vv[0][1] = a0.y; vv[0][2] = a0.z;
    vv[1][0] = a0.w; vv[1][1] = a1.x; vv[1][2] = a1.y;
    vv[2][0] = a1.z; vv[2][1] = a1.w; vv[2][2] = a2.x;
    vv[3][0] = a2.y; vv[3][1] = a2.z; vv[3][2] = a2.w;
#pragma unroll
    for (int bb = 0; bb < 4; bb++) {
      int b = 4 * bq + bb;
      float4 w_s = *(const float4*)(ws + b * 32 + 4 * fq);
      float4 w_v = *(const float4*)(wv + b * 32 + 4 * fq);
      float wsx[4] = {w_s.x, w_s.y, w_s.z, w_s.w};
      float wvx[4] = {w_v.x, w_v.y, w_v.z, w_v.w};
#pragma unroll
      for (int k = 0; k < 4; k++) {
        acc[k][0] += xsv[bb] * wsx[k];
        acc[k][1] += vv[bb][0] * wvx[k];
        acc[k][2] += vv[bb][1] * wvx[k];
        acc[k][3] += vv[bb][2] * wvx[k];
      }
    }
  }
  const float sc = 0.088388347648318447f;  // 1/sqrt(128)
#pragma unroll
  for (int k = 0; k < 4; k++) {
    float4 o;
    o.x = acc[k][0] * sc; o.y = acc[k][1] * sc;
    o.z = acc[k][2] * sc; o.w = acc[k][3] * sc;
    hsv[(size_t)(b0 + n) * 32 + 4 * fq + k] = o;
  }
}

// ---------------- CSR build ----------------
__global__ __launch_bounds__(256) void k_count(const int* __restrict__ idx_i,
        int* __restrict__ cnt, int* __restrict__ pos) {
  int e = blockIdx.x * 256 + threadIdx.x;
  pos[e] = atomicAdd(cnt + idx_i[e], 1);
}

__global__ __launch_bounds__(256) void k_scan(const int* __restrict__ cnt,
        int* __restrict__ offs) {
  __shared__ int part[256];
  int t = threadIdx.x;
  int s = 0;
  for (int i = t * 64; i < t * 64 + 64; ++i) s += cnt[i];
  part[t] = s;
  __syncthreads();
  if (t == 0) {
    int run = 0;
    for (int i = 0; i < 256; i++) { int v = part[i]; part[i] = run; run += v; }
    offs[NN] = run;
  }
  __syncthreads();
  int run = part[t];
  for (int i = t * 64; i < t * 64 + 64; ++i) { offs[i] = run; run += cnt[i]; }
}

// CSR permutation: slot_of_e (for wab scatter-write) + idx_j/Yr slot streams
__global__ __launch_bounds__(256) void k_fill(const int* __restrict__ idx_i,
        const int* __restrict__ idx_j, const float* __restrict__ Yr,
        const int* __restrict__ pos, const int* __restrict__ offs,
        int* __restrict__ slot_of_e, int* __restrict__ idxj_csr,
        float4* __restrict__ Yr_csr) {
  int e = blockIdx.x * 256 + threadIdx.x;
  int slot = offs[idx_i[e]] + pos[e];
  slot_of_e[e] = slot;
  idxj_csr[slot] = idx_j[e];
  Yr_csr[slot] = *(const float4*)(Yr + (size_t)e * 4);
}

// ---------------- fused vector output weight: Wv = w1v @ w2v * 1/sqrt(64*128) ----------------
__global__ __launch_bounds__(256) void k_wv(const float* __restrict__ w1v,
        const float* __restrict__ w2v, float* __restrict__ Wv) {
  int o = blockIdx.x * 256 + threadIdx.x;   // 8192
  int m = o >> 7, d = o & 127;
  float s = 0.f;
  for (int b = 0; b < 128; b++) s += w1v[m * 128 + b] * w2v[b * 128 + d];
  Wv[o] = s * 0.011048543456039804f;
}

// ---------------- k_wab: 128-edge tiles, 8x8 register blocking, bf16 scatter write ----
// Thread = 8 edges x 8 cols {4q..4q+3, 64+4q..64+4q+3}; each weight b128 read
// feeds 64 FMAs (LDS-cyc/output halved vs 4x8). Row written as bf16x2 to CSR slot.
__global__ __launch_bounds__(256, 4) void k_wab(
        const float* __restrict__ fij, const float* __restrict__ rcut,
        const int* __restrict__ slot_of_e,
        const float* __restrict__ W1, const float* __restrict__ b1,
        const float* __restrict__ W2, const float* __restrict__ b2,
        unsigned int* __restrict__ Wab) {
  __shared__ float sW1[640];
  __shared__ float sb1[32];
  __shared__ float sW2c[4096];     // [p][128] compact cols (4f+k <- 6f+k)
  __shared__ float sb2c[128];
  __shared__ float sfij[20 * 130]; // [r][el]
  __shared__ float sh[128 * 37];   // [el][fp]
  __shared__ float srct[128];
  __shared__ int sslot[128];
  int t = threadIdx.x;
  size_t e0 = (size_t)blockIdx.x * 128;   // 2048 blocks
  for (int i = t; i < 640; i += 256) sW1[i] = W1[i];
  if (t < 32) sb1[t] = b1[t];
  for (int i = t; i < 4096; i += 256) {
    int p = i >> 7, c = i & 127;
    sW2c[i] = W2[p * 192 + 6 * (c >> 2) + (c & 3)];
  }
  if (t < 128) sb2c[t] = b2[6 * (t >> 2) + (t & 3)];
  for (int i = t; i < 2560; i += 256) {
    int el = i / 20, r = i - el * 20;
    sfij[r * 130 + el] = fij[e0 * 20 + i];   // coalesced global read
  }
  if (t < 128) {
    srct[t] = rcut[e0 + t];
    sslot[t] = slot_of_e[e0 + t];
  }
  __syncthreads();
  {
    int el = t & 127, fp0 = (t >> 7) * 16;
    float acc[16];
#pragma unroll
    for (int i = 0; i < 16; i++) acc[i] = sb1[fp0 + i];
#pragma unroll
    for (int r = 0; r < 20; r++) {
      float fe = sfij[r * 130 + el];
      float4 wA = *(const float4*)(sW1 + r * 32 + fp0);
      float4 wB = *(const float4*)(sW1 + r * 32 + fp0 + 4);
      float4 wC = *(const float4*)(sW1 + r * 32 + fp0 + 8);
      float4 wD = *(const float4*)(sW1 + r * 32 + fp0 + 12);
      acc[0] += fe * wA.x;  acc[1] += fe * wA.y;
      acc[2] += fe * wA.z;  acc[3] += fe * wA.w;
      acc[4] += fe * wB.x;  acc[5] += fe * wB.y;
      acc[6] += fe * wB.z;  acc[7] += fe * wB.w;
      acc[8] += fe * wC.x;  acc[9] += fe * wC.y;
      acc[10] += fe * wC.z; acc[11] += fe * wC.w;
      acc[12] += fe * wD.x; acc[13] += fe * wD.y;
      acc[14] += fe * wD.z; acc[15] += fe * wD.w;
    }
#pragma unroll
    for (int i = 0; i < 16; i++) sh[el * 37 + fp0 + i] = sspf(acc[i]);
  }
  __syncthreads();
  {
    int eq = t >> 4, q = t & 15;   // 8 edges; cols {4q..4q+3, 64+4q..64+4q+3}
    float acc[8][8];
#pragma unroll
    for (int j = 0; j < 8; j++)
#pragma unroll
      for (int i = 0; i < 8; i++)
        acc[j][i] = (i < 4) ? sb2c[4 * q + i] : sb2c[64 + 4 * q + (i - 4)];
#pragma unroll
    for (int p = 0; p < 32; p++) {
      float4 wA = *(const float4*)(sW2c + p * 128 + 4 * q);        // 2-way, free
      float4 wB = *(const float4*)(sW2c + p * 128 + 64 + 4 * q);   // 2-way, free
      float w[8] = {wA.x, wA.y, wA.z, wA.w, wB.x, wB.y, wB.z, wB.w};
#pragma unroll
      for (int j = 0; j < 8; j++) {
        float hh = sh[(8 * eq + j) * 37 + p];
#pragma unroll
        for (int i = 0; i < 8; i++) acc[j][i] += hh * w[i];
      }
    }
#pragma unroll
    for (int j = 0; j < 8; j++) {
      float rc = srct[8 * eq + j];
      unsigned int* base = Wab + (size_t)sslot[8 * eq + j] * 64;   // CSR scatter
      uint2 oA, oB;
      oA.x = pack_bf2(acc[j][0] * rc, acc[j][1] * rc);
      oA.y = pack_bf2(acc[j][2] * rc, acc[j][3] * rc);
      oB.x = pack_bf2(acc[j][4] * rc, acc[j][5] * rc);
      oB.y = pack_bf2(acc[j][6] * rc, acc[j][7] * rc);
      *(uint2*)(base + 2 * q) = oA;          // cols 4q..4q+3
      *(uint2*)(base + 32 + 2 * q) = oB;     // cols 64+4q..64+4q+3
    }
  }
}

// ---------------- k_agg3: one wave per node; sequential bf16 Wab stream ------
// Lane l owns compact cols {2l, 2l+1} = one packed uint Wab[slot*64+l].
// Only random access: hsv[j] (depth-2 prefetch).
__global__ __launch_bounds__(256, 4) void k_agg3(
        const unsigned int* __restrict__ Wu, const int* __restrict__ idxj_csr,
        const float4* __restrict__ Yr_csr, const float4* __restrict__ hsv,
        const int* __restrict__ offs, float* __restrict__ nagg) {
  int t = threadIdx.x;
  int w = t >> 6, l = t & 63;
  int n = blockIdx.x * 4 + w;          // 4096 blocks
  int f = l >> 1, kb = (l & 1) * 2;
  int start = offs[n], end = offs[n + 1];
  float a0 = 0, a1 = 0, a2 = 0, a3 = 0, a4 = 0, a5 = 0;
  if (start < end) {
    int last = end - 1;
    int i1 = start + 1 < last ? start + 1 : last;
    int i2 = start + 2 < last ? start + 2 : last;
    int j0 = idxj_csr[start];
    int j1 = idxj_csr[i1];
    int j2 = idxj_csr[i2];
    float4 y0 = Yr_csr[start];
    float4 sv0 = hsv[(size_t)j0 * 32 + f];
    float4 sv1 = hsv[(size_t)j1 * 32 + f];
    unsigned int W0 = Wu[(size_t)start * 64 + l];
    unsigned int W1 = Wu[(size_t)i1 * 64 + l];
    for (int ei = start; ei < end; ++ei) {
      int in1 = ei + 1 < last ? ei + 1 : last;
      int in2 = ei + 2 < last ? ei + 2 : last;
      int in3 = ei + 3 < last ? ei + 3 : last;
      float4 sv2 = hsv[(size_t)j2 * 32 + f];     // depth-2 (random)
      unsigned int W2r = Wu[(size_t)in2 * 64 + l]; // depth-2 (sequential)
      float4 y1 = Yr_csr[in1];                   // depth-1 (sequential)
      int j3 = idxj_csr[in3];                    // depth-3 (sequential)
      float Wx = __uint_as_float(W0 << 16);
      float Wy = __uint_as_float(W0 & 0xffff0000u);
      float ys = y0.x, yx = y0.y, yy = y0.z, yz = y0.w;
      float ss = sv0.x, vx = sv0.y, vy = sv0.z, vz = sv0.w;
      if (kb == 0) {
        a0 += ss * ys * Wx;                                          // ch0
        a1 += (vx * yx + vy * yy + vz * yz) * 0.57735026918962576f * Wy; // ch1
      } else {
        a0 += ss * yx * Wx; a1 += ss * yy * Wx; a2 += ss * yz * Wx; // t_v1
        a3 += vx * ys * Wy; a4 += vy * ys * Wy; a5 += vz * ys * Wy; // t_v2
      }
      y0 = y1; sv0 = sv1; sv1 = sv2; W0 = W1; W1 = W2r; j2 = j3;
    }
  }
  float* na = nagg + (size_t)n * 256;
  if (kb == 0) {
    na[f] = a0;
    na[32 + f] = a1;
  } else {
    na[64 + 3 * f + 0] = a0;  na[64 + 3 * f + 1] = a1;  na[64 + 3 * f + 2] = a2;
    na[160 + 3 * f + 0] = a3; na[160 + 3 * f + 1] = a4; na[160 + 3 * f + 2] = a5;
  }
}

// ---------------- output GEMMs: W in LDS [k][d], A in register tiles ----------------
__global__ __launch_bounds__(256) void k_os1(const float* __restrict__ na,
        const float* __restrict__ w1s, float* __restrict__ os1) {
  __shared__ float sw[8192];       // w1s [64][128]
  int t = threadIdx.x;
  for (int i = t; i < 8192; i += 256) sw[i] = w1s[i];
  __syncthreads();
  int dg = t & 31, ng = t >> 5;
  int d0 = dg * 4;
  int n0 = blockIdx.x * 32 + ng * 4;      // grid 512
  const float* ap = na + (size_t)n0 * 256;
  float acc[4][4] = {};
#pragma unroll
  for (int kq = 0; kq < 16; kq++) {
    float4 a[4];
#pragma unroll
    for (int j = 0; j < 4; j++) a[j] = *(const float4*)(ap + j * 256 + 4 * kq);
    float4 w0 = *(const float4*)(sw + (4 * kq + 0) * 128 + d0);
    float4 w1 = *(const float4*)(sw + (4 * kq + 1) * 128 + d0);
    float4 w2 = *(const float4*)(sw + (4 * kq + 2) * 128 + d0);
    float4 w3 = *(const float4*)(sw + (4 * kq + 3) * 128 + d0);
#pragma unroll
    for (int j = 0; j < 4; j++) {
      acc[j][0] += a[j].x * w0.x + a[j].y * w1.x + a[j].z * w2.x + a[j].w * w3.x;
      acc[j][1] += a[j].x * w0.y + a[j].y * w1.y + a[j].z * w2.y + a[j].w * w3.y;
      acc[j][2] += a[j].x * w0.z + a[j].y * w1.z + a[j].z * w2.z + a[j].w * w3.z;
      acc[j][3] += a[j].x * w0.w + a[j].y * w1.w + a[j].z * w2.w + a[j].w * w3.w;
    }
  }
#pragma unroll
  for (int j = 0; j < 4; j++) {
    float4 o;
    o.x = sspf(acc[j][0] * 0.125f);   // 1/sqrt(64)
    o.y = sspf(acc[j][1] * 0.125f);
    o.z = sspf(acc[j][2] * 0.125f);
    o.w = sspf(acc[j][3] * 0.125f);
    *(float4*)(os1 + (size_t)(n0 + j) * 128 + d0) = o;
  }
}

__global__ __launch_bounds__(256) void k_os2(const float* __restrict__ os1,
        const float* __restrict__ w2s, float* __restrict__ out) {
  __shared__ float sw[16384];      // w2s [128][128] = 64 KB
  int t = threadIdx.x;
  for (int i = t; i < 16384; i += 256) sw[i] = w2s[i];
  __syncthreads();
  int dg = t & 31, ng = t >> 5;
  int d0 = dg * 4;
  int n0 = blockIdx.x * 32 + ng * 4;      // grid 512
  const float* ap = os1 + (size_t)n0 * 128;
  float acc[4][4] = {};
#pragma unroll
  for (int kq = 0; kq < 32; kq++) {
    float4 a[4];
#pragma unroll
    for (int j = 0; j < 4; j++) a[j] = *(const float4*)(ap + j * 128 + 4 * kq);
    float4 w0 = *(const float4*)(sw + (4 * kq + 0) * 128 + d0);
    float4 w1 = *(const float4*)(sw + (4 * kq + 1) * 128 + d0);
    float4 w2 = *(const float4*)(sw + (4 * kq + 2) * 128 + d0);
    float4 w3 = *(const float4*)(sw + (4 * kq + 3) * 128 + d0);
#pragma unroll
    for (int j = 0; j < 4; j++) {
      acc[j][0] += a[j].x * w0.x + a[j].y * w1.x + a[j].z * w2.x + a[j].w * w3.x;
      acc[j][1] += a[j].x * w0.y + a[j].y * w1.y + a[j].z * w2.y + a[j].w * w3.y;
      acc[j][2] += a[j].x * w0.z + a[j].y * w1.z + a[j].z * w2.z + a[j].w * w3.z;
      acc[j][3] += a[j].x * w0.w + a[j].y * w1.w + a[j].z * w2.w + a[j].w * w3.w;
    }
  }
  const float sc = 0.088388347648318447f;   // 1/sqrt(128)
#pragma unroll
  for (int j = 0; j < 4; j++) {
    float4 o;
    o.x = acc[j][0] * sc; o.y = acc[j][1] * sc;
    o.z = acc[j][2] * sc; o.w = acc[j][3] * sc;
    *(float4*)(out + (size_t)(n0 + j) * 512 + d0) = o;
  }
}

// thread = 2 nodes x 4 d x 3 comps
__global__ __launch_bounds__(256) void k_ov(const float* __restrict__ na,
        const float* __restrict__ Wv, float* __restrict__ out) {
  __shared__ float sw[8192];       // Wv [64][128]
  int t = threadIdx.x;
  for (int i = t; i < 8192; i += 256) sw[i] = Wv[i];
  __syncthreads();
  int dg = t & 31, ng = t >> 5;
  int d0 = dg * 4;
  int n0 = blockIdx.x * 16 + ng * 2;      // grid 1024
  const float* ap = na + (size_t)n0 * 256 + 64;   // v_in row: 192 contiguous
  float acc[2][12] = {};
#pragma unroll
  for (int mq = 0; mq < 16; mq++) {
    float4 p[2][3];
#pragma unroll
    for (int j = 0; j < 2; j++) {
      p[j][0] = *(const float4*)(ap + j * 256 + 12 * mq);
      p[j][1] = *(const float4*)(ap + j * 256 + 12 * mq + 4);
      p[j][2] = *(const float4*)(ap + j * 256 + 12 * mq + 8);
    }
    float4 w0 = *(const float4*)(sw + (4 * mq + 0) * 128 + d0);
    float4 w1 = *(const float4*)(sw + (4 * mq + 1) * 128 + d0);
    float4 w2 = *(const float4*)(sw + (4 * mq + 2) * 128 + d0);
    float4 w3 = *(const float4*)(sw + (4 * mq + 3) * 128 + d0);
#pragma unroll
    for (int j = 0; j < 2; j++) {
      float vm[4][3];
      vm[0][0] = p[j][0].x; vm[0][1] = p[j][0].y; vm[0][2] = p[j][0].z;
      vm[1][0] = p[j][0].w; vm[1][1] = p[j][1].x; vm[1][2] = p[j][1].y;
      vm[2][0] = p[j][1].z; vm[2][1] = p[j][1].w; vm[2][2] = p[j][2].x;
      vm[3][0] = p[j][2].y; vm[3][1] = p[j][2].z; vm[3][2] = p[j][2].w;
      float wm[4][4];
      wm[0][0] = w0.x; wm[0][1] = w0.y; wm[0][2] = w0.z; wm[0][3] = w0.w;
      wm[1][0] = w1.x; wm[1][1] = w1.y; wm[1][2] = w1.z; wm[1][3] = w1.w;
      wm[2][0] = w2.x; wm[2][1] = w2.y; wm[2][2] = w2.z; wm[2][3] = w2.w;
      wm[3][0] = w3.x; wm[3][1] = w3.y; wm[3][2] = w3.z; wm[3][3] = w3.w;
#pragma unroll
      for (int m = 0; m < 4; m++)
#pragma unroll
        for (int i = 0; i < 4; i++)
#pragma unroll
          for (int c = 0; c < 3; c++)
            acc[j][i * 3 + c] += vm[m][c] * wm[m][i];
    }
  }
#pragma unroll
  for (int j = 0; j < 2; j++) {
    float* op = out + (size_t)(n0 + j) * 512 + 128 + 12 * dg;
    float4 o0, o1, o2;
    o0.x = acc[j][0]; o0.y = acc[j][1]; o0.z = acc[j][2]; o0.w = acc[j][3];
    o1.x = acc[j][4]; o1.y = acc[j][5]; o1.z = acc[j][6]; o1.w = acc[j][7];
    o2.x = acc[j][8]; o2.y = acc[j][9]; o2.z = acc[j][10]; o2.w = acc[j][11];
    *(float4*)op = o0;
    *(float4*)(op + 4) = o1;
    *(float4*)(op + 8) = o2;
  }
}

extern "C" void kernel_launch(void* const* d_in, const int* in_sizes, int n_in,
                              void* d_out, int out_size, void* d_ws, size_t ws_size,
                              hipStream_t stream) {
  const float* x    = (const float*)d_in[0];
  const int*   idx_i = (const int*)d_in[1];
  const int*   idx_j = (const int*)d_in[2];
  const float* fij  = (const float*)d_in[3];
  const float* rcut = (const float*)d_in[4];
  const float* Yr   = (const float*)d_in[5];
  const float* w_s  = (const float*)d_in[6];
  const float* w_v  = (const float*)d_in[7];
  const float* W1   = (const float*)d_in[8];
  const float* b1   = (const float*)d_in[9];
  const float* W2   = (const float*)d_in[10];
  const float* b2   = (const float*)d_in[11];
  const float* w1s  = (const float*)d_in[12];
  const float* w1v  = (const float*)d_in[13];
  const float* w2s  = (const float*)d_in[14];
  const float* w2v  = (const float*)d_in[15];
  float* out = (float*)d_out;

  char* ws = (char*)d_ws;
  size_t off = 0;
  auto alloc = [&](size_t bytes) {
    void* p = ws + off;
    off += (bytes + 255) & ~(size_t)255;
    return p;
  };
  float4* hsv   = (float4*)alloc((size_t)NN * 32 * 16);
  float*  nagg  = (float*)alloc((size_t)NN * 256 * 4);
  unsigned int* Wab = (unsigned int*)alloc((size_t)EE * 128 * 2);  // bf16, 67 MB
  float*  os1   = (float*)alloc((size_t)NN * 128 * 4);
  float4* Yr_csr = (float4*)alloc((size_t)EE * 16);
  int* idxj_csr = (int*)alloc((size_t)EE * 4);
  int* slot_of_e = (int*)alloc((size_t)EE * 4);
  float* Wv     = (float*)alloc((size_t)8192 * 4);
  int* cnt      = (int*)alloc((size_t)NN * 4);
  int* offs     = (int*)alloc((size_t)(NN + 1) * 4);
  int* pos      = (int*)alloc((size_t)EE * 4);

  hipMemsetAsync(cnt, 0, (size_t)NN * 4, stream);
  k_count<<<EE / 256, 256, 0, stream>>>(idx_i, cnt, pos);
  k_scan<<<1, 256, 0, stream>>>(cnt, offs);
  k_fill<<<EE / 256, 256, 0, stream>>>(idx_i, idx_j, Yr, pos, offs,
                                       slot_of_e, idxj_csr, Yr_csr);
  k_embed<<<NN / 32, 256, 0, stream>>>(x, w_s, w_v, hsv);
  k_wv<<<32, 256, 0, stream>>>(w1v, w2v, Wv);
  k_wab<<<EE / 128, 256, 0, stream>>>(fij, rcut, slot_of_e, W1, b1, W2, b2, Wab);
  k_agg3<<<NN / 4, 256, 0, stream>>>(Wab, idxj_csr, Yr_csr, hsv, offs, nagg);
  k_os1<<<512, 256, 0, stream>>>(nagg, w1s, os1);
  k_os2<<<512, 256, 0, stream>>>(os1, w2s, out);
  k_ov<<<1024, 256, 0, stream>>>(nagg, Wv, out);
}

// Round 13
// 219.655 us; speedup vs baseline: 1.5927x; 1.0590x over previous
//
#include <hip/hip_runtime.h>
#include <math.h>

#define NN 16384
#define BB 128
#define FF 32
#define RR 20
#define EE 262144

typedef __attribute__((ext_vector_type(8))) short bf16x8;
typedef __attribute__((ext_vector_type(4))) float f32x4;

__device__ __forceinline__ float sspf(float x) {
  // softplus(x) - log(2), numerically stable
  return fmaxf(x, 0.0f) + log1pf(expf(-fabsf(x))) - 0.69314718055994531f;
}

// pack two floats to bf16x2 (RNE)
__device__ __forceinline__ unsigned int pack_bf2(float a, float b) {
  unsigned int ua = __float_as_uint(a);
  ua = (ua + 0x7fffu + ((ua >> 16) & 1u)) >> 16;
  unsigned int ub = __float_as_uint(b);
  ub = (ub + 0x7fffu + ((ub >> 16) & 1u)) & 0xffff0000u;
  return ua | ub;
}

__device__ __forceinline__ unsigned short pack_bf1(float a) {
  unsigned int ua = __float_as_uint(a);
  ua = (ua + 0x7fffu + ((ua >> 16) & 1u)) >> 16;
  return (unsigned short)ua;
}

// ---------------- K1: node embeddings, x rows staged in LDS ----------------
__global__ __launch_bounds__(256) void k_embed(const float* __restrict__ x,
        const float* __restrict__ ws, const float* __restrict__ wv,
        float4* __restrict__ hsv) {
  __shared__ float sx[32 * 516];   // 66 KB
  int t = threadIdx.x;
  int b0 = blockIdx.x * 32;        // 512 blocks
  const float4* xg = (const float4*)(x + (size_t)b0 * 512);
  for (int i = t; i < 4096; i += 256) {
    int row = i >> 7, col = i & 127;
    *(float4*)(sx + row * 516 + col * 4) = xg[i];
  }
  __syncthreads();
  int n = t >> 3, fq = t & 7;
  const float* xr = sx + n * 516;
  float acc[4][4];
#pragma unroll
  for (int k = 0; k < 4; k++)
#pragma unroll
    for (int c = 0; c < 4; c++) acc[k][c] = 0.f;
  for (int bq = 0; bq < 32; bq++) {
    float4 xs4 = *(const float4*)(xr + 4 * bq);
    float4 a0 = *(const float4*)(xr + 128 + 12 * bq);
    float4 a1 = *(const float4*)(xr + 128 + 12 * bq + 4);
    float4 a2 = *(const float4*)(xr + 128 + 12 * bq + 8);
    float xsv[4] = {xs4.x, xs4.y, xs4.z, xs4.w};
    float vv[4][3];
    vv[0][0] = a0.x; vv[0][1] = a0.y; vv[0][2] = a0.z;
    vv[1][0] = a0.w; vv[1][1] = a1.x; vv[1][2] = a1.y;
    vv[2][0] = a1.z; vv[2][1] = a1.w; vv[2][2] = a2.x;
    vv[3][0] = a2.y; vv[3][1] = a2.z; vv[3][2] = a2.w;
#pragma unroll
    for (int bb = 0; bb < 4; bb++) {
      int b = 4 * bq + bb;
      float4 w_s = *(const float4*)(ws + b * 32 + 4 * fq);
      float4 w_v = *(const float4*)(wv + b * 32 + 4 * fq);
      float wsx[4] = {w_s.x, w_s.y, w_s.z, w_s.w};
      float wvx[4] = {w_v.x, w_v.y, w_v.z, w_v.w};
#pragma unroll
      for (int k = 0; k < 4; k++) {
        acc[k][0] += xsv[bb] * wsx[k];
        acc[k][1] += vv[bb][0] * wvx[k];
        acc[k][2] += vv[bb][1] * wvx[k];
        acc[k][3] += vv[bb][2] * wvx[k];
      }
    }
  }
  const float sc = 0.088388347648318447f;  // 1/sqrt(128)
#pragma unroll
  for (int k = 0; k < 4; k++) {
    float4 o;
    o.x = acc[k][0] * sc; o.y = acc[k][1] * sc;
    o.z = acc[k][2] * sc; o.w = acc[k][3] * sc;
    hsv[(size_t)(b0 + n) * 32 + 4 * fq + k] = o;
  }
}

// ---------------- CSR build ----------------
__global__ __launch_bounds__(256) void k_count(const int* __restrict__ idx_i,
        int* __restrict__ cnt, int* __restrict__ pos) {
  int e = blockIdx.x * 256 + threadIdx.x;
  pos[e] = atomicAdd(cnt + idx_i[e], 1);
}

__global__ __launch_bounds__(256) void k_scan(const int* __restrict__ cnt,
        int* __restrict__ offs) {
  __shared__ int part[256];
  int t = threadIdx.x;
  int s = 0;
  for (int i = t * 64; i < t * 64 + 64; ++i) s += cnt[i];
  part[t] = s;
  __syncthreads();
  if (t == 0) {
    int run = 0;
    for (int i = 0; i < 256; i++) { int v = part[i]; part[i] = run; run += v; }
    offs[NN] = run;
  }
  __syncthreads();
  int run = part[t];
  for (int i = t * 64; i < t * 64 + 64; ++i) { offs[i] = run; run += cnt[i]; }
}

// CSR permutation: slot_of_e (for wab scatter-write) + idx_j/Yr slot streams
__global__ __launch_bounds__(256) void k_fill(const int* __restrict__ idx_i,
        const int* __restrict__ idx_j, const float* __restrict__ Yr,
        const int* __restrict__ pos, const int* __restrict__ offs,
        int* __restrict__ slot_of_e, int* __restrict__ idxj_csr,
        float4* __restrict__ Yr_csr) {
  int e = blockIdx.x * 256 + threadIdx.x;
  int slot = offs[idx_i[e]] + pos[e];
  slot_of_e[e] = slot;
  idxj_csr[slot] = idx_j[e];
  Yr_csr[slot] = *(const float4*)(Yr + (size_t)e * 4);
}

// ---------------- fused vector output weight: Wv = w1v @ w2v * 1/sqrt(64*128) ----------------
__global__ __launch_bounds__(256) void k_wv(const float* __restrict__ w1v,
        const float* __restrict__ w2v, float* __restrict__ Wv) {
  int o = blockIdx.x * 256 + threadIdx.x;   // 8192
  int m = o >> 7, d = o & 127;
  float s = 0.f;
  for (int b = 0; b < 128; b++) s += w1v[m * 128 + b] * w2v[b * 128 + d];
  Wv[o] = s * 0.011048543456039804f;
}

// ---------------- k_prep: W2c^T in bf16, [col][k] layout for MFMA B frags ----
__global__ __launch_bounds__(256) void k_prep(const float* __restrict__ W2,
        unsigned short* __restrict__ BTbf) {
  int i = blockIdx.x * 256 + threadIdx.x;   // 4096
  int col = i >> 5, k = i & 31;
  BTbf[col * 32 + k] = pack_bf1(W2[k * 192 + 6 * (col >> 2) + (col & 3)]);
}

// ---------------- k_wab: h (fp32 VALU) then MFMA bf16 GEMM h@W2c, CSR scatter ----
// Block = 128 edges. Phase1: h=ssp(fij@W1+b1) -> bf16 LDS [128][40].
// Phase2: 64x mfma_f32_16x16x32_bf16 (16/wave), +bias, *rcut, bf16 -> stage.
// Phase3: 128B-chunk scatter to Wab[slot].
__global__ __launch_bounds__(256, 2) void k_wab(
        const float* __restrict__ fij, const float* __restrict__ rcut,
        const int* __restrict__ slot_of_e,
        const float* __restrict__ W1, const float* __restrict__ b1,
        const unsigned short* __restrict__ BTbf, const float* __restrict__ b2,
        unsigned int* __restrict__ Wab) {
  __shared__ float sW1[640];
  __shared__ float sb1[32];
  __shared__ float sb2c[128];
  __shared__ float srct[128];
  __shared__ int sslot[128];
  __shared__ unsigned short hbf[128 * 40];    // [edge][k], 80B rows (16B-align)
  __shared__ unsigned short sBT[128 * 40];    // [col][k]
  __shared__ unsigned short stage[128 * 136]; // [edge][col], 272B rows
  int t = threadIdx.x;
  size_t e0 = (size_t)blockIdx.x * 128;       // 2048 blocks
  for (int i = t; i < 640; i += 256) sW1[i] = W1[i];
  if (t < 32) sb1[t] = b1[t];
  if (t < 128) {
    sb2c[t] = b2[6 * (t >> 2) + (t & 3)];
    srct[t] = rcut[e0 + t];
    sslot[t] = slot_of_e[e0 + t];
  }
  {
    unsigned int* dst = (unsigned int*)sBT;
    const unsigned int* src = (const unsigned int*)BTbf;
    for (int i = t; i < 2048; i += 256) {
      int col = i >> 4, kp = i & 15;
      dst[col * 20 + kp] = src[i];
    }
  }
  __syncthreads();
  // ---- phase 1: h rows, 2 threads/edge (16 fp each) ----
  {
    int el = t >> 1, fp0 = (t & 1) * 16;
    const float* fr = fij + (e0 + el) * 20;
    float acc[16];
#pragma unroll
    for (int i = 0; i < 16; i++) acc[i] = sb1[fp0 + i];
    for (int r = 0; r < 20; r++) {
      float fe = fr[r];
      float4 wA = *(const float4*)(sW1 + r * 32 + fp0);
      float4 wB = *(const float4*)(sW1 + r * 32 + fp0 + 4);
      float4 wC = *(const float4*)(sW1 + r * 32 + fp0 + 8);
      float4 wD = *(const float4*)(sW1 + r * 32 + fp0 + 12);
      acc[0] += fe * wA.x;  acc[1] += fe * wA.y;
      acc[2] += fe * wA.z;  acc[3] += fe * wA.w;
      acc[4] += fe * wB.x;  acc[5] += fe * wB.y;
      acc[6] += fe * wB.z;  acc[7] += fe * wB.w;
      acc[8] += fe * wC.x;  acc[9] += fe * wC.y;
      acc[10] += fe * wC.z; acc[11] += fe * wC.w;
      acc[12] += fe * wD.x; acc[13] += fe * wD.y;
      acc[14] += fe * wD.z; acc[15] += fe * wD.w;
    }
    unsigned int* hw = (unsigned int*)hbf;
#pragma unroll
    for (int i = 0; i < 8; i++)
      hw[el * 20 + (fp0 >> 1) + i] =
          pack_bf2(sspf(acc[2 * i]), sspf(acc[2 * i + 1]));
  }
  __syncthreads();
  // ---- phase 2: MFMA GEMM ----
  {
    int w = t >> 6, l = t & 63;
    int lrow = l & 15, lkb = (l >> 4) * 16;   // k-group byte offset (8 bf16)
    const char* hb = (const char*)hbf;
    const char* bb = (const char*)sBT;
#pragma unroll
    for (int g = 0; g < 2; g++) {
      bf16x8 bfr[4];
#pragma unroll
      for (int c = 0; c < 4; c++) {
        int col = (4 * g + c) * 16 + lrow;
        bfr[c] = *(const bf16x8*)(bb + col * 80 + lkb);
      }
      f32x4 acc[2][4];
#pragma unroll
      for (int rt = 0; rt < 2; rt++) {
        int row = w * 32 + rt * 16 + lrow;
        bf16x8 af = *(const bf16x8*)(hb + row * 80 + lkb);
#pragma unroll
        for (int c = 0; c < 4; c++) {
          f32x4 z = {0.f, 0.f, 0.f, 0.f};
          acc[rt][c] = __builtin_amdgcn_mfma_f32_16x16x32_bf16(
              af, bfr[c], z, 0, 0, 0);
        }
      }
      // epilogue: +bias, *rcut, bf16 into stage
#pragma unroll
      for (int rt = 0; rt < 2; rt++)
#pragma unroll
        for (int c = 0; c < 4; c++) {
          int col = (4 * g + c) * 16 + lrow;
          float bias = sb2c[col];
          int rbase = w * 32 + rt * 16 + (l >> 4) * 4;
#pragma unroll
          for (int r = 0; r < 4; r++) {
            int row = rbase + r;
            float v = (acc[rt][c][r] + bias) * srct[row];
            stage[row * 136 + col] = pack_bf1(v);
          }
        }
    }
  }
  __syncthreads();
  // ---- phase 3: 128B-chunk scatter to CSR slots ----
  {
    int row = t >> 1, half = t & 1;
    const uint4* src = (const uint4*)((const char*)stage + row * 272 + half * 128);
    uint4* dst = (uint4*)(Wab + (size_t)sslot[row] * 64 + half * 32);
#pragma unroll
    for (int i = 0; i < 8; i++) dst[i] = src[i];
  }
}

// ---------------- k_agg3: one wave per node; sequential bf16 Wab stream ------
__global__ __launch_bounds__(256, 4) void k_agg3(
        const unsigned int* __restrict__ Wu, const int* __restrict__ idxj_csr,
        const float4* __restrict__ Yr_csr, const float4* __restrict__ hsv,
        const int* __restrict__ offs, float* __restrict__ nagg) {
  int t = threadIdx.x;
  int w = t >> 6, l = t & 63;
  int n = blockIdx.x * 4 + w;          // 4096 blocks
  int f = l >> 1, kb = (l & 1) * 2;
  int start = offs[n], end = offs[n + 1];
  float a0 = 0, a1 = 0, a2 = 0, a3 = 0, a4 = 0, a5 = 0;
  if (start < end) {
    int last = end - 1;
    int i1 = start + 1 < last ? start + 1 : last;
    int i2 = start + 2 < last ? start + 2 : last;
    int j0 = idxj_csr[start];
    int j1 = idxj_csr[i1];
    int j2 = idxj_csr[i2];
    float4 y0 = Yr_csr[start];
    float4 sv0 = hsv[(size_t)j0 * 32 + f];
    float4 sv1 = hsv[(size_t)j1 * 32 + f];
    unsigned int W0 = Wu[(size_t)start * 64 + l];
    unsigned int W1 = Wu[(size_t)i1 * 64 + l];
    for (int ei = start; ei < end; ++ei) {
      int in1 = ei + 1 < last ? ei + 1 : last;
      int in2 = ei + 2 < last ? ei + 2 : last;
      int in3 = ei + 3 < last ? ei + 3 : last;
      float4 sv2 = hsv[(size_t)j2 * 32 + f];       // depth-2 (random)
      unsigned int W2r = Wu[(size_t)in2 * 64 + l]; // depth-2 (sequential)
      float4 y1 = Yr_csr[in1];                     // depth-1 (sequential)
      int j3 = idxj_csr[in3];                      // depth-3 (sequential)
      float Wx = __uint_as_float(W0 << 16);
      float Wy = __uint_as_float(W0 & 0xffff0000u);
      float ys = y0.x, yx = y0.y, yy = y0.z, yz = y0.w;
      float ss = sv0.x, vx = sv0.y, vy = sv0.z, vz = sv0.w;
      if (kb == 0) {
        a0 += ss * ys * Wx;                                          // ch0
        a1 += (vx * yx + vy * yy + vz * yz) * 0.57735026918962576f * Wy; // ch1
      } else {
        a0 += ss * yx * Wx; a1 += ss * yy * Wx; a2 += ss * yz * Wx; // t_v1
        a3 += vx * ys * Wy; a4 += vy * ys * Wy; a5 += vz * ys * Wy; // t_v2
      }
      y0 = y1; sv0 = sv1; sv1 = sv2; W0 = W1; W1 = W2r; j2 = j3;
    }
  }
  float* na = nagg + (size_t)n * 256;
  if (kb == 0) {
    na[f] = a0;
    na[32 + f] = a1;
  } else {
    na[64 + 3 * f + 0] = a0;  na[64 + 3 * f + 1] = a1;  na[64 + 3 * f + 2] = a2;
    na[160 + 3 * f + 0] = a3; na[160 + 3 * f + 1] = a4; na[160 + 3 * f + 2] = a5;
  }
}

// ---------------- output GEMMs: W in LDS [k][d], A in register tiles ----------------
__global__ __launch_bounds__(256) void k_os1(const float* __restrict__ na,
        const float* __restrict__ w1s, float* __restrict__ os1) {
  __shared__ float sw[8192];       // w1s [64][128]
  int t = threadIdx.x;
  for (int i = t; i < 8192; i += 256) sw[i] = w1s[i];
  __syncthreads();
  int dg = t & 31, ng = t >> 5;
  int d0 = dg * 4;
  int n0 = blockIdx.x * 32 + ng * 4;      // grid 512
  const float* ap = na + (size_t)n0 * 256;
  float acc[4][4] = {};
#pragma unroll
  for (int kq = 0; kq < 16; kq++) {
    float4 a[4];
#pragma unroll
    for (int j = 0; j < 4; j++) a[j] = *(const float4*)(ap + j * 256 + 4 * kq);
    float4 w0 = *(const float4*)(sw + (4 * kq + 0) * 128 + d0);
    float4 w1 = *(const float4*)(sw + (4 * kq + 1) * 128 + d0);
    float4 w2 = *(const float4*)(sw + (4 * kq + 2) * 128 + d0);
    float4 w3 = *(const float4*)(sw + (4 * kq + 3) * 128 + d0);
#pragma unroll
    for (int j = 0; j < 4; j++) {
      acc[j][0] += a[j].x * w0.x + a[j].y * w1.x + a[j].z * w2.x + a[j].w * w3.x;
      acc[j][1] += a[j].x * w0.y + a[j].y * w1.y + a[j].z * w2.y + a[j].w * w3.y;
      acc[j][2] += a[j].x * w0.z + a[j].y * w1.z + a[j].z * w2.z + a[j].w * w3.z;
      acc[j][3] += a[j].x * w0.w + a[j].y * w1.w + a[j].z * w2.w + a[j].w * w3.w;
    }
  }
#pragma unroll
  for (int j = 0; j < 4; j++) {
    float4 o;
    o.x = sspf(acc[j][0] * 0.125f);   // 1/sqrt(64)
    o.y = sspf(acc[j][1] * 0.125f);
    o.z = sspf(acc[j][2] * 0.125f);
    o.w = sspf(acc[j][3] * 0.125f);
    *(float4*)(os1 + (size_t)(n0 + j) * 128 + d0) = o;
  }
}

__global__ __launch_bounds__(256) void k_os2(const float* __restrict__ os1,
        const float* __restrict__ w2s, float* __restrict__ out) {
  __shared__ float sw[16384];      // w2s [128][128] = 64 KB
  int t = threadIdx.x;
  for (int i = t; i < 16384; i += 256) sw[i] = w2s[i];
  __syncthreads();
  int dg = t & 31, ng = t >> 5;
  int d0 = dg * 4;
  int n0 = blockIdx.x * 32 + ng * 4;      // grid 512
  const float* ap = os1 + (size_t)n0 * 128;
  float acc[4][4] = {};
#pragma unroll
  for (int kq = 0; kq < 32; kq++) {
    float4 a[4];
#pragma unroll
    for (int j = 0; j < 4; j++) a[j] = *(const float4*)(ap + j * 128 + 4 * kq);
    float4 w0 = *(const float4*)(sw + (4 * kq + 0) * 128 + d0);
    float4 w1 = *(const float4*)(sw + (4 * kq + 1) * 128 + d0);
    float4 w2 = *(const float4*)(sw + (4 * kq + 2) * 128 + d0);
    float4 w3 = *(const float4*)(sw + (4 * kq + 3) * 128 + d0);
#pragma unroll
    for (int j = 0; j < 4; j++) {
      acc[j][0] += a[j].x * w0.x + a[j].y * w1.x + a[j].z * w2.x + a[j].w * w3.x;
      acc[j][1] += a[j].x * w0.y + a[j].y * w1.y + a[j].z * w2.y + a[j].w * w3.y;
      acc[j][2] += a[j].x * w0.z + a[j].y * w1.z + a[j].z * w2.z + a[j].w * w3.z;
      acc[j][3] += a[j].x * w0.w + a[j].y * w1.w + a[j].z * w2.w + a[j].w * w3.w;
    }
  }
  const float sc = 0.088388347648318447f;   // 1/sqrt(128)
#pragma unroll
  for (int j = 0; j < 4; j++) {
    float4 o;
    o.x = acc[j][0] * sc; o.y = acc[j][1] * sc;
    o.z = acc[j][2] * sc; o.w = acc[j][3] * sc;
    *(float4*)(out + (size_t)(n0 + j) * 512 + d0) = o;
  }
}

// thread = 2 nodes x 4 d x 3 comps
__global__ __launch_bounds__(256) void k_ov(const float* __restrict__ na,
        const float* __restrict__ Wv, float* __restrict__ out) {
  __shared__ float sw[8192];       // Wv [64][128]
  int t = threadIdx.x;
  for (int i = t; i < 8192; i += 256) sw[i] = Wv[i];
  __syncthreads();
  int dg = t & 31, ng = t >> 5;
  int d0 = dg * 4;
  int n0 = blockIdx.x * 16 + ng * 2;      // grid 1024
  const float* ap = na + (size_t)n0 * 256 + 64;   // v_in row: 192 contiguous
  float acc[2][12] = {};
#pragma unroll
  for (int mq = 0; mq < 16; mq++) {
    float4 p[2][3];
#pragma unroll
    for (int j = 0; j < 2; j++) {
      p[j][0] = *(const float4*)(ap + j * 256 + 12 * mq);
      p[j][1] = *(const float4*)(ap + j * 256 + 12 * mq + 4);
      p[j][2] = *(const float4*)(ap + j * 256 + 12 * mq + 8);
    }
    float4 w0 = *(const float4*)(sw + (4 * mq + 0) * 128 + d0);
    float4 w1 = *(const float4*)(sw + (4 * mq + 1) * 128 + d0);
    float4 w2 = *(const float4*)(sw + (4 * mq + 2) * 128 + d0);
    float4 w3 = *(const float4*)(sw + (4 * mq + 3) * 128 + d0);
#pragma unroll
    for (int j = 0; j < 2; j++) {
      float vm[4][3];
      vm[0][0] = p[j][0].x; vm[0][1] = p[j][0].y; vm[0][2] = p[j][0].z;
      vm[1][0] = p[j][0].w; vm[1][1] = p[j][1].x; vm[1][2] = p[j][1].y;
      vm[2][0] = p[j][1].z; vm[2][1] = p[j][1].w; vm[2][2] = p[j][2].x;
      vm[3][0] = p[j][2].y; vm[3][1] = p[j][2].z; vm[3][2] = p[j][2].w;
      float wm[4][4];
      wm[0][0] = w0.x; wm[0][1] = w0.y; wm[0][2] = w0.z; wm[0][3] = w0.w;
      wm[1][0] = w1.x; wm[1][1] = w1.y; wm[1][2] = w1.z; wm[1][3] = w1.w;
      wm[2][0] = w2.x; wm[2][1] = w2.y; wm[2][2] = w2.z; wm[2][3] = w2.w;
      wm[3][0] = w3.x; wm[3][1] = w3.y; wm[3][2] = w3.z; wm[3][3] = w3.w;
#pragma unroll
      for (int m = 0; m < 4; m++)
#pragma unroll
        for (int i = 0; i < 4; i++)
#pragma unroll
          for (int c = 0; c < 3; c++)
            acc[j][i * 3 + c] += vm[m][c] * wm[m][i];
    }
  }
#pragma unroll
  for (int j = 0; j < 2; j++) {
    float* op = out + (size_t)(n0 + j) * 512 + 128 + 12 * dg;
    float4 o0, o1, o2;
    o0.x = acc[j][0]; o0.y = acc[j][1]; o0.z = acc[j][2]; o0.w = acc[j][3];
    o1.x = acc[j][4]; o1.y = acc[j][5]; o1.z = acc[j][6]; o1.w = acc[j][7];
    o2.x = acc[j][8]; o2.y = acc[j][9]; o2.z = acc[j][10]; o2.w = acc[j][11];
    *(float4*)op = o0;
    *(float4*)(op + 4) = o1;
    *(float4*)(op + 8) = o2;
  }
}

extern "C" void kernel_launch(void* const* d_in, const int* in_sizes, int n_in,
                              void* d_out, int out_size, void* d_ws, size_t ws_size,
                              hipStream_t stream) {
  const float* x    = (const float*)d_in[0];
  const int*   idx_i = (const int*)d_in[1];
  const int*   idx_j = (const int*)d_in[2];
  const float* fij  = (const float*)d_in[3];
  const float* rcut = (const float*)d_in[4];
  const float* Yr   = (const float*)d_in[5];
  const float* w_s  = (const float*)d_in[6];
  const float* w_v  = (const float*)d_in[7];
  const float* W1   = (const float*)d_in[8];
  const float* b1   = (const float*)d_in[9];
  const float* W2   = (const float*)d_in[10];
  const float* b2   = (const float*)d_in[11];
  const float* w1s  = (const float*)d_in[12];
  const float* w1v  = (const float*)d_in[13];
  const float* w2s  = (const float*)d_in[14];
  const float* w2v  = (const float*)d_in[15];
  float* out = (float*)d_out;

  char* ws = (char*)d_ws;
  size_t off = 0;
  auto alloc = [&](size_t bytes) {
    void* p = ws + off;
    off += (bytes + 255) & ~(size_t)255;
    return p;
  };
  float4* hsv   = (float4*)alloc((size_t)NN * 32 * 16);
  float*  nagg  = (float*)alloc((size_t)NN * 256 * 4);
  unsigned int* Wab = (unsigned int*)alloc((size_t)EE * 128 * 2);  // bf16, 67 MB
  float*  os1   = (float*)alloc((size_t)NN * 128 * 4);
  float4* Yr_csr = (float4*)alloc((size_t)EE * 16);
  int* idxj_csr = (int*)alloc((size_t)EE * 4);
  int* slot_of_e = (int*)alloc((size_t)EE * 4);
  float* Wv     = (float*)alloc((size_t)8192 * 4);
  unsigned short* BTbf = (unsigned short*)alloc((size_t)4096 * 2);
  int* cnt      = (int*)alloc((size_t)NN * 4);
  int* offs     = (int*)alloc((size_t)(NN + 1) * 4);
  int* pos      = (int*)alloc((size_t)EE * 4);

  hipMemsetAsync(cnt, 0, (size_t)NN * 4, stream);
  k_count<<<EE / 256, 256, 0, stream>>>(idx_i, cnt, pos);
  k_scan<<<1, 256, 0, stream>>>(cnt, offs);
  k_fill<<<EE / 256, 256, 0, stream>>>(idx_i, idx_j, Yr, pos, offs,
                                       slot_of_e, idxj_csr, Yr_csr);
  k_embed<<<NN / 32, 256, 0, stream>>>(x, w_s, w_v, hsv);
  k_wv<<<32, 256, 0, stream>>>(w1v, w2v, Wv);
  k_prep<<<16, 256, 0, stream>>>(W2, BTbf);
  k_wab<<<EE / 128, 256, 0, stream>>>(fij, rcut, slot_of_e, W1, b1, BTbf, b2, Wab);
  k_agg3<<<NN / 4, 256, 0, stream>>>(Wab, idxj_csr, Yr_csr, hsv, offs, nagg);
  k_os1<<<512, 256, 0, stream>>>(nagg, w1s, os1);
  k_os2<<<512, 256, 0, stream>>>(os1, w2s, out);
  k_ov<<<1024, 256, 0, stream>>>(nagg, Wv, out);
}

// Round 14
// 219.035 us; speedup vs baseline: 1.5972x; 1.0028x over previous
//
#include <hip/hip_runtime.h>
#include <math.h>

#define NN 16384
#define BB 128
#define FF 32
#define RR 20
#define EE 262144

typedef __attribute__((ext_vector_type(8))) short bf16x8;
typedef __attribute__((ext_vector_type(4))) float f32x4;

__device__ __forceinline__ float sspf(float x) {
  // softplus(x) - log(2), numerically stable
  return fmaxf(x, 0.0f) + log1pf(expf(-fabsf(x))) - 0.69314718055994531f;
}

// pack two floats to bf16x2 (RNE)
__device__ __forceinline__ unsigned int pack_bf2(float a, float b) {
  unsigned int ua = __float_as_uint(a);
  ua = (ua + 0x7fffu + ((ua >> 16) & 1u)) >> 16;
  unsigned int ub = __float_as_uint(b);
  ub = (ub + 0x7fffu + ((ub >> 16) & 1u)) & 0xffff0000u;
  return ua | ub;
}

__device__ __forceinline__ unsigned short pack_bf1(float a) {
  unsigned int ua = __float_as_uint(a);
  ua = (ua + 0x7fffu + ((ua >> 16) & 1u)) >> 16;
  return (unsigned short)ua;
}

// ---------------- K1: node embeddings, x rows staged in LDS ----------------
__global__ __launch_bounds__(256) void k_embed(const float* __restrict__ x,
        const float* __restrict__ ws, const float* __restrict__ wv,
        float4* __restrict__ hsv) {
  __shared__ float sx[32 * 516];   // 66 KB
  int t = threadIdx.x;
  int b0 = blockIdx.x * 32;        // 512 blocks
  const float4* xg = (const float4*)(x + (size_t)b0 * 512);
  for (int i = t; i < 4096; i += 256) {
    int row = i >> 7, col = i & 127;
    *(float4*)(sx + row * 516 + col * 4) = xg[i];
  }
  __syncthreads();
  int n = t >> 3, fq = t & 7;
  const float* xr = sx + n * 516;
  float acc[4][4];
#pragma unroll
  for (int k = 0; k < 4; k++)
#pragma unroll
    for (int c = 0; c < 4; c++) acc[k][c] = 0.f;
  for (int bq = 0; bq < 32; bq++) {
    float4 xs4 = *(const float4*)(xr + 4 * bq);
    float4 a0 = *(const float4*)(xr + 128 + 12 * bq);
    float4 a1 = *(const float4*)(xr + 128 + 12 * bq + 4);
    float4 a2 = *(const float4*)(xr + 128 + 12 * bq + 8);
    float xsv[4] = {xs4.x, xs4.y, xs4.z, xs4.w};
    float vv[4][3];
    vv[0][0] = a0.x; vv[0][1] = a0.y; vv[0][2] = a0.z;
    vv[1][0] = a0.w; vv[1][1] = a1.x; vv[1][2] = a1.y;
    vv[2][0] = a1.z; vv[2][1] = a1.w; vv[2][2] = a2.x;
    vv[3][0] = a2.y; vv[3][1] = a2.z; vv[3][2] = a2.w;
#pragma unroll
    for (int bb = 0; bb < 4; bb++) {
      int b = 4 * bq + bb;
      float4 w_s = *(const float4*)(ws + b * 32 + 4 * fq);
      float4 w_v = *(const float4*)(wv + b * 32 + 4 * fq);
      float wsx[4] = {w_s.x, w_s.y, w_s.z, w_s.w};
      float wvx[4] = {w_v.x, w_v.y, w_v.z, w_v.w};
#pragma unroll
      for (int k = 0; k < 4; k++) {
        acc[k][0] += xsv[bb] * wsx[k];
        acc[k][1] += vv[bb][0] * wvx[k];
        acc[k][2] += vv[bb][1] * wvx[k];
        acc[k][3] += vv[bb][2] * wvx[k];
      }
    }
  }
  const float sc = 0.088388347648318447f;  // 1/sqrt(128)
#pragma unroll
  for (int k = 0; k < 4; k++) {
    float4 o;
    o.x = acc[k][0] * sc; o.y = acc[k][1] * sc;
    o.z = acc[k][2] * sc; o.w = acc[k][3] * sc;
    hsv[(size_t)(b0 + n) * 32 + 4 * fq + k] = o;
  }
}

// ---------------- CSR build ----------------
__global__ __launch_bounds__(256) void k_count(const int* __restrict__ idx_i,
        int* __restrict__ cnt, int* __restrict__ pos) {
  int e = blockIdx.x * 256 + threadIdx.x;
  pos[e] = atomicAdd(cnt + idx_i[e], 1);
}

__global__ __launch_bounds__(256) void k_scan(const int* __restrict__ cnt,
        int* __restrict__ offs) {
  __shared__ int part[256];
  int t = threadIdx.x;
  int s = 0;
  for (int i = t * 64; i < t * 64 + 64; ++i) s += cnt[i];
  part[t] = s;
  __syncthreads();
  if (t == 0) {
    int run = 0;
    for (int i = 0; i < 256; i++) { int v = part[i]; part[i] = run; run += v; }
    offs[NN] = run;
  }
  __syncthreads();
  int run = part[t];
  for (int i = t * 64; i < t * 64 + 64; ++i) { offs[i] = run; run += cnt[i]; }
}

// CSR permutation: slot_of_e (for wab scatter-write) + idx_j/Yr slot streams
__global__ __launch_bounds__(256) void k_fill(const int* __restrict__ idx_i,
        const int* __restrict__ idx_j, const float* __restrict__ Yr,
        const int* __restrict__ pos, const int* __restrict__ offs,
        int* __restrict__ slot_of_e, int* __restrict__ idxj_csr,
        float4* __restrict__ Yr_csr) {
  int e = blockIdx.x * 256 + threadIdx.x;
  int slot = offs[idx_i[e]] + pos[e];
  slot_of_e[e] = slot;
  idxj_csr[slot] = idx_j[e];
  Yr_csr[slot] = *(const float4*)(Yr + (size_t)e * 4);
}

// ---------------- fused vector output weight: Wv = w1v @ w2v * 1/sqrt(64*128) ----------------
__global__ __launch_bounds__(256) void k_wv(const float* __restrict__ w1v,
        const float* __restrict__ w2v, float* __restrict__ Wv) {
  int o = blockIdx.x * 256 + threadIdx.x;   // 8192
  int m = o >> 7, d = o & 127;
  float s = 0.f;
  for (int b = 0; b < 128; b++) s += w1v[m * 128 + b] * w2v[b * 128 + d];
  Wv[o] = s * 0.011048543456039804f;
}

// ---------------- k_prep: W2c^T in bf16, [col][k] layout for MFMA B frags ----
__global__ __launch_bounds__(256) void k_prep(const float* __restrict__ W2,
        unsigned short* __restrict__ BTbf) {
  int i = blockIdx.x * 256 + threadIdx.x;   // 4096
  int col = i >> 5, k = i & 31;
  BTbf[col * 32 + k] = pack_bf1(W2[k * 192 + 6 * (col >> 2) + (col & 3)]);
}

// ---------------- k_wab: h (fp32 VALU) then MFMA bf16 GEMM h@W2c, CSR scatter ----
// Block = 128 edges. sfij (coalesced stage) ALIASES the scatter stage buffer;
// B fragments load straight from global (coalesced 1KB/wave, L2-hot).
// LDS ~49.3 KB -> 3 blocks/CU.
__global__ __launch_bounds__(256, 2) void k_wab(
        const float* __restrict__ fij, const float* __restrict__ rcut,
        const int* __restrict__ slot_of_e,
        const float* __restrict__ W1, const float* __restrict__ b1,
        const unsigned short* __restrict__ BTbf, const float* __restrict__ b2,
        unsigned int* __restrict__ Wab) {
  __shared__ char smem[34816];                // union: sfij (10.4K) / stage (34.8K)
  __shared__ unsigned short hbf[128 * 40];    // [edge][k], 80B rows
  __shared__ float sW1[640];
  __shared__ float sb1[32];
  __shared__ float sb2c[128];
  __shared__ float srct[128];
  __shared__ int sslot[128];
  float* sfij = (float*)smem;                 // [r][130], phases 0-1
  unsigned short* stage = (unsigned short*)smem; // [edge][136], phases 2-3
  int t = threadIdx.x;
  size_t e0 = (size_t)blockIdx.x * 128;       // 2048 blocks
  for (int i = t; i < 640; i += 256) sW1[i] = W1[i];
  if (t < 32) sb1[t] = b1[t];
  if (t < 128) {
    sb2c[t] = b2[6 * (t >> 2) + (t & 3)];
    srct[t] = rcut[e0 + t];
    sslot[t] = slot_of_e[e0 + t];
  }
  for (int i = t; i < 2560; i += 256) {
    int el = i / 20, r = i - el * 20;
    sfij[r * 130 + el] = fij[e0 * 20 + i];    // coalesced global read
  }
  __syncthreads();
  // ---- phase 1: h rows, 2 threads/edge (16 fp each) ----
  {
    int el = t >> 1, fp0 = (t & 1) * 16;
    float acc[16];
#pragma unroll
    for (int i = 0; i < 16; i++) acc[i] = sb1[fp0 + i];
#pragma unroll
    for (int r = 0; r < 20; r++) {
      float fe = sfij[r * 130 + el];
      float4 wA = *(const float4*)(sW1 + r * 32 + fp0);
      float4 wB = *(const float4*)(sW1 + r * 32 + fp0 + 4);
      float4 wC = *(const float4*)(sW1 + r * 32 + fp0 + 8);
      float4 wD = *(const float4*)(sW1 + r * 32 + fp0 + 12);
      acc[0] += fe * wA.x;  acc[1] += fe * wA.y;
      acc[2] += fe * wA.z;  acc[3] += fe * wA.w;
      acc[4] += fe * wB.x;  acc[5] += fe * wB.y;
      acc[6] += fe * wB.z;  acc[7] += fe * wB.w;
      acc[8] += fe * wC.x;  acc[9] += fe * wC.y;
      acc[10] += fe * wC.z; acc[11] += fe * wC.w;
      acc[12] += fe * wD.x; acc[13] += fe * wD.y;
      acc[14] += fe * wD.z; acc[15] += fe * wD.w;
    }
    unsigned int* hw = (unsigned int*)hbf;
#pragma unroll
    for (int i = 0; i < 8; i++)
      hw[el * 20 + (fp0 >> 1) + i] =
          pack_bf2(sspf(acc[2 * i]), sspf(acc[2 * i + 1]));
  }
  __syncthreads();    // sfij fully consumed; smem becomes stage
  // ---- phase 2: MFMA GEMM (B frags from global, coalesced, L2-hot) ----
  {
    int w = t >> 6, l = t & 63;
    int lrow = l & 15, lkq = (l >> 4) * 8;    // k-offset in shorts
    const char* hb = (const char*)hbf;
#pragma unroll
    for (int g = 0; g < 2; g++) {
      bf16x8 bfr[4];
#pragma unroll
      for (int c = 0; c < 4; c++) {
        int col = (4 * g + c) * 16 + lrow;
        bfr[c] = *(const bf16x8*)(BTbf + col * 32 + lkq);
      }
      f32x4 acc[2][4];
#pragma unroll
      for (int rt = 0; rt < 2; rt++) {
        int row = w * 32 + rt * 16 + lrow;
        bf16x8 af = *(const bf16x8*)(hb + row * 80 + lkq * 2);
#pragma unroll
        for (int c = 0; c < 4; c++) {
          f32x4 z = {0.f, 0.f, 0.f, 0.f};
          acc[rt][c] = __builtin_amdgcn_mfma_f32_16x16x32_bf16(
              af, bfr[c], z, 0, 0, 0);
        }
      }
      // epilogue: +bias, *rcut, bf16 into stage
#pragma unroll
      for (int rt = 0; rt < 2; rt++)
#pragma unroll
        for (int c = 0; c < 4; c++) {
          int col = (4 * g + c) * 16 + lrow;
          float bias = sb2c[col];
          int rbase = w * 32 + rt * 16 + (l >> 4) * 4;
#pragma unroll
          for (int r = 0; r < 4; r++) {
            int row = rbase + r;
            float v = (acc[rt][c][r] + bias) * srct[row];
            stage[row * 136 + col] = pack_bf1(v);
          }
        }
    }
  }
  __syncthreads();
  // ---- phase 3: 128B-chunk scatter to CSR slots ----
  {
    int row = t >> 1, half = t & 1;
    const uint4* src = (const uint4*)((const char*)stage + row * 272 + half * 128);
    uint4* dst = (uint4*)(Wab + (size_t)sslot[row] * 64 + half * 32);
#pragma unroll
    for (int i = 0; i < 8; i++) dst[i] = src[i];
  }
}

// ---------------- k_agg3: one wave per node; sequential bf16 Wab stream ------
__global__ __launch_bounds__(256, 4) void k_agg3(
        const unsigned int* __restrict__ Wu, const int* __restrict__ idxj_csr,
        const float4* __restrict__ Yr_csr, const float4* __restrict__ hsv,
        const int* __restrict__ offs, float* __restrict__ nagg) {
  int t = threadIdx.x;
  int w = t >> 6, l = t & 63;
  int n = blockIdx.x * 4 + w;          // 4096 blocks
  int f = l >> 1, kb = (l & 1) * 2;
  int start = offs[n], end = offs[n + 1];
  float a0 = 0, a1 = 0, a2 = 0, a3 = 0, a4 = 0, a5 = 0;
  if (start < end) {
    int last = end - 1;
    int i1 = start + 1 < last ? start + 1 : last;
    int i2 = start + 2 < last ? start + 2 : last;
    int j0 = idxj_csr[start];
    int j1 = idxj_csr[i1];
    int j2 = idxj_csr[i2];
    float4 y0 = Yr_csr[start];
    float4 sv0 = hsv[(size_t)j0 * 32 + f];
    float4 sv1 = hsv[(size_t)j1 * 32 + f];
    unsigned int W0 = Wu[(size_t)start * 64 + l];
    unsigned int W1 = Wu[(size_t)i1 * 64 + l];
    for (int ei = start; ei < end; ++ei) {
      int in1 = ei + 1 < last ? ei + 1 : last;
      int in2 = ei + 2 < last ? ei + 2 : last;
      int in3 = ei + 3 < last ? ei + 3 : last;
      float4 sv2 = hsv[(size_t)j2 * 32 + f];       // depth-2 (random)
      unsigned int W2r = Wu[(size_t)in2 * 64 + l]; // depth-2 (sequential)
      float4 y1 = Yr_csr[in1];                     // depth-1 (sequential)
      int j3 = idxj_csr[in3];                      // depth-3 (sequential)
      float Wx = __uint_as_float(W0 << 16);
      float Wy = __uint_as_float(W0 & 0xffff0000u);
      float ys = y0.x, yx = y0.y, yy = y0.z, yz = y0.w;
      float ss = sv0.x, vx = sv0.y, vy = sv0.z, vz = sv0.w;
      if (kb == 0) {
        a0 += ss * ys * Wx;                                          // ch0
        a1 += (vx * yx + vy * yy + vz * yz) * 0.57735026918962576f * Wy; // ch1
      } else {
        a0 += ss * yx * Wx; a1 += ss * yy * Wx; a2 += ss * yz * Wx; // t_v1
        a3 += vx * ys * Wy; a4 += vy * ys * Wy; a5 += vz * ys * Wy; // t_v2
      }
      y0 = y1; sv0 = sv1; sv1 = sv2; W0 = W1; W1 = W2r; j2 = j3;
    }
  }
  float* na = nagg + (size_t)n * 256;
  if (kb == 0) {
    na[f] = a0;
    na[32 + f] = a1;
  } else {
    na[64 + 3 * f + 0] = a0;  na[64 + 3 * f + 1] = a1;  na[64 + 3 * f + 2] = a2;
    na[160 + 3 * f + 0] = a3; na[160 + 3 * f + 1] = a4; na[160 + 3 * f + 2] = a5;
  }
}

// ---------------- output GEMMs: W in LDS [k][d], A in register tiles ----------------
__global__ __launch_bounds__(256) void k_os1(const float* __restrict__ na,
        const float* __restrict__ w1s, float* __restrict__ os1) {
  __shared__ float sw[8192];       // w1s [64][128]
  int t = threadIdx.x;
  for (int i = t; i < 8192; i += 256) sw[i] = w1s[i];
  __syncthreads();
  int dg = t & 31, ng = t >> 5;
  int d0 = dg * 4;
  int n0 = blockIdx.x * 32 + ng * 4;      // grid 512
  const float* ap = na + (size_t)n0 * 256;
  float acc[4][4] = {};
#pragma unroll
  for (int kq = 0; kq < 16; kq++) {
    float4 a[4];
#pragma unroll
    for (int j = 0; j < 4; j++) a[j] = *(const float4*)(ap + j * 256 + 4 * kq);
    float4 w0 = *(const float4*)(sw + (4 * kq + 0) * 128 + d0);
    float4 w1 = *(const float4*)(sw + (4 * kq + 1) * 128 + d0);
    float4 w2 = *(const float4*)(sw + (4 * kq + 2) * 128 + d0);
    float4 w3 = *(const float4*)(sw + (4 * kq + 3) * 128 + d0);
#pragma unroll
    for (int j = 0; j < 4; j++) {
      acc[j][0] += a[j].x * w0.x + a[j].y * w1.x + a[j].z * w2.x + a[j].w * w3.x;
      acc[j][1] += a[j].x * w0.y + a[j].y * w1.y + a[j].z * w2.y + a[j].w * w3.y;
      acc[j][2] += a[j].x * w0.z + a[j].y * w1.z + a[j].z * w2.z + a[j].w * w3.z;
      acc[j][3] += a[j].x * w0.w + a[j].y * w1.w + a[j].z * w2.w + a[j].w * w3.w;
    }
  }
#pragma unroll
  for (int j = 0; j < 4; j++) {
    float4 o;
    o.x = sspf(acc[j][0] * 0.125f);   // 1/sqrt(64)
    o.y = sspf(acc[j][1] * 0.125f);
    o.z = sspf(acc[j][2] * 0.125f);
    o.w = sspf(acc[j][3] * 0.125f);
    *(float4*)(os1 + (size_t)(n0 + j) * 128 + d0) = o;
  }
}

__global__ __launch_bounds__(256) void k_os2(const float* __restrict__ os1,
        const float* __restrict__ w2s, float* __restrict__ out) {
  __shared__ float sw[16384];      // w2s [128][128] = 64 KB
  int t = threadIdx.x;
  for (int i = t; i < 16384; i += 256) sw[i] = w2s[i];
  __syncthreads();
  int dg = t & 31, ng = t >> 5;
  int d0 = dg * 4;
  int n0 = blockIdx.x * 32 + ng * 4;      // grid 512
  const float* ap = os1 + (size_t)n0 * 128;
  float acc[4][4] = {};
#pragma unroll
  for (int kq = 0; kq < 32; kq++) {
    float4 a[4];
#pragma unroll
    for (int j = 0; j < 4; j++) a[j] = *(const float4*)(ap + j * 128 + 4 * kq);
    float4 w0 = *(const float4*)(sw + (4 * kq + 0) * 128 + d0);
    float4 w1 = *(const float4*)(sw + (4 * kq + 1) * 128 + d0);
    float4 w2 = *(const float4*)(sw + (4 * kq + 2) * 128 + d0);
    float4 w3 = *(const float4*)(sw + (4 * kq + 3) * 128 + d0);
#pragma unroll
    for (int j = 0; j < 4; j++) {
      acc[j][0] += a[j].x * w0.x + a[j].y * w1.x + a[j].z * w2.x + a[j].w * w3.x;
      acc[j][1] += a[j].x * w0.y + a[j].y * w1.y + a[j].z * w2.y + a[j].w * w3.y;
      acc[j][2] += a[j].x * w0.z + a[j].y * w1.z + a[j].z * w2.z + a[j].w * w3.z;
      acc[j][3] += a[j].x * w0.w + a[j].y * w1.w + a[j].z * w2.w + a[j].w * w3.w;
    }
  }
  const float sc = 0.088388347648318447f;   // 1/sqrt(128)
#pragma unroll
  for (int j = 0; j < 4; j++) {
    float4 o;
    o.x = acc[j][0] * sc; o.y = acc[j][1] * sc;
    o.z = acc[j][2] * sc; o.w = acc[j][3] * sc;
    *(float4*)(out + (size_t)(n0 + j) * 512 + d0) = o;
  }
}

// thread = 2 nodes x 4 d x 3 comps
__global__ __launch_bounds__(256) void k_ov(const float* __restrict__ na,
        const float* __restrict__ Wv, float* __restrict__ out) {
  __shared__ float sw[8192];       // Wv [64][128]
  int t = threadIdx.x;
  for (int i = t; i < 8192; i += 256) sw[i] = Wv[i];
  __syncthreads();
  int dg = t & 31, ng = t >> 5;
  int d0 = dg * 4;
  int n0 = blockIdx.x * 16 + ng * 2;      // grid 1024
  const float* ap = na + (size_t)n0 * 256 + 64;   // v_in row: 192 contiguous
  float acc[2][12] = {};
#pragma unroll
  for (int mq = 0; mq < 16; mq++) {
    float4 p[2][3];
#pragma unroll
    for (int j = 0; j < 2; j++) {
      p[j][0] = *(const float4*)(ap + j * 256 + 12 * mq);
      p[j][1] = *(const float4*)(ap + j * 256 + 12 * mq + 4);
      p[j][2] = *(const float4*)(ap + j * 256 + 12 * mq + 8);
    }
    float4 w0 = *(const float4*)(sw + (4 * mq + 0) * 128 + d0);
    float4 w1 = *(const float4*)(sw + (4 * mq + 1) * 128 + d0);
    float4 w2 = *(const float4*)(sw + (4 * mq + 2) * 128 + d0);
    float4 w3 = *(const float4*)(sw + (4 * mq + 3) * 128 + d0);
#pragma unroll
    for (int j = 0; j < 2; j++) {
      float vm[4][3];
      vm[0][0] = p[j][0].x; vm[0][1] = p[j][0].y; vm[0][2] = p[j][0].z;
      vm[1][0] = p[j][0].w; vm[1][1] = p[j][1].x; vm[1][2] = p[j][1].y;
      vm[2][0] = p[j][1].z; vm[2][1] = p[j][1].w; vm[2][2] = p[j][2].x;
      vm[3][0] = p[j][2].y; vm[3][1] = p[j][2].z; vm[3][2] = p[j][2].w;
      float wm[4][4];
      wm[0][0] = w0.x; wm[0][1] = w0.y; wm[0][2] = w0.z; wm[0][3] = w0.w;
      wm[1][0] = w1.x; wm[1][1] = w1.y; wm[1][2] = w1.z; wm[1][3] = w1.w;
      wm[2][0] = w2.x; wm[2][1] = w2.y; wm[2][2] = w2.z; wm[2][3] = w2.w;
      wm[3][0] = w3.x; wm[3][1] = w3.y; wm[3][2] = w3.z; wm[3][3] = w3.w;
#pragma unroll
      for (int m = 0; m < 4; m++)
#pragma unroll
        for (int i = 0; i < 4; i++)
#pragma unroll
          for (int c = 0; c < 3; c++)
            acc[j][i * 3 + c] += vm[m][c] * wm[m][i];
    }
  }
#pragma unroll
  for (int j = 0; j < 2; j++) {
    float* op = out + (size_t)(n0 + j) * 512 + 128 + 12 * dg;
    float4 o0, o1, o2;
    o0.x = acc[j][0]; o0.y = acc[j][1]; o0.z = acc[j][2]; o0.w = acc[j][3];
    o1.x = acc[j][4]; o1.y = acc[j][5]; o1.z = acc[j][6]; o1.w = acc[j][7];
    o2.x = acc[j][8]; o2.y = acc[j][9]; o2.z = acc[j][10]; o2.w = acc[j][11];
    *(float4*)op = o0;
    *(float4*)(op + 4) = o1;
    *(float4*)(op + 8) = o2;
  }
}

extern "C" void kernel_launch(void* const* d_in, const int* in_sizes, int n_in,
                              void* d_out, int out_size, void* d_ws, size_t ws_size,
                              hipStream_t stream) {
  const float* x    = (const float*)d_in[0];
  const int*   idx_i = (const int*)d_in[1];
  const int*   idx_j = (const int*)d_in[2];
  const float* fij  = (const float*)d_in[3];
  const float* rcut = (const float*)d_in[4];
  const float* Yr   = (const float*)d_in[5];
  const float* w_s  = (const float*)d_in[6];
  const float* w_v  = (const float*)d_in[7];
  const float* W1   = (const float*)d_in[8];
  const float* b1   = (const float*)d_in[9];
  const float* W2   = (const float*)d_in[10];
  const float* b2   = (const float*)d_in[11];
  const float* w1s  = (const float*)d_in[12];
  const float* w1v  = (const float*)d_in[13];
  const float* w2s  = (const float*)d_in[14];
  const float* w2v  = (const float*)d_in[15];
  float* out = (float*)d_out;

  char* ws = (char*)d_ws;
  size_t off = 0;
  auto alloc = [&](size_t bytes) {
    void* p = ws + off;
    off += (bytes + 255) & ~(size_t)255;
    return p;
  };
  float4* hsv   = (float4*)alloc((size_t)NN * 32 * 16);
  float*  nagg  = (float*)alloc((size_t)NN * 256 * 4);
  unsigned int* Wab = (unsigned int*)alloc((size_t)EE * 128 * 2);  // bf16, 67 MB
  float*  os1   = (float*)alloc((size_t)NN * 128 * 4);
  float4* Yr_csr = (float4*)alloc((size_t)EE * 16);
  int* idxj_csr = (int*)alloc((size_t)EE * 4);
  int* slot_of_e = (int*)alloc((size_t)EE * 4);
  float* Wv     = (float*)alloc((size_t)8192 * 4);
  unsigned short* BTbf = (unsigned short*)alloc((size_t)4096 * 2);
  int* cnt      = (int*)alloc((size_t)NN * 4);
  int* offs     = (int*)alloc((size_t)(NN + 1) * 4);
  int* pos      = (int*)alloc((size_t)EE * 4);

  hipMemsetAsync(cnt, 0, (size_t)NN * 4, stream);
  k_count<<<EE / 256, 256, 0, stream>>>(idx_i, cnt, pos);
  k_scan<<<1, 256, 0, stream>>>(cnt, offs);
  k_fill<<<EE / 256, 256, 0, stream>>>(idx_i, idx_j, Yr, pos, offs,
                                       slot_of_e, idxj_csr, Yr_csr);
  k_embed<<<NN / 32, 256, 0, stream>>>(x, w_s, w_v, hsv);
  k_wv<<<32, 256, 0, stream>>>(w1v, w2v, Wv);
  k_prep<<<16, 256, 0, stream>>>(W2, BTbf);
  k_wab<<<EE / 128, 256, 0, stream>>>(fij, rcut, slot_of_e, W1, b1, BTbf, b2, Wab);
  k_agg3<<<NN / 4, 256, 0, stream>>>(Wab, idxj_csr, Yr_csr, hsv, offs, nagg);
  k_os1<<<512, 256, 0, stream>>>(nagg, w1s, os1);
  k_os2<<<512, 256, 0, stream>>>(os1, w2s, out);
  k_ov<<<1024, 256, 0, stream>>>(nagg, Wv, out);
}

// Round 15
// 202.921 us; speedup vs baseline: 1.7241x; 1.0794x over previous
//
#include <hip/hip_runtime.h>
#include <math.h>

#define NN 16384
#define BB 128
#define FF 32
#define RR 20
#define EE 262144

typedef __attribute__((ext_vector_type(8))) short bf16x8;
typedef __attribute__((ext_vector_type(4))) float f32x4;

__device__ __forceinline__ float sspf(float x) {
  // softplus(x) - log(2) via HW v_exp/v_log: max(x,0) + (log2(1+e^-|x|)-1)*ln2
  float t = __expf(-fabsf(x));
  return fmaxf(x, 0.0f) + (__log2f(1.0f + t) - 1.0f) * 0.69314718055994531f;
}

// pack two floats to bf16x2 (RNE)
__device__ __forceinline__ unsigned int pack_bf2(float a, float b) {
  unsigned int ua = __float_as_uint(a);
  ua = (ua + 0x7fffu + ((ua >> 16) & 1u)) >> 16;
  unsigned int ub = __float_as_uint(b);
  ub = (ub + 0x7fffu + ((ub >> 16) & 1u)) & 0xffff0000u;
  return ua | ub;
}

__device__ __forceinline__ unsigned short pack_bf1(float a) {
  unsigned int ua = __float_as_uint(a);
  ua = (ua + 0x7fffu + ((ua >> 16) & 1u)) >> 16;
  return (unsigned short)ua;
}

// ---------------- K1: node embeddings, x rows staged in LDS ----------------
__global__ __launch_bounds__(256) void k_embed(const float* __restrict__ x,
        const float* __restrict__ ws, const float* __restrict__ wv,
        float4* __restrict__ hsv) {
  __shared__ float sx[32 * 516];   // 66 KB
  int t = threadIdx.x;
  int b0 = blockIdx.x * 32;        // 512 blocks
  const float4* xg = (const float4*)(x + (size_t)b0 * 512);
  for (int i = t; i < 4096; i += 256) {
    int row = i >> 7, col = i & 127;
    *(float4*)(sx + row * 516 + col * 4) = xg[i];
  }
  __syncthreads();
  int n = t >> 3, fq = t & 7;
  const float* xr = sx + n * 516;
  float acc[4][4];
#pragma unroll
  for (int k = 0; k < 4; k++)
#pragma unroll
    for (int c = 0; c < 4; c++) acc[k][c] = 0.f;
  for (int bq = 0; bq < 32; bq++) {
    float4 xs4 = *(const float4*)(xr + 4 * bq);
    float4 a0 = *(const float4*)(xr + 128 + 12 * bq);
    float4 a1 = *(const float4*)(xr + 128 + 12 * bq + 4);
    float4 a2 = *(const float4*)(xr + 128 + 12 * bq + 8);
    float xsv[4] = {xs4.x, xs4.y, xs4.z, xs4.w};
    float vv[4][3];
    vv[0][0] = a0.x; vv[0][1] = a0.y; vv[0][2] = a0.z;
    vv[1][0] = a0.w; vv[1][1] = a1.x; vv[1][2] = a1.y;
    vv[2][0] = a1.z; vv[2][1] = a1.w; vv[2][2] = a2.x;
    vv[3][0] = a2.y; vv[3][1] = a2.z; vv[3][2] = a2.w;
#pragma unroll
    for (int bb = 0; bb < 4; bb++) {
      int b = 4 * bq + bb;
      float4 w_s = *(const float4*)(ws + b * 32 + 4 * fq);
      float4 w_v = *(const float4*)(wv + b * 32 + 4 * fq);
      float wsx[4] = {w_s.x, w_s.y, w_s.z, w_s.w};
      float wvx[4] = {w_v.x, w_v.y, w_v.z, w_v.w};
#pragma unroll
      for (int k = 0; k < 4; k++) {
        acc[k][0] += xsv[bb] * wsx[k];
        acc[k][1] += vv[bb][0] * wvx[k];
        acc[k][2] += vv[bb][1] * wvx[k];
        acc[k][3] += vv[bb][2] * wvx[k];
      }
    }
  }
  const float sc = 0.088388347648318447f;  // 1/sqrt(128)
#pragma unroll
  for (int k = 0; k < 4; k++) {
    float4 o;
    o.x = acc[k][0] * sc; o.y = acc[k][1] * sc;
    o.z = acc[k][2] * sc; o.w = acc[k][3] * sc;
    hsv[(size_t)(b0 + n) * 32 + 4 * fq + k] = o;
  }
}

// ---------------- CSR build ----------------
__global__ __launch_bounds__(256) void k_count(const int* __restrict__ idx_i,
        int* __restrict__ cnt, int* __restrict__ pos) {
  int e = blockIdx.x * 256 + threadIdx.x;
  pos[e] = atomicAdd(cnt + idx_i[e], 1);
}

__global__ __launch_bounds__(256) void k_scan(const int* __restrict__ cnt,
        int* __restrict__ offs) {
  __shared__ int part[256];
  int t = threadIdx.x;
  int s = 0;
  for (int i = t * 64; i < t * 64 + 64; ++i) s += cnt[i];
  part[t] = s;
  __syncthreads();
  if (t == 0) {
    int run = 0;
    for (int i = 0; i < 256; i++) { int v = part[i]; part[i] = run; run += v; }
    offs[NN] = run;
  }
  __syncthreads();
  int run = part[t];
  for (int i = t * 64; i < t * 64 + 64; ++i) { offs[i] = run; run += cnt[i]; }
}

// CSR permutation: slot_of_e (for wab scatter-write) + idx_j/Yr slot streams
__global__ __launch_bounds__(256) void k_fill(const int* __restrict__ idx_i,
        const int* __restrict__ idx_j, const float* __restrict__ Yr,
        const int* __restrict__ pos, const int* __restrict__ offs,
        int* __restrict__ slot_of_e, int* __restrict__ idxj_csr,
        float4* __restrict__ Yr_csr) {
  int e = blockIdx.x * 256 + threadIdx.x;
  int slot = offs[idx_i[e]] + pos[e];
  slot_of_e[e] = slot;
  idxj_csr[slot] = idx_j[e];
  Yr_csr[slot] = *(const float4*)(Yr + (size_t)e * 4);
}

// ---------------- fused vector output weight: Wv = w1v @ w2v * 1/sqrt(64*128) ----------------
__global__ __launch_bounds__(256) void k_wv(const float* __restrict__ w1v,
        const float* __restrict__ w2v, float* __restrict__ Wv) {
  int o = blockIdx.x * 256 + threadIdx.x;   // 8192
  int m = o >> 7, d = o & 127;
  float s = 0.f;
  for (int b = 0; b < 128; b++) s += w1v[m * 128 + b] * w2v[b * 128 + d];
  Wv[o] = s * 0.011048543456039804f;
}

// ---------------- k_prep: W2c^T in bf16, [col][k] layout for MFMA frags ----
__global__ __launch_bounds__(256) void k_prep(const float* __restrict__ W2,
        unsigned short* __restrict__ BTbf) {
  int i = blockIdx.x * 256 + threadIdx.x;   // 4096
  int col = i >> 5, k = i & 31;
  BTbf[col * 32 + k] = pack_bf1(W2[k * 192 + 6 * (col >> 2) + (col & 3)]);
}

// ---------------- k_wab: h (fp32 VALU) then MFMA bf16 GEMM, CSR scatter ----
// Block = 128 edges. MFMA computed D[col][edge] (A=W2c^T frags, B=h frags):
// each lane owns 4 CONSECUTIVE cols of one edge -> vector epilogue + b64
// stage writes. sfij aliases stage. LDS ~49.3 KB.
__global__ __launch_bounds__(256, 2) void k_wab(
        const float* __restrict__ fij, const float* __restrict__ rcut,
        const int* __restrict__ slot_of_e,
        const float* __restrict__ W1, const float* __restrict__ b1,
        const unsigned short* __restrict__ BTbf, const float* __restrict__ b2,
        unsigned int* __restrict__ Wab) {
  __shared__ char smem[34816];                // union: sfij (10.4K) / stage (34.8K)
  __shared__ unsigned short hbf[128 * 40];    // [edge][k], 80B rows
  __shared__ float sW1[640];
  __shared__ float sb1[32];
  __shared__ float sb2c[128];
  __shared__ float srct[128];
  __shared__ int sslot[128];
  float* sfij = (float*)smem;                 // [r][130], phases 0-1
  unsigned short* stage = (unsigned short*)smem; // [edge][136], phases 2-3
  int t = threadIdx.x;
  size_t e0 = (size_t)blockIdx.x * 128;       // 2048 blocks
  for (int i = t; i < 640; i += 256) sW1[i] = W1[i];
  if (t < 32) sb1[t] = b1[t];
  if (t < 128) {
    sb2c[t] = b2[6 * (t >> 2) + (t & 3)];
    srct[t] = rcut[e0 + t];
    sslot[t] = slot_of_e[e0 + t];
  }
  for (int i = t; i < 2560; i += 256) {
    int el = i / 20, r = i - el * 20;
    sfij[r * 130 + el] = fij[e0 * 20 + i];    // coalesced global read
  }
  __syncthreads();
  // ---- phase 1: h rows, 2 threads/edge (16 fp each) ----
  {
    int el = t >> 1, fp0 = (t & 1) * 16;
    float acc[16];
#pragma unroll
    for (int i = 0; i < 16; i++) acc[i] = sb1[fp0 + i];
#pragma unroll
    for (int r = 0; r < 20; r++) {
      float fe = sfij[r * 130 + el];
      float4 wA = *(const float4*)(sW1 + r * 32 + fp0);
      float4 wB = *(const float4*)(sW1 + r * 32 + fp0 + 4);
      float4 wC = *(const float4*)(sW1 + r * 32 + fp0 + 8);
      float4 wD = *(const float4*)(sW1 + r * 32 + fp0 + 12);
      acc[0] += fe * wA.x;  acc[1] += fe * wA.y;
      acc[2] += fe * wA.z;  acc[3] += fe * wA.w;
      acc[4] += fe * wB.x;  acc[5] += fe * wB.y;
      acc[6] += fe * wB.z;  acc[7] += fe * wB.w;
      acc[8] += fe * wC.x;  acc[9] += fe * wC.y;
      acc[10] += fe * wC.z; acc[11] += fe * wC.w;
      acc[12] += fe * wD.x; acc[13] += fe * wD.y;
      acc[14] += fe * wD.z; acc[15] += fe * wD.w;
    }
    unsigned int* hw = (unsigned int*)hbf;
#pragma unroll
    for (int i = 0; i < 8; i++)
      hw[el * 20 + (fp0 >> 1) + i] =
          pack_bf2(sspf(acc[2 * i]), sspf(acc[2 * i + 1]));
  }
  __syncthreads();    // sfij fully consumed; smem becomes stage
  // ---- phase 2: MFMA GEMM, D[col][edge]; lane owns 4 consecutive cols ----
  {
    int w = t >> 6, l = t & 63;
    int lrow = l & 15, lkq = (l >> 4) * 8;    // k-offset in shorts
    bf16x8 bfr[8];
#pragma unroll
    for (int g = 0; g < 8; g++)               // A frags: W2c^T col-tiles
      bfr[g] = *(const bf16x8*)(BTbf + (g * 16 + lrow) * 32 + lkq);
    const char* hb = (const char*)hbf;
    unsigned int* stg = (unsigned int*)stage;
#pragma unroll
    for (int et2 = 0; et2 < 2; et2++) {
      int et = 2 * w + et2;
      int edge = et * 16 + lrow;
      bf16x8 af = *(const bf16x8*)(hb + edge * 80 + lkq * 2);  // B frag: h
      float rc = srct[edge];
#pragma unroll
      for (int g = 0; g < 8; g++) {
        f32x4 z = {0.f, 0.f, 0.f, 0.f};
        f32x4 acc = __builtin_amdgcn_mfma_f32_16x16x32_bf16(bfr[g], af, z, 0, 0, 0);
        float4 bias = *(const float4*)(sb2c + g * 16 + (l >> 4) * 4);
        uint2 o;
        o.x = pack_bf2((acc[0] + bias.x) * rc, (acc[1] + bias.y) * rc);
        o.y = pack_bf2((acc[2] + bias.z) * rc, (acc[3] + bias.w) * rc);
        *(uint2*)(stg + edge * 68 + g * 8 + (l >> 4) * 2) = o;
      }
    }
  }
  __syncthreads();
  // ---- phase 3: 128B-chunk scatter to CSR slots ----
  {
    int row = t >> 1, half = t & 1;
    const uint4* src = (const uint4*)((const char*)stage + row * 272 + half * 128);
    uint4* dst = (uint4*)(Wab + (size_t)sslot[row] * 64 + half * 32);
#pragma unroll
    for (int i = 0; i < 8; i++) dst[i] = src[i];
  }
}

// ---------------- k_agg3: one wave per node; sequential bf16 Wab stream ------
__global__ __launch_bounds__(256, 4) void k_agg3(
        const unsigned int* __restrict__ Wu, const int* __restrict__ idxj_csr,
        const float4* __restrict__ Yr_csr, const float4* __restrict__ hsv,
        const int* __restrict__ offs, float* __restrict__ nagg) {
  int t = threadIdx.x;
  int w = t >> 6, l = t & 63;
  int n = blockIdx.x * 4 + w;          // 4096 blocks
  int f = l >> 1, kb = (l & 1) * 2;
  int start = offs[n], end = offs[n + 1];
  float a0 = 0, a1 = 0, a2 = 0, a3 = 0, a4 = 0, a5 = 0;
  if (start < end) {
    int last = end - 1;
    int i1 = start + 1 < last ? start + 1 : last;
    int i2 = start + 2 < last ? start + 2 : last;
    int j0 = idxj_csr[start];
    int j1 = idxj_csr[i1];
    int j2 = idxj_csr[i2];
    float4 y0 = Yr_csr[start];
    float4 sv0 = hsv[(size_t)j0 * 32 + f];
    float4 sv1 = hsv[(size_t)j1 * 32 + f];
    unsigned int W0 = Wu[(size_t)start * 64 + l];
    unsigned int W1 = Wu[(size_t)i1 * 64 + l];
    for (int ei = start; ei < end; ++ei) {
      int in1 = ei + 1 < last ? ei + 1 : last;
      int in2 = ei + 2 < last ? ei + 2 : last;
      int in3 = ei + 3 < last ? ei + 3 : last;
      float4 sv2 = hsv[(size_t)j2 * 32 + f];       // depth-2 (random)
      unsigned int W2r = Wu[(size_t)in2 * 64 + l]; // depth-2 (sequential)
      float4 y1 = Yr_csr[in1];                     // depth-1 (sequential)
      int j3 = idxj_csr[in3];                      // depth-3 (sequential)
      float Wx = __uint_as_float(W0 << 16);
      float Wy = __uint_as_float(W0 & 0xffff0000u);
      float ys = y0.x, yx = y0.y, yy = y0.z, yz = y0.w;
      float ss = sv0.x, vx = sv0.y, vy = sv0.z, vz = sv0.w;
      if (kb == 0) {
        a0 += ss * ys * Wx;                                          // ch0
        a1 += (vx * yx + vy * yy + vz * yz) * 0.57735026918962576f * Wy; // ch1
      } else {
        a0 += ss * yx * Wx; a1 += ss * yy * Wx; a2 += ss * yz * Wx; // t_v1
        a3 += vx * ys * Wy; a4 += vy * ys * Wy; a5 += vz * ys * Wy; // t_v2
      }
      y0 = y1; sv0 = sv1; sv1 = sv2; W0 = W1; W1 = W2r; j2 = j3;
    }
  }
  float* na = nagg + (size_t)n * 256;
  if (kb == 0) {
    na[f] = a0;
    na[32 + f] = a1;
  } else {
    na[64 + 3 * f + 0] = a0;  na[64 + 3 * f + 1] = a1;  na[64 + 3 * f + 2] = a2;
    na[160 + 3 * f + 0] = a3; na[160 + 3 * f + 1] = a4; na[160 + 3 * f + 2] = a5;
  }
}

// ---------------- output GEMMs: W in LDS [k][d], A in register tiles ----------------
__global__ __launch_bounds__(256) void k_os1(const float* __restrict__ na,
        const float* __restrict__ w1s, float* __restrict__ os1) {
  __shared__ float sw[8192];       // w1s [64][128]
  int t = threadIdx.x;
  for (int i = t; i < 8192; i += 256) sw[i] = w1s[i];
  __syncthreads();
  int dg = t & 31, ng = t >> 5;
  int d0 = dg * 4;
  int n0 = blockIdx.x * 32 + ng * 4;      // grid 512
  const float* ap = na + (size_t)n0 * 256;
  float acc[4][4] = {};
#pragma unroll
  for (int kq = 0; kq < 16; kq++) {
    float4 a[4];
#pragma unroll
    for (int j = 0; j < 4; j++) a[j] = *(const float4*)(ap + j * 256 + 4 * kq);
    float4 w0 = *(const float4*)(sw + (4 * kq + 0) * 128 + d0);
    float4 w1 = *(const float4*)(sw + (4 * kq + 1) * 128 + d0);
    float4 w2 = *(const float4*)(sw + (4 * kq + 2) * 128 + d0);
    float4 w3 = *(const float4*)(sw + (4 * kq + 3) * 128 + d0);
#pragma unroll
    for (int j = 0; j < 4; j++) {
      acc[j][0] += a[j].x * w0.x + a[j].y * w1.x + a[j].z * w2.x + a[j].w * w3.x;
      acc[j][1] += a[j].x * w0.y + a[j].y * w1.y + a[j].z * w2.y + a[j].w * w3.y;
      acc[j][2] += a[j].x * w0.z + a[j].y * w1.z + a[j].z * w2.z + a[j].w * w3.z;
      acc[j][3] += a[j].x * w0.w + a[j].y * w1.w + a[j].z * w2.w + a[j].w * w3.w;
    }
  }
#pragma unroll
  for (int j = 0; j < 4; j++) {
    float4 o;
    o.x = sspf(acc[j][0] * 0.125f);   // 1/sqrt(64)
    o.y = sspf(acc[j][1] * 0.125f);
    o.z = sspf(acc[j][2] * 0.125f);
    o.w = sspf(acc[j][3] * 0.125f);
    *(float4*)(os1 + (size_t)(n0 + j) * 128 + d0) = o;
  }
}

__global__ __launch_bounds__(256) void k_os2(const float* __restrict__ os1,
        const float* __restrict__ w2s, float* __restrict__ out) {
  __shared__ float sw[16384];      // w2s [128][128] = 64 KB
  int t = threadIdx.x;
  for (int i = t; i < 16384; i += 256) sw[i] = w2s[i];
  __syncthreads();
  int dg = t & 31, ng = t >> 5;
  int d0 = dg * 4;
  int n0 = blockIdx.x * 32 + ng * 4;      // grid 512
  const float* ap = os1 + (size_t)n0 * 128;
  float acc[4][4] = {};
#pragma unroll
  for (int kq = 0; kq < 32; kq++) {
    float4 a[4];
#pragma unroll
    for (int j = 0; j < 4; j++) a[j] = *(const float4*)(ap + j * 128 + 4 * kq);
    float4 w0 = *(const float4*)(sw + (4 * kq + 0) * 128 + d0);
    float4 w1 = *(const float4*)(sw + (4 * kq + 1) * 128 + d0);
    float4 w2 = *(const float4*)(sw + (4 * kq + 2) * 128 + d0);
    float4 w3 = *(const float4*)(sw + (4 * kq + 3) * 128 + d0);
#pragma unroll
    for (int j = 0; j < 4; j++) {
      acc[j][0] += a[j].x * w0.x + a[j].y * w1.x + a[j].z * w2.x + a[j].w * w3.x;
      acc[j][1] += a[j].x * w0.y + a[j].y * w1.y + a[j].z * w2.y + a[j].w * w3.y;
      acc[j][2] += a[j].x * w0.z + a[j].y * w1.z + a[j].z * w2.z + a[j].w * w3.z;
      acc[j][3] += a[j].x * w0.w + a[j].y * w1.w + a[j].z * w2.w + a[j].w * w3.w;
    }
  }
  const float sc = 0.088388347648318447f;   // 1/sqrt(128)
#pragma unroll
  for (int j = 0; j < 4; j++) {
    float4 o;
    o.x = acc[j][0] * sc; o.y = acc[j][1] * sc;
    o.z = acc[j][2] * sc; o.w = acc[j][3] * sc;
    *(float4*)(out + (size_t)(n0 + j) * 512 + d0) = o;
  }
}

// thread = 2 nodes x 4 d x 3 comps
__global__ __launch_bounds__(256) void k_ov(const float* __restrict__ na,
        const float* __restrict__ Wv, float* __restrict__ out) {
  __shared__ float sw[8192];       // Wv [64][128]
  int t = threadIdx.x;
  for (int i = t; i < 8192; i += 256) sw[i] = Wv[i];
  __syncthreads();
  int dg = t & 31, ng = t >> 5;
  int d0 = dg * 4;
  int n0 = blockIdx.x * 16 + ng * 2;      // grid 1024
  const float* ap = na + (size_t)n0 * 256 + 64;   // v_in row: 192 contiguous
  float acc[2][12] = {};
#pragma unroll
  for (int mq = 0; mq < 16; mq++) {
    float4 p[2][3];
#pragma unroll
    for (int j = 0; j < 2; j++) {
      p[j][0] = *(const float4*)(ap + j * 256 + 12 * mq);
      p[j][1] = *(const float4*)(ap + j * 256 + 12 * mq + 4);
      p[j][2] = *(const float4*)(ap + j * 256 + 12 * mq + 8);
    }
    float4 w0 = *(const float4*)(sw + (4 * mq + 0) * 128 + d0);
    float4 w1 = *(const float4*)(sw + (4 * mq + 1) * 128 + d0);
    float4 w2 = *(const float4*)(sw + (4 * mq + 2) * 128 + d0);
    float4 w3 = *(const float4*)(sw + (4 * mq + 3) * 128 + d0);
#pragma unroll
    for (int j = 0; j < 2; j++) {
      float vm[4][3];
      vm[0][0] = p[j][0].x; vm[0][1] = p[j][0].y; vm[0][2] = p[j][0].z;
      vm[1][0] = p[j][0].w; vm[1][1] = p[j][1].x; vm[1][2] = p[j][1].y;
      vm[2][0] = p[j][1].z; vm[2][1] = p[j][1].w; vm[2][2] = p[j][2].x;
      vm[3][0] = p[j][2].y; vm[3][1] = p[j][2].z; vm[3][2] = p[j][2].w;
      float wm[4][4];
      wm[0][0] = w0.x; wm[0][1] = w0.y; wm[0][2] = w0.z; wm[0][3] = w0.w;
      wm[1][0] = w1.x; wm[1][1] = w1.y; wm[1][2] = w1.z; wm[1][3] = w1.w;
      wm[2][0] = w2.x; wm[2][1] = w2.y; wm[2][2] = w2.z; wm[2][3] = w2.w;
      wm[3][0] = w3.x; wm[3][1] = w3.y; wm[3][2] = w3.z; wm[3][3] = w3.w;
#pragma unroll
      for (int m = 0; m < 4; m++)
#pragma unroll
        for (int i = 0; i < 4; i++)
#pragma unroll
          for (int c = 0; c < 3; c++)
            acc[j][i * 3 + c] += vm[m][c] * wm[m][i];
    }
  }
#pragma unroll
  for (int j = 0; j < 2; j++) {
    float* op = out + (size_t)(n0 + j) * 512 + 128 + 12 * dg;
    float4 o0, o1, o2;
    o0.x = acc[j][0]; o0.y = acc[j][1]; o0.z = acc[j][2]; o0.w = acc[j][3];
    o1.x = acc[j][4]; o1.y = acc[j][5]; o1.z = acc[j][6]; o1.w = acc[j][7];
    o2.x = acc[j][8]; o2.y = acc[j][9]; o2.z = acc[j][10]; o2.w = acc[j][11];
    *(float4*)op = o0;
    *(float4*)(op + 4) = o1;
    *(float4*)(op + 8) = o2;
  }
}

extern "C" void kernel_launch(void* const* d_in, const int* in_sizes, int n_in,
                              void* d_out, int out_size, void* d_ws, size_t ws_size,
                              hipStream_t stream) {
  const float* x    = (const float*)d_in[0];
  const int*   idx_i = (const int*)d_in[1];
  const int*   idx_j = (const int*)d_in[2];
  const float* fij  = (const float*)d_in[3];
  const float* rcut = (const float*)d_in[4];
  const float* Yr   = (const float*)d_in[5];
  const float* w_s  = (const float*)d_in[6];
  const float* w_v  = (const float*)d_in[7];
  const float* W1   = (const float*)d_in[8];
  const float* b1   = (const float*)d_in[9];
  const float* W2   = (const float*)d_in[10];
  const float* b2   = (const float*)d_in[11];
  const float* w1s  = (const float*)d_in[12];
  const float* w1v  = (const float*)d_in[13];
  const float* w2s  = (const float*)d_in[14];
  const float* w2v  = (const float*)d_in[15];
  float* out = (float*)d_out;

  char* ws = (char*)d_ws;
  size_t off = 0;
  auto alloc = [&](size_t bytes) {
    void* p = ws + off;
    off += (bytes + 255) & ~(size_t)255;
    return p;
  };
  float4* hsv   = (float4*)alloc((size_t)NN * 32 * 16);
  float*  nagg  = (float*)alloc((size_t)NN * 256 * 4);
  unsigned int* Wab = (unsigned int*)alloc((size_t)EE * 128 * 2);  // bf16, 67 MB
  float*  os1   = (float*)alloc((size_t)NN * 128 * 4);
  float4* Yr_csr = (float4*)alloc((size_t)EE * 16);
  int* idxj_csr = (int*)alloc((size_t)EE * 4);
  int* slot_of_e = (int*)alloc((size_t)EE * 4);
  float* Wv     = (float*)alloc((size_t)8192 * 4);
  unsigned short* BTbf = (unsigned short*)alloc((size_t)4096 * 2);
  int* cnt      = (int*)alloc((size_t)NN * 4);
  int* offs     = (int*)alloc((size_t)(NN + 1) * 4);
  int* pos      = (int*)alloc((size_t)EE * 4);

  hipMemsetAsync(cnt, 0, (size_t)NN * 4, stream);
  k_count<<<EE / 256, 256, 0, stream>>>(idx_i, cnt, pos);
  k_scan<<<1, 256, 0, stream>>>(cnt, offs);
  k_fill<<<EE / 256, 256, 0, stream>>>(idx_i, idx_j, Yr, pos, offs,
                                       slot_of_e, idxj_csr, Yr_csr);
  k_embed<<<NN / 32, 256, 0, stream>>>(x, w_s, w_v, hsv);
  k_wv<<<32, 256, 0, stream>>>(w1v, w2v, Wv);
  k_prep<<<16, 256, 0, stream>>>(W2, BTbf);
  k_wab<<<EE / 128, 256, 0, stream>>>(fij, rcut, slot_of_e, W1, b1, BTbf, b2, Wab);
  k_agg3<<<NN / 4, 256, 0, stream>>>(Wab, idxj_csr, Yr_csr, hsv, offs, nagg);
  k_os1<<<512, 256, 0, stream>>>(nagg, w1s, os1);
  k_os2<<<512, 256, 0, stream>>>(os1, w2s, out);
  k_ov<<<1024, 256, 0, stream>>>(nagg, Wv, out);
}

// Round 16
// 194.380 us; speedup vs baseline: 1.7998x; 1.0439x over previous
//
#include <hip/hip_runtime.h>
#include <math.h>

#define NN 16384
#define BB 128
#define FF 32
#define RR 20
#define EE 262144

typedef __attribute__((ext_vector_type(8))) short bf16x8;
typedef __attribute__((ext_vector_type(4))) float f32x4;

__device__ __forceinline__ float sspf(float x) {
  // softplus(x) - log(2) via HW v_exp/v_log: max(x,0) + (log2(1+e^-|x|)-1)*ln2
  float t = __expf(-fabsf(x));
  return fmaxf(x, 0.0f) + (__log2f(1.0f + t) - 1.0f) * 0.69314718055994531f;
}

// pack two floats to bf16x2 (RNE)
__device__ __forceinline__ unsigned int pack_bf2(float a, float b) {
  unsigned int ua = __float_as_uint(a);
  ua = (ua + 0x7fffu + ((ua >> 16) & 1u)) >> 16;
  unsigned int ub = __float_as_uint(b);
  ub = (ub + 0x7fffu + ((ub >> 16) & 1u)) & 0xffff0000u;
  return ua | ub;
}

__device__ __forceinline__ unsigned short pack_bf1(float a) {
  unsigned int ua = __float_as_uint(a);
  ua = (ua + 0x7fffu + ((ua >> 16) & 1u)) >> 16;
  return (unsigned short)ua;
}

// ---------------- K1: node embeddings, x rows staged in LDS ----------------
__global__ __launch_bounds__(256) void k_embed(const float* __restrict__ x,
        const float* __restrict__ ws, const float* __restrict__ wv,
        float4* __restrict__ hsv) {
  __shared__ float sx[32 * 516];   // 66 KB
  int t = threadIdx.x;
  int b0 = blockIdx.x * 32;        // 512 blocks
  const float4* xg = (const float4*)(x + (size_t)b0 * 512);
  for (int i = t; i < 4096; i += 256) {
    int row = i >> 7, col = i & 127;
    *(float4*)(sx + row * 516 + col * 4) = xg[i];
  }
  __syncthreads();
  int n = t >> 3, fq = t & 7;
  const float* xr = sx + n * 516;
  float acc[4][4];
#pragma unroll
  for (int k = 0; k < 4; k++)
#pragma unroll
    for (int c = 0; c < 4; c++) acc[k][c] = 0.f;
  for (int bq = 0; bq < 32; bq++) {
    float4 xs4 = *(const float4*)(xr + 4 * bq);
    float4 a0 = *(const float4*)(xr + 128 + 12 * bq);
    float4 a1 = *(const float4*)(xr + 128 + 12 * bq + 4);
    float4 a2 = *(const float4*)(xr + 128 + 12 * bq + 8);
    float xsv[4] = {xs4.x, xs4.y, xs4.z, xs4.w};
    float vv[4][3];
    vv[0][0] = a0.x; vv[0][1] = a0.y; vv[0][2] = a0.z;
    vv[1][0] = a0.w; vv[1][1] = a1.x; vv[1][2] = a1.y;
    vv[2][0] = a1.z; vv[2][1] = a1.w; vv[2][2] = a2.x;
    vv[3][0] = a2.y; vv[3][1] = a2.z; vv[3][2] = a2.w;
#pragma unroll
    for (int bb = 0; bb < 4; bb++) {
      int b = 4 * bq + bb;
      float4 w_s = *(const float4*)(ws + b * 32 + 4 * fq);
      float4 w_v = *(const float4*)(wv + b * 32 + 4 * fq);
      float wsx[4] = {w_s.x, w_s.y, w_s.z, w_s.w};
      float wvx[4] = {w_v.x, w_v.y, w_v.z, w_v.w};
#pragma unroll
      for (int k = 0; k < 4; k++) {
        acc[k][0] += xsv[bb] * wsx[k];
        acc[k][1] += vv[bb][0] * wvx[k];
        acc[k][2] += vv[bb][1] * wvx[k];
        acc[k][3] += vv[bb][2] * wvx[k];
      }
    }
  }
  const float sc = 0.088388347648318447f;  // 1/sqrt(128)
#pragma unroll
  for (int k = 0; k < 4; k++) {
    float4 o;
    o.x = acc[k][0] * sc; o.y = acc[k][1] * sc;
    o.z = acc[k][2] * sc; o.w = acc[k][3] * sc;
    hsv[(size_t)(b0 + n) * 32 + 4 * fq + k] = o;
  }
}

// ---------------- CSR build ----------------
__global__ __launch_bounds__(256) void k_count(const int* __restrict__ idx_i,
        int* __restrict__ cnt, int* __restrict__ pos) {
  int e = blockIdx.x * 256 + threadIdx.x;
  pos[e] = atomicAdd(cnt + idx_i[e], 1);
}

__global__ __launch_bounds__(256) void k_scan(const int* __restrict__ cnt,
        int* __restrict__ offs) {
  __shared__ int part[256];
  int t = threadIdx.x;
  int s = 0;
  for (int i = t * 64; i < t * 64 + 64; ++i) s += cnt[i];
  part[t] = s;
  __syncthreads();
  if (t == 0) {
    int run = 0;
    for (int i = 0; i < 256; i++) { int v = part[i]; part[i] = run; run += v; }
    offs[NN] = run;
  }
  __syncthreads();
  int run = part[t];
  for (int i = t * 64; i < t * 64 + 64; ++i) { offs[i] = run; run += cnt[i]; }
}

// CSR permutation: slot_of_e (for wab scatter-write) + idx_j/Yr slot streams
__global__ __launch_bounds__(256) void k_fill(const int* __restrict__ idx_i,
        const int* __restrict__ idx_j, const float* __restrict__ Yr,
        const int* __restrict__ pos, const int* __restrict__ offs,
        int* __restrict__ slot_of_e, int* __restrict__ idxj_csr,
        float4* __restrict__ Yr_csr) {
  int e = blockIdx.x * 256 + threadIdx.x;
  int slot = offs[idx_i[e]] + pos[e];
  slot_of_e[e] = slot;
  idxj_csr[slot] = idx_j[e];
  Yr_csr[slot] = *(const float4*)(Yr + (size_t)e * 4);
}

// ---------------- fused vector output weight: Wv = w1v @ w2v * 1/sqrt(64*128) ----------------
__global__ __launch_bounds__(256) void k_wv(const float* __restrict__ w1v,
        const float* __restrict__ w2v, float* __restrict__ Wv) {
  int o = blockIdx.x * 256 + threadIdx.x;   // 8192
  int m = o >> 7, d = o & 127;
  float s = 0.f;
  for (int b = 0; b < 128; b++) s += w1v[m * 128 + b] * w2v[b * 128 + d];
  Wv[o] = s * 0.011048543456039804f;
}

// ---------------- k_prep: W2c^T in bf16, [col][k] layout for MFMA frags ----
__global__ __launch_bounds__(256) void k_prep(const float* __restrict__ W2,
        unsigned short* __restrict__ BTbf) {
  int i = blockIdx.x * 256 + threadIdx.x;   // 4096
  int col = i >> 5, k = i & 31;
  BTbf[col * 32 + k] = pack_bf1(W2[k * 192 + 6 * (col >> 2) + (col & 3)]);
}

// ---------------- k_wab: h (fp32 VALU) then MFMA bf16 GEMM, direct scatter ----
// Block = 128 edges. MFMA D[col][edge]: lane owns 4 consecutive cols of one
// edge; epilogue writes uint2 straight to Wab[slot] (no LDS stage, no 3rd
// phase). LDS ~24.6 KB -> 6 blocks/CU.
__global__ __launch_bounds__(256, 4) void k_wab(
        const float* __restrict__ fij, const float* __restrict__ rcut,
        const int* __restrict__ slot_of_e,
        const float* __restrict__ W1, const float* __restrict__ b1,
        const unsigned short* __restrict__ BTbf, const float* __restrict__ b2,
        unsigned int* __restrict__ Wab) {
  __shared__ float sfij[20 * 130];            // [r][el], 10.4 KB
  __shared__ unsigned short hbf[128 * 40];    // [edge][k], 80B rows, 10.2 KB
  __shared__ float sW1[640];
  __shared__ float sb1[32];
  __shared__ float sb2c[128];
  __shared__ float srct[128];
  __shared__ int sslot[128];
  int t = threadIdx.x;
  size_t e0 = (size_t)blockIdx.x * 128;       // 2048 blocks
  for (int i = t; i < 640; i += 256) sW1[i] = W1[i];
  if (t < 32) sb1[t] = b1[t];
  if (t < 128) {
    sb2c[t] = b2[6 * (t >> 2) + (t & 3)];
    srct[t] = rcut[e0 + t];
    sslot[t] = slot_of_e[e0 + t];
  }
  for (int i = t; i < 2560; i += 256) {
    int el = i / 20, r = i - el * 20;
    sfij[r * 130 + el] = fij[e0 * 20 + i];    // coalesced global read
  }
  __syncthreads();
  // ---- phase 1: h rows, 2 threads/edge (16 fp each) ----
  {
    int el = t >> 1, fp0 = (t & 1) * 16;
    float acc[16];
#pragma unroll
    for (int i = 0; i < 16; i++) acc[i] = sb1[fp0 + i];
#pragma unroll
    for (int r = 0; r < 20; r++) {
      float fe = sfij[r * 130 + el];
      float4 wA = *(const float4*)(sW1 + r * 32 + fp0);
      float4 wB = *(const float4*)(sW1 + r * 32 + fp0 + 4);
      float4 wC = *(const float4*)(sW1 + r * 32 + fp0 + 8);
      float4 wD = *(const float4*)(sW1 + r * 32 + fp0 + 12);
      acc[0] += fe * wA.x;  acc[1] += fe * wA.y;
      acc[2] += fe * wA.z;  acc[3] += fe * wA.w;
      acc[4] += fe * wB.x;  acc[5] += fe * wB.y;
      acc[6] += fe * wB.z;  acc[7] += fe * wB.w;
      acc[8] += fe * wC.x;  acc[9] += fe * wC.y;
      acc[10] += fe * wC.z; acc[11] += fe * wC.w;
      acc[12] += fe * wD.x; acc[13] += fe * wD.y;
      acc[14] += fe * wD.z; acc[15] += fe * wD.w;
    }
    unsigned int* hw = (unsigned int*)hbf;
#pragma unroll
    for (int i = 0; i < 8; i++)
      hw[el * 20 + (fp0 >> 1) + i] =
          pack_bf2(sspf(acc[2 * i]), sspf(acc[2 * i + 1]));
  }
  __syncthreads();
  // ---- phase 2: MFMA GEMM D[col][edge]; direct uint2 scatter to Wab ----
  {
    int w = t >> 6, l = t & 63;
    int lrow = l & 15, lq = l >> 4;
    int lkq = lq * 8;                         // k-offset in shorts
    bf16x8 bfr[8];
#pragma unroll
    for (int g = 0; g < 8; g++)               // A frags: W2c^T col-tiles
      bfr[g] = *(const bf16x8*)(BTbf + (g * 16 + lrow) * 32 + lkq);
#pragma unroll
    for (int et2 = 0; et2 < 2; et2++) {
      int edge = (2 * w + et2) * 16 + lrow;
      bf16x8 af = *(const bf16x8*)(hbf + edge * 40 + lkq);   // B frag: h
      float rc = srct[edge];
      unsigned int* dst = Wab + (size_t)sslot[edge] * 64;
#pragma unroll
      for (int g = 0; g < 8; g++) {
        f32x4 z = {0.f, 0.f, 0.f, 0.f};
        f32x4 acc = __builtin_amdgcn_mfma_f32_16x16x32_bf16(bfr[g], af, z, 0, 0, 0);
        float4 bias = *(const float4*)(sb2c + g * 16 + lq * 4);
        uint2 o;
        o.x = pack_bf2((acc[0] + bias.x) * rc, (acc[1] + bias.y) * rc);
        o.y = pack_bf2((acc[2] + bias.z) * rc, (acc[3] + bias.w) * rc);
        *(uint2*)(dst + g * 8 + lq * 2) = o;
      }
    }
  }
}

// ---------------- k_agg3: one wave per node; sequential bf16 Wab stream ------
__global__ __launch_bounds__(256, 4) void k_agg3(
        const unsigned int* __restrict__ Wu, const int* __restrict__ idxj_csr,
        const float4* __restrict__ Yr_csr, const float4* __restrict__ hsv,
        const int* __restrict__ offs, float* __restrict__ nagg) {
  int t = threadIdx.x;
  int w = t >> 6, l = t & 63;
  int n = blockIdx.x * 4 + w;          // 4096 blocks
  int f = l >> 1, kb = (l & 1) * 2;
  int start = offs[n], end = offs[n + 1];
  float a0 = 0, a1 = 0, a2 = 0, a3 = 0, a4 = 0, a5 = 0;
  if (start < end) {
    int last = end - 1;
    int i1 = start + 1 < last ? start + 1 : last;
    int i2 = start + 2 < last ? start + 2 : last;
    int j0 = idxj_csr[start];
    int j1 = idxj_csr[i1];
    int j2 = idxj_csr[i2];
    float4 y0 = Yr_csr[start];
    float4 sv0 = hsv[(size_t)j0 * 32 + f];
    float4 sv1 = hsv[(size_t)j1 * 32 + f];
    unsigned int W0 = Wu[(size_t)start * 64 + l];
    unsigned int W1 = Wu[(size_t)i1 * 64 + l];
    for (int ei = start; ei < end; ++ei) {
      int in1 = ei + 1 < last ? ei + 1 : last;
      int in2 = ei + 2 < last ? ei + 2 : last;
      int in3 = ei + 3 < last ? ei + 3 : last;
      float4 sv2 = hsv[(size_t)j2 * 32 + f];       // depth-2 (random)
      unsigned int W2r = Wu[(size_t)in2 * 64 + l]; // depth-2 (sequential)
      float4 y1 = Yr_csr[in1];                     // depth-1 (sequential)
      int j3 = idxj_csr[in3];                      // depth-3 (sequential)
      float Wx = __uint_as_float(W0 << 16);
      float Wy = __uint_as_float(W0 & 0xffff0000u);
      float ys = y0.x, yx = y0.y, yy = y0.z, yz = y0.w;
      float ss = sv0.x, vx = sv0.y, vy = sv0.z, vz = sv0.w;
      if (kb == 0) {
        a0 += ss * ys * Wx;                                          // ch0
        a1 += (vx * yx + vy * yy + vz * yz) * 0.57735026918962576f * Wy; // ch1
      } else {
        a0 += ss * yx * Wx; a1 += ss * yy * Wx; a2 += ss * yz * Wx; // t_v1
        a3 += vx * ys * Wy; a4 += vy * ys * Wy; a5 += vz * ys * Wy; // t_v2
      }
      y0 = y1; sv0 = sv1; sv1 = sv2; W0 = W1; W1 = W2r; j2 = j3;
    }
  }
  float* na = nagg + (size_t)n * 256;
  if (kb == 0) {
    na[f] = a0;
    na[32 + f] = a1;
  } else {
    na[64 + 3 * f + 0] = a0;  na[64 + 3 * f + 1] = a1;  na[64 + 3 * f + 2] = a2;
    na[160 + 3 * f + 0] = a3; na[160 + 3 * f + 1] = a4; na[160 + 3 * f + 2] = a5;
  }
}

// ---------------- output GEMMs: W in LDS [k][d], A in register tiles ----------------
__global__ __launch_bounds__(256) void k_os1(const float* __restrict__ na,
        const float* __restrict__ w1s, float* __restrict__ os1) {
  __shared__ float sw[8192];       // w1s [64][128]
  int t = threadIdx.x;
  for (int i = t; i < 8192; i += 256) sw[i] = w1s[i];
  __syncthreads();
  int dg = t & 31, ng = t >> 5;
  int d0 = dg * 4;
  int n0 = blockIdx.x * 32 + ng * 4;      // grid 512
  const float* ap = na + (size_t)n0 * 256;
  float acc[4][4] = {};
#pragma unroll
  for (int kq = 0; kq < 16; kq++) {
    float4 a[4];
#pragma unroll
    for (int j = 0; j < 4; j++) a[j] = *(const float4*)(ap + j * 256 + 4 * kq);
    float4 w0 = *(const float4*)(sw + (4 * kq + 0) * 128 + d0);
    float4 w1 = *(const float4*)(sw + (4 * kq + 1) * 128 + d0);
    float4 w2 = *(const float4*)(sw + (4 * kq + 2) * 128 + d0);
    float4 w3 = *(const float4*)(sw + (4 * kq + 3) * 128 + d0);
#pragma unroll
    for (int j = 0; j < 4; j++) {
      acc[j][0] += a[j].x * w0.x + a[j].y * w1.x + a[j].z * w2.x + a[j].w * w3.x;
      acc[j][1] += a[j].x * w0.y + a[j].y * w1.y + a[j].z * w2.y + a[j].w * w3.y;
      acc[j][2] += a[j].x * w0.z + a[j].y * w1.z + a[j].z * w2.z + a[j].w * w3.z;
      acc[j][3] += a[j].x * w0.w + a[j].y * w1.w + a[j].z * w2.w + a[j].w * w3.w;
    }
  }
#pragma unroll
  for (int j = 0; j < 4; j++) {
    float4 o;
    o.x = sspf(acc[j][0] * 0.125f);   // 1/sqrt(64)
    o.y = sspf(acc[j][1] * 0.125f);
    o.z = sspf(acc[j][2] * 0.125f);
    o.w = sspf(acc[j][3] * 0.125f);
    *(float4*)(os1 + (size_t)(n0 + j) * 128 + d0) = o;
  }
}

__global__ __launch_bounds__(256) void k_os2(const float* __restrict__ os1,
        const float* __restrict__ w2s, float* __restrict__ out) {
  __shared__ float sw[16384];      // w2s [128][128] = 64 KB
  int t = threadIdx.x;
  for (int i = t; i < 16384; i += 256) sw[i] = w2s[i];
  __syncthreads();
  int dg = t & 31, ng = t >> 5;
  int d0 = dg * 4;
  int n0 = blockIdx.x * 32 + ng * 4;      // grid 512
  const float* ap = os1 + (size_t)n0 * 128;
  float acc[4][4] = {};
#pragma unroll
  for (int kq = 0; kq < 32; kq++) {
    float4 a[4];
#pragma unroll
    for (int j = 0; j < 4; j++) a[j] = *(const float4*)(ap + j * 128 + 4 * kq);
    float4 w0 = *(const float4*)(sw + (4 * kq + 0) * 128 + d0);
    float4 w1 = *(const float4*)(sw + (4 * kq + 1) * 128 + d0);
    float4 w2 = *(const float4*)(sw + (4 * kq + 2) * 128 + d0);
    float4 w3 = *(const float4*)(sw + (4 * kq + 3) * 128 + d0);
#pragma unroll
    for (int j = 0; j < 4; j++) {
      acc[j][0] += a[j].x * w0.x + a[j].y * w1.x + a[j].z * w2.x + a[j].w * w3.x;
      acc[j][1] += a[j].x * w0.y + a[j].y * w1.y + a[j].z * w2.y + a[j].w * w3.y;
      acc[j][2] += a[j].x * w0.z + a[j].y * w1.z + a[j].z * w2.z + a[j].w * w3.z;
      acc[j][3] += a[j].x * w0.w + a[j].y * w1.w + a[j].z * w2.w + a[j].w * w3.w;
    }
  }
  const float sc = 0.088388347648318447f;   // 1/sqrt(128)
#pragma unroll
  for (int j = 0; j < 4; j++) {
    float4 o;
    o.x = acc[j][0] * sc; o.y = acc[j][1] * sc;
    o.z = acc[j][2] * sc; o.w = acc[j][3] * sc;
    *(float4*)(out + (size_t)(n0 + j) * 512 + d0) = o;
  }
}

// thread = 2 nodes x 4 d x 3 comps
__global__ __launch_bounds__(256) void k_ov(const float* __restrict__ na,
        const float* __restrict__ Wv, float* __restrict__ out) {
  __shared__ float sw[8192];       // Wv [64][128]
  int t = threadIdx.x;
  for (int i = t; i < 8192; i += 256) sw[i] = Wv[i];
  __syncthreads();
  int dg = t & 31, ng = t >> 5;
  int d0 = dg * 4;
  int n0 = blockIdx.x * 16 + ng * 2;      // grid 1024
  const float* ap = na + (size_t)n0 * 256 + 64;   // v_in row: 192 contiguous
  float acc[2][12] = {};
#pragma unroll
  for (int mq = 0; mq < 16; mq++) {
    float4 p[2][3];
#pragma unroll
    for (int j = 0; j < 2; j++) {
      p[j][0] = *(const float4*)(ap + j * 256 + 12 * mq);
      p[j][1] = *(const float4*)(ap + j * 256 + 12 * mq + 4);
      p[j][2] = *(const float4*)(ap + j * 256 + 12 * mq + 8);
    }
    float4 w0 = *(const float4*)(sw + (4 * mq + 0) * 128 + d0);
    float4 w1 = *(const float4*)(sw + (4 * mq + 1) * 128 + d0);
    float4 w2 = *(const float4*)(sw + (4 * mq + 2) * 128 + d0);
    float4 w3 = *(const float4*)(sw + (4 * mq + 3) * 128 + d0);
#pragma unroll
    for (int j = 0; j < 2; j++) {
      float vm[4][3];
      vm[0][0] = p[j][0].x; vm[0][1] = p[j][0].y; vm[0][2] = p[j][0].z;
      vm[1][0] = p[j][0].w; vm[1][1] = p[j][1].x; vm[1][2] = p[j][1].y;
      vm[2][0] = p[j][1].z; vm[2][1] = p[j][1].w; vm[2][2] = p[j][2].x;
      vm[3][0] = p[j][2].y; vm[3][1] = p[j][2].z; vm[3][2] = p[j][2].w;
      float wm[4][4];
      wm[0][0] = w0.x; wm[0][1] = w0.y; wm[0][2] = w0.z; wm[0][3] = w0.w;
      wm[1][0] = w1.x; wm[1][1] = w1.y; wm[1][2] = w1.z; wm[1][3] = w1.w;
      wm[2][0] = w2.x; wm[2][1] = w2.y; wm[2][2] = w2.z; wm[2][3] = w2.w;
      wm[3][0] = w3.x; wm[3][1] = w3.y; wm[3][2] = w3.z; wm[3][3] = w3.w;
#pragma unroll
      for (int m = 0; m < 4; m++)
#pragma unroll
        for (int i = 0; i < 4; i++)
#pragma unroll
          for (int c = 0; c < 3; c++)
            acc[j][i * 3 + c] += vm[m][c] * wm[m][i];
    }
  }
#pragma unroll
  for (int j = 0; j < 2; j++) {
    float* op = out + (size_t)(n0 + j) * 512 + 128 + 12 * dg;
    float4 o0, o1, o2;
    o0.x = acc[j][0]; o0.y = acc[j][1]; o0.z = acc[j][2]; o0.w = acc[j][3];
    o1.x = acc[j][4]; o1.y = acc[j][5]; o1.z = acc[j][6]; o1.w = acc[j][7];
    o2.x = acc[j][8]; o2.y = acc[j][9]; o2.z = acc[j][10]; o2.w = acc[j][11];
    *(float4*)op = o0;
    *(float4*)(op + 4) = o1;
    *(float4*)(op + 8) = o2;
  }
}

extern "C" void kernel_launch(void* const* d_in, const int* in_sizes, int n_in,
                              void* d_out, int out_size, void* d_ws, size_t ws_size,
                              hipStream_t stream) {
  const float* x    = (const float*)d_in[0];
  const int*   idx_i = (const int*)d_in[1];
  const int*   idx_j = (const int*)d_in[2];
  const float* fij  = (const float*)d_in[3];
  const float* rcut = (const float*)d_in[4];
  const float* Yr   = (const float*)d_in[5];
  const float* w_s  = (const float*)d_in[6];
  const float* w_v  = (const float*)d_in[7];
  const float* W1   = (const float*)d_in[8];
  const float* b1   = (const float*)d_in[9];
  const float* W2   = (const float*)d_in[10];
  const float* b2   = (const float*)d_in[11];
  const float* w1s  = (const float*)d_in[12];
  const float* w1v  = (const float*)d_in[13];
  const float* w2s  = (const float*)d_in[14];
  const float* w2v  = (const float*)d_in[15];
  float* out = (float*)d_out;

  char* ws = (char*)d_ws;
  size_t off = 0;
  auto alloc = [&](size_t bytes) {
    void* p = ws + off;
    off += (bytes + 255) & ~(size_t)255;
    return p;
  };
  float4* hsv   = (float4*)alloc((size_t)NN * 32 * 16);
  float*  nagg  = (float*)alloc((size_t)NN * 256 * 4);
  unsigned int* Wab = (unsigned int*)alloc((size_t)EE * 128 * 2);  // bf16, 67 MB
  float*  os1   = (float*)alloc((size_t)NN * 128 * 4);
  float4* Yr_csr = (float4*)alloc((size_t)EE * 16);
  int* idxj_csr = (int*)alloc((size_t)EE * 4);
  int* slot_of_e = (int*)alloc((size_t)EE * 4);
  float* Wv     = (float*)alloc((size_t)8192 * 4);
  unsigned short* BTbf = (unsigned short*)alloc((size_t)4096 * 2);
  int* cnt      = (int*)alloc((size_t)NN * 4);
  int* offs     = (int*)alloc((size_t)(NN + 1) * 4);
  int* pos      = (int*)alloc((size_t)EE * 4);

  hipMemsetAsync(cnt, 0, (size_t)NN * 4, stream);
  k_count<<<EE / 256, 256, 0, stream>>>(idx_i, cnt, pos);
  k_scan<<<1, 256, 0, stream>>>(cnt, offs);
  k_fill<<<EE / 256, 256, 0, stream>>>(idx_i, idx_j, Yr, pos, offs,
                                       slot_of_e, idxj_csr, Yr_csr);
  k_embed<<<NN / 32, 256, 0, stream>>>(x, w_s, w_v, hsv);
  k_wv<<<32, 256, 0, stream>>>(w1v, w2v, Wv);
  k_prep<<<16, 256, 0, stream>>>(W2, BTbf);
  k_wab<<<EE / 128, 256, 0, stream>>>(fij, rcut, slot_of_e, W1, b1, BTbf, b2, Wab);
  k_agg3<<<NN / 4, 256, 0, stream>>>(Wab, idxj_csr, Yr_csr, hsv, offs, nagg);
  k_os1<<<512, 256, 0, stream>>>(nagg, w1s, os1);
  k_os2<<<512, 256, 0, stream>>>(os1, w2s, out);
  k_ov<<<1024, 256, 0, stream>>>(nagg, Wv, out);
}